// Round 3
// baseline (1407.511 us; speedup 1.0000x reference)
//
#include <hip/hip_runtime.h>

#define NN 50000
#define NE 1600000
#define DD 64
#define NGRAPH 64
#define DOUT 32
#define DELTA_F 2.5749f
#define BN_EPS_F 1e-5f

// ---------------- init: zero counters / bn stats / pool ----------------
__global__ void k_init(int* __restrict__ counts, float* __restrict__ bnstat,
                       float* __restrict__ gpool) {
    int i = blockIdx.x * 256 + threadIdx.x;
    if (i < NN) counts[i] = 0;
    if (i < 384) bnstat[i] = 0.f;
    if (i < NGRAPH * DD) gpool[i] = 0.f;
}

// ---------------- CSR build ----------------
__global__ void k_count(const int* __restrict__ dst, int* __restrict__ counts) {
    int e = blockIdx.x * 256 + threadIdx.x;
    if (e < NE) atomicAdd(&counts[dst[e]], 1);
}

__global__ void k_scan_a(const int* __restrict__ counts, int* __restrict__ blockSums) {
    __shared__ int red[256];
    int tid = threadIdx.x;
    int gid = blockIdx.x * 256 + tid;
    int v = (gid < NN) ? counts[gid] : 0;
    red[tid] = v;
    __syncthreads();
    for (int s = 128; s > 0; s >>= 1) {
        if (tid < s) red[tid] += red[tid + s];
        __syncthreads();
    }
    if (tid == 0) blockSums[blockIdx.x] = red[0];
}

__global__ void k_scan_b(const int* __restrict__ blockSums, int* __restrict__ blockBase) {
    __shared__ int sh[256];
    int tid = threadIdx.x;
    int v = (tid < 196) ? blockSums[tid] : 0;
    sh[tid] = v;
    __syncthreads();
    for (int off = 1; off < 256; off <<= 1) {
        int t = (tid >= off) ? sh[tid - off] : 0;
        __syncthreads();
        sh[tid] += t;
        __syncthreads();
    }
    blockBase[tid] = sh[tid] - v;  // exclusive
}

__global__ void k_scan_c(const int* __restrict__ counts, const int* __restrict__ blockBase,
                         int* __restrict__ row_ptr, int* __restrict__ cursor) {
    __shared__ int sh[256];
    int tid = threadIdx.x;
    int gid = blockIdx.x * 256 + tid;
    int v = (gid < NN) ? counts[gid] : 0;
    sh[tid] = v;
    __syncthreads();
    for (int off = 1; off < 256; off <<= 1) {
        int t = (tid >= off) ? sh[tid - off] : 0;
        __syncthreads();
        sh[tid] += t;
        __syncthreads();
    }
    int excl = blockBase[blockIdx.x] + sh[tid] - v;
    if (gid <= NN) {
        row_ptr[gid] = excl;
        if (gid < NN) cursor[gid] = excl;
    }
}

__global__ void k_fill(const int* __restrict__ src, const int* __restrict__ dst,
                       int* __restrict__ cursor, int* __restrict__ csr_src) {
    int e = blockIdx.x * 256 + threadIdx.x;
    if (e < NE) {
        int d = dst[e];
        int pos = atomicAdd(&cursor[d], 1);
        csr_src[pos] = src[e];
    }
}

// ---------------- per-node aggregation: sum/max/mean/var ----------------
// 1 node per wave; 16 lanes per row (float4/lane), 4 edges in flight per load
// instruction, 2x unrolled (8 edges). Cross-group combine via shfl_xor.
__global__ __launch_bounds__(256) void k_agg(const float* __restrict__ X,
                                             const int* __restrict__ row_ptr,
                                             const int* __restrict__ csr_src,
                                             float* __restrict__ aggr) {
    int wave = threadIdx.x >> 6;
    int lane = threadIdx.x & 63;
    int node = blockIdx.x * 4 + wave;
    if (node >= NN) return;
    int beg = row_ptr[node], end = row_ptr[node + 1];
    int grp = lane >> 4;
    int l16 = lane & 15;
    const float* Xq = X + l16 * 4;

    float sx = 0.f, sy = 0.f, sz = 0.f, sw = 0.f;
    float qx = 0.f, qy = 0.f, qz = 0.f, qw = 0.f;
    const float NEG = -3.402823466e38f;
    float mx = NEG, my = NEG, mz = NEG, mw = NEG;

    for (int e0 = beg; e0 < end; e0 += 8) {
        int ea = e0 + grp;
        int eb = e0 + 4 + grp;
        int ia = csr_src[(ea < end) ? ea : beg];
        int ib = csr_src[(eb < end) ? eb : beg];
        float4 va = *(const float4*)(Xq + (size_t)ia * DD);
        float4 vb = *(const float4*)(Xq + (size_t)ib * DD);
        if (ea < end) {
            sx += va.x; sy += va.y; sz += va.z; sw += va.w;
            qx += va.x * va.x; qy += va.y * va.y; qz += va.z * va.z; qw += va.w * va.w;
            mx = fmaxf(mx, va.x); my = fmaxf(my, va.y); mz = fmaxf(mz, va.z); mw = fmaxf(mw, va.w);
        }
        if (eb < end) {
            sx += vb.x; sy += vb.y; sz += vb.z; sw += vb.w;
            qx += vb.x * vb.x; qy += vb.y * vb.y; qz += vb.z * vb.z; qw += vb.w * vb.w;
            mx = fmaxf(mx, vb.x); my = fmaxf(my, vb.y); mz = fmaxf(mz, vb.z); mw = fmaxf(mw, vb.w);
        }
    }
    // reduce across the 4 groups (lane bits 4,5)
    for (int off = 16; off < 64; off <<= 1) {
        sx += __shfl_xor(sx, off); sy += __shfl_xor(sy, off);
        sz += __shfl_xor(sz, off); sw += __shfl_xor(sw, off);
        qx += __shfl_xor(qx, off); qy += __shfl_xor(qy, off);
        qz += __shfl_xor(qz, off); qw += __shfl_xor(qw, off);
        mx = fmaxf(mx, __shfl_xor(mx, off)); my = fmaxf(my, __shfl_xor(my, off));
        mz = fmaxf(mz, __shfl_xor(mz, off)); mw = fmaxf(mw, __shfl_xor(mw, off));
    }
    float c = (float)(end - beg);
    float rinv = 1.0f / c;
    float mex = sx * rinv, mey = sy * rinv, mez = sz * rinv, mew = sw * rinv;
    float vx = fmaxf(qx * rinv - mex * mex, 0.f);
    float vy = fmaxf(qy * rinv - mey * mey, 0.f);
    float vz = fmaxf(qz * rinv - mez * mez, 0.f);
    float vw = fmaxf(qw * rinv - mew * mew, 0.f);

    float4 o;
    if (grp == 0)      o = make_float4(sx, sy, sz, sw);
    else if (grp == 1) o = make_float4(mx, my, mz, mw);
    else if (grp == 2) o = make_float4(mex, mey, mez, mew);
    else               o = make_float4(vx, vy, vz, vw);
    *(float4*)(aggr + (size_t)node * 256 + grp * 64 + l16 * 4) = o;
}

// ---------------- transpose mlp weights (f32 [64,768] -> f32 [3 chunks][k][o]) ----------------
__global__ void k_wt(const float* __restrict__ w0, const float* __restrict__ w1,
                     const float* __restrict__ w2, float* __restrict__ Wt) {
    int i = blockIdx.x * 256 + threadIdx.x;  // < 3*49152
    if (i >= 3 * 49152) return;
    int l = i / 49152, r = i % 49152;
    const float* w = (l == 0) ? w0 : ((l == 1) ? w1 : w2);
    int o = r / 768, kk = r % 768;
    int c = kk >> 8, k = kk & 255;
    Wt[l * 49152 + c * 16384 + k * 64 + o] = w[r];
}

// ---------------- transpose the six 64x64 MLP weights ----------------
__global__ void k_wsmall(const float* __restrict__ a0, const float* __restrict__ a1,
                         const float* __restrict__ a2, const float* __restrict__ a3,
                         const float* __restrict__ a4, const float* __restrict__ a5,
                         float* __restrict__ Wsm) {
    int i = blockIdx.x * 256 + threadIdx.x;  // < 6*4096
    if (i >= 24576) return;
    int l = i >> 12, r = i & 4095;
    const float* w = (l == 0) ? a0 : (l == 1) ? a1 : (l == 2) ? a2
                   : (l == 3) ? a3 : (l == 4) ? a4 : a5;
    int o = r >> 6, j = r & 63;
    Wsm[l * 4096 + j * 64 + o] = w[r];
}

// ---------------- fused: a = comb@mlpW^T + b ; h = x+a ; Lin2(relu(Lin1(h))) ; relu ; BN partials ----------------
// LDS: As/hs region [k|o][66] x 64 = 4224 floats + 256 tail = 17.9 KB -> 6 blocks/CU.
__global__ __launch_bounds__(256, 6) void k_mlp(
    const float* __restrict__ X, const float* __restrict__ aggr,
    const float* __restrict__ Wt, const float* __restrict__ mlp_b,
    const float* __restrict__ W1t, const float* __restrict__ b1,
    const float* __restrict__ W2t, const float* __restrict__ b2,
    const int* __restrict__ row_ptr,
    float* __restrict__ Y, float* __restrict__ bnstat) {
    __shared__ float lds[4480];
    float* const mbias = lds + 4224;
    float* const b1s = lds + 4288;
    float* const b2s = lds + 4352;
    float* const degs = lds + 4416;

    const int tid = threadIdx.x;
    const int node0 = blockIdx.x * 64;

    if (tid < 64) {
        mbias[tid] = mlp_b[tid];
        b1s[tid] = b1[tid];
        b2s[tid] = b2[tid];
        int node = node0 + tid;
        degs[tid] = (node < NN) ? (float)(row_ptr[node + 1] - row_ptr[node]) : 1.f;
    }

    const int tx = tid & 15, ty = tid >> 4;
    const int o0 = tx * 4, n0 = ty * 4;

    float acc0[16], acc1[16], acc2[16];
#pragma unroll
    for (int i = 0; i < 16; ++i) { acc0[i] = 0.f; acc1[i] = 0.f; acc2[i] = 0.f; }

    for (int qt = 0; qt < 4; ++qt) {
        __syncthreads();
        // stage As[k][n] (transposed) for k in [qt*64, qt*64+64)
#pragma unroll
        for (int m = 0; m < 4; ++m) {
            int i = tid + m * 256;
            int n = i >> 4, kq = (i & 15) * 4;
            int node = node0 + n;
            float4 v = make_float4(0.f, 0.f, 0.f, 0.f);
            if (node < NN) v = *(const float4*)(aggr + (size_t)node * 256 + qt * 64 + kq);
            lds[(kq + 0) * 66 + n] = v.x;
            lds[(kq + 1) * 66 + n] = v.y;
            lds[(kq + 2) * 66 + n] = v.z;
            lds[(kq + 3) * 66 + n] = v.w;
        }
        __syncthreads();
        const float* Wq0 = Wt + qt * 4096;
        const float* Wq1 = Wt + 16384 + qt * 4096;
        const float* Wq2 = Wt + 32768 + qt * 4096;
#pragma unroll 4
        for (int k = 0; k < 64; ++k) {
            const float4 a4 = *(const float4*)&lds[k * 66 + n0];
            const float4 w0 = *(const float4*)(Wq0 + k * 64 + o0);
            const float4 w1v = *(const float4*)(Wq1 + k * 64 + o0);
            const float4 w2v = *(const float4*)(Wq2 + k * 64 + o0);
            const float av[4] = {a4.x, a4.y, a4.z, a4.w};
#pragma unroll
            for (int ni = 0; ni < 4; ++ni) {
                acc0[ni * 4 + 0] += av[ni] * w0.x;  acc0[ni * 4 + 1] += av[ni] * w0.y;
                acc0[ni * 4 + 2] += av[ni] * w0.z;  acc0[ni * 4 + 3] += av[ni] * w0.w;
                acc1[ni * 4 + 0] += av[ni] * w1v.x; acc1[ni * 4 + 1] += av[ni] * w1v.y;
                acc1[ni * 4 + 2] += av[ni] * w1v.z; acc1[ni * 4 + 3] += av[ni] * w1v.w;
                acc2[ni * 4 + 0] += av[ni] * w2v.x; acc2[ni * 4 + 1] += av[ni] * w2v.y;
                acc2[ni * 4 + 2] += av[ni] * w2v.z; acc2[ni * 4 + 3] += av[ni] * w2v.w;
            }
        }
    }
    __syncthreads();

    // h = x + a (stored transposed: lds[o][n])
#pragma unroll
    for (int ni = 0; ni < 4; ++ni) {
        int n = n0 + ni;
        int node = node0 + n;
        float dg = degs[n];
        float c1 = dg * (1.0f / DELTA_F);
        float c2 = DELTA_F / dg;
        float4 xv = make_float4(0.f, 0.f, 0.f, 0.f);
        if (node < NN) xv = *(const float4*)(X + (size_t)node * DD + o0);
        lds[(o0 + 0) * 66 + n] = xv.x + acc0[ni * 4 + 0] + c1 * acc1[ni * 4 + 0] + c2 * acc2[ni * 4 + 0] + mbias[o0 + 0];
        lds[(o0 + 1) * 66 + n] = xv.y + acc0[ni * 4 + 1] + c1 * acc1[ni * 4 + 1] + c2 * acc2[ni * 4 + 1] + mbias[o0 + 1];
        lds[(o0 + 2) * 66 + n] = xv.z + acc0[ni * 4 + 2] + c1 * acc1[ni * 4 + 2] + c2 * acc2[ni * 4 + 2] + mbias[o0 + 2];
        lds[(o0 + 3) * 66 + n] = xv.w + acc0[ni * 4 + 3] + c1 * acc1[ni * 4 + 3] + c2 * acc2[ni * 4 + 3] + mbias[o0 + 3];
    }
    __syncthreads();

    // Lin1: stream W1t from global, a-quads from LDS
    float l1[16];
#pragma unroll
    for (int i = 0; i < 16; ++i) l1[i] = 0.f;
#pragma unroll 4
    for (int j = 0; j < 64; ++j) {
        const float4 a4 = *(const float4*)&lds[j * 66 + n0];
        const float4 wv = *(const float4*)(W1t + j * 64 + o0);
        const float av[4] = {a4.x, a4.y, a4.z, a4.w};
#pragma unroll
        for (int ni = 0; ni < 4; ++ni) {
            l1[ni * 4 + 0] += av[ni] * wv.x; l1[ni * 4 + 1] += av[ni] * wv.y;
            l1[ni * 4 + 2] += av[ni] * wv.z; l1[ni * 4 + 3] += av[ni] * wv.w;
        }
    }
    __syncthreads();
#pragma unroll
    for (int ni = 0; ni < 4; ++ni)
#pragma unroll
        for (int oi = 0; oi < 4; ++oi)
            lds[(o0 + oi) * 66 + n0 + ni] = fmaxf(l1[ni * 4 + oi] + b1s[o0 + oi], 0.f);
    __syncthreads();

    // Lin2 + outer relu
    float l2[16];
#pragma unroll
    for (int i = 0; i < 16; ++i) l2[i] = 0.f;
#pragma unroll 4
    for (int j = 0; j < 64; ++j) {
        const float4 a4 = *(const float4*)&lds[j * 66 + n0];
        const float4 wv = *(const float4*)(W2t + j * 64 + o0);
        const float av[4] = {a4.x, a4.y, a4.z, a4.w};
#pragma unroll
        for (int ni = 0; ni < 4; ++ni) {
            l2[ni * 4 + 0] += av[ni] * wv.x; l2[ni * 4 + 1] += av[ni] * wv.y;
            l2[ni * 4 + 2] += av[ni] * wv.z; l2[ni * 4 + 3] += av[ni] * wv.w;
        }
    }
    __syncthreads();
#pragma unroll
    for (int ni = 0; ni < 4; ++ni) {
        int node = node0 + n0 + ni;
        float4 yv;
        yv.x = fmaxf(l2[ni * 4 + 0] + b2s[o0 + 0], 0.f);
        yv.y = fmaxf(l2[ni * 4 + 1] + b2s[o0 + 1], 0.f);
        yv.z = fmaxf(l2[ni * 4 + 2] + b2s[o0 + 2], 0.f);
        yv.w = fmaxf(l2[ni * 4 + 3] + b2s[o0 + 3], 0.f);
        if (node < NN) *(float4*)(Y + (size_t)node * DD + o0) = yv;
        lds[(o0 + 0) * 66 + n0 + ni] = yv.x;
        lds[(o0 + 1) * 66 + n0 + ni] = yv.y;
        lds[(o0 + 2) * 66 + n0 + ni] = yv.z;
        lds[(o0 + 3) * 66 + n0 + ni] = yv.w;
    }
    __syncthreads();

    // BN partial sums for this tile (feature f = tid)
    if (tid < 64) {
        float s = 0.f, sq = 0.f;
        int lim = NN - node0;
        if (lim > 64) lim = 64;
        for (int n = 0; n < lim; ++n) {
            float v = lds[tid * 66 + n];
            s += v;
            sq += v * v;
        }
        atomicAdd(&bnstat[tid], s);
        atomicAdd(&bnstat[64 + tid], sq);
    }
}

// ---------------- BN finalize: scale/shift per feature ----------------
__global__ void k_bnfin(const float* __restrict__ bs, const float* __restrict__ g,
                        const float* __restrict__ b, float* __restrict__ ss) {
    int f = threadIdx.x;
    if (f < 64) {
        float mean = bs[f] * (1.f / NN);
        float var = fmaxf(bs[64 + f] * (1.f / NN) - mean * mean, 0.f);
        float inv = rsqrtf(var + BN_EPS_F);
        float sc = g[f] * inv;
        ss[f] = sc;
        ss[64 + f] = b[f] - mean * sc;
    }
}

// ---------------- BN apply (+ optional fused global add pool) ----------------
__global__ __launch_bounds__(256) void k_bnapply(const float* __restrict__ Y,
                                                 const float* __restrict__ ss,
                                                 float* __restrict__ XO,
                                                 const int* __restrict__ batch,
                                                 float* __restrict__ gpool, int do_pool) {
    int i = blockIdx.x * 256 + threadIdx.x;  // float4 index
    if (i >= NN * 16) return;
    int n = i >> 4, fq = (i & 15) * 4;
    float4 y = *(const float4*)(Y + (size_t)i * 4);
    float4 sc = *(const float4*)(ss + fq);
    float4 sh = *(const float4*)(ss + 64 + fq);
    float4 r;
    r.x = y.x * sc.x + sh.x;
    r.y = y.y * sc.y + sh.y;
    r.z = y.z * sc.z + sh.z;
    r.w = y.w * sc.w + sh.w;
    *(float4*)(XO + (size_t)i * 4) = r;
    if (do_pool) {
        float* gp = gpool + (size_t)batch[n] * DD + fq;
        atomicAdd(gp + 0, r.x);
        atomicAdd(gp + 1, r.y);
        atomicAdd(gp + 2, r.z);
        atomicAdd(gp + 3, r.w);
    }
}

// ---------------- head: fc1+relu, fc2, log_softmax ----------------
__global__ __launch_bounds__(256) void k_head(const float* __restrict__ gpool,
                                              const float* __restrict__ fc1W, const float* __restrict__ fc1b,
                                              const float* __restrict__ fc2W, const float* __restrict__ fc2b,
                                              float* __restrict__ out) {
    __shared__ float sh[12576];
    float* const gs = sh;
    float* const w1t = sh + 4096;
    float* const z1s = sh + 8256;
    float* const b1s = sh + 12416;
    float* const b2s = sh + 12480;
    float* const w2t = sh;
    float* const z2s = sh + 4096;

    int tid = threadIdx.x;
    for (int i = tid; i < 4096; i += 256) {
        gs[i] = gpool[i];
        int o = i >> 6, j = i & 63;
        w1t[j * 65 + o] = fc1W[i];
    }
    if (tid < 64) b1s[tid] = fc1b[tid];
    if (tid < 32) b2s[tid] = fc2b[tid];
    __syncthreads();
    {
        int tx = tid & 15, ty = tid >> 4, o0 = tx * 4, g0 = ty * 4;
        float acc[16];
#pragma unroll
        for (int i = 0; i < 16; ++i) acc[i] = 0.f;
        for (int j = 0; j < 64; ++j) {
            float w0 = w1t[j * 65 + o0 + 0], w1 = w1t[j * 65 + o0 + 1];
            float w2 = w1t[j * 65 + o0 + 2], w3 = w1t[j * 65 + o0 + 3];
#pragma unroll
            for (int gi = 0; gi < 4; ++gi) {
                float a = gs[(g0 + gi) * 64 + j];
                acc[gi * 4 + 0] += a * w0; acc[gi * 4 + 1] += a * w1;
                acc[gi * 4 + 2] += a * w2; acc[gi * 4 + 3] += a * w3;
            }
        }
        __syncthreads();
#pragma unroll
        for (int gi = 0; gi < 4; ++gi)
#pragma unroll
            for (int oi = 0; oi < 4; ++oi)
                z1s[(g0 + gi) * 65 + o0 + oi] = fmaxf(acc[gi * 4 + oi] + b1s[o0 + oi], 0.f);
    }
    for (int i = tid; i < 2048; i += 256) {
        int o = i >> 6, j = i & 63;
        w2t[j * 33 + o] = fc2W[i];
    }
    __syncthreads();
    {
        int tx = tid & 7, ty = tid >> 3, o0 = tx * 4, g0 = ty * 2;
        float acc[8];
#pragma unroll
        for (int i = 0; i < 8; ++i) acc[i] = 0.f;
        for (int j = 0; j < 64; ++j) {
            float w0 = w2t[j * 33 + o0 + 0], w1 = w2t[j * 33 + o0 + 1];
            float w2 = w2t[j * 33 + o0 + 2], w3 = w2t[j * 33 + o0 + 3];
            float a0 = z1s[(g0 + 0) * 65 + j];
            float a1 = z1s[(g0 + 1) * 65 + j];
            acc[0] += a0 * w0; acc[1] += a0 * w1; acc[2] += a0 * w2; acc[3] += a0 * w3;
            acc[4] += a1 * w0; acc[5] += a1 * w1; acc[6] += a1 * w2; acc[7] += a1 * w3;
        }
#pragma unroll
        for (int gi = 0; gi < 2; ++gi)
#pragma unroll
            for (int oi = 0; oi < 4; ++oi)
                z2s[(g0 + gi) * 33 + o0 + oi] = acc[gi * 4 + oi] + b2s[o0 + oi];
    }
    __syncthreads();
    if (tid < 64) {
        float m = -3.402823466e38f;
        for (int c = 0; c < DOUT; ++c) m = fmaxf(m, z2s[tid * 33 + c]);
        float s = 0.f;
        for (int c = 0; c < DOUT; ++c) s += expf(z2s[tid * 33 + c] - m);
        float lse = m + logf(s);
        for (int c = 0; c < DOUT; ++c)
            out[tid * DOUT + c] = z2s[tid * 33 + c] - lse;
    }
}

extern "C" void kernel_launch(void* const* d_in, const int* in_sizes, int n_in,
                              void* d_out, int out_size, void* d_ws, size_t ws_size,
                              hipStream_t stream) {
    const float* x = (const float*)d_in[0];
    const int* ei = (const int*)d_in[1];
    const int* src = ei;
    const int* dst = ei + NE;
    const int* batch = (const int*)d_in[2];
    const float *mlpW[3], *mlpB[3], *w1[3], *bb1[3], *w2[3], *bb2[3], *bng[3], *bnb[3];
    for (int l = 0; l < 3; ++l) {
        mlpW[l] = (const float*)d_in[3 + 6 * l];
        mlpB[l] = (const float*)d_in[4 + 6 * l];
        w1[l]   = (const float*)d_in[5 + 6 * l];
        bb1[l]  = (const float*)d_in[6 + 6 * l];
        w2[l]   = (const float*)d_in[7 + 6 * l];
        bb2[l]  = (const float*)d_in[8 + 6 * l];
        bng[l]  = (const float*)d_in[21 + 2 * l];
        bnb[l]  = (const float*)d_in[22 + 2 * l];
    }
    const float* fc1W = (const float*)d_in[27];
    const float* fc1b = (const float*)d_in[28];
    const float* fc2W = (const float*)d_in[29];
    const float* fc2b = (const float*)d_in[30];
    float* out = (float*)d_out;

    char* ws = (char*)d_ws;
    size_t off = 0;
    auto alloc = [&](size_t bytes) -> void* {
        void* p = ws + off;
        off = (off + bytes + 511) & ~(size_t)511;
        return p;
    };
    int* counts    = (int*)alloc((size_t)NN * 4);
    int* row_ptr   = (int*)alloc((size_t)(NN + 1) * 4);
    int* cursor    = (int*)alloc((size_t)NN * 4);
    int* blockSums = (int*)alloc(256 * 4);
    int* blockBase = (int*)alloc(256 * 4);
    int* csr_src   = (int*)alloc((size_t)NE * 4);
    float* XB      = (float*)alloc((size_t)NN * DD * 4);
    float* Yb      = (float*)alloc((size_t)NN * DD * 4);
    float* aggr    = (float*)alloc((size_t)NN * 256 * 4);
    float* Wt      = (float*)alloc((size_t)3 * 49152 * 4);
    float* Wsm     = (float*)alloc((size_t)6 * 4096 * 4);
    float* bnstat  = (float*)alloc(384 * 4);
    float* bnss    = (float*)alloc((size_t)3 * 128 * 4);
    float* gpool   = (float*)alloc((size_t)NGRAPH * DD * 4);
    (void)ws_size; (void)in_sizes; (void)n_in; (void)out_size;

    k_init<<<196, 256, 0, stream>>>(counts, bnstat, gpool);
    k_count<<<6250, 256, 0, stream>>>(dst, counts);
    k_scan_a<<<196, 256, 0, stream>>>(counts, blockSums);
    k_scan_b<<<1, 256, 0, stream>>>(blockSums, blockBase);
    k_scan_c<<<196, 256, 0, stream>>>(counts, blockBase, row_ptr, cursor);
    k_fill<<<6250, 256, 0, stream>>>(src, dst, cursor, csr_src);
    k_wt<<<576, 256, 0, stream>>>(mlpW[0], mlpW[1], mlpW[2], Wt);
    k_wsmall<<<96, 256, 0, stream>>>(w1[0], w2[0], w1[1], w2[1], w1[2], w2[2], Wsm);

    const float* Xin = x;
    for (int l = 0; l < 3; ++l) {
        k_agg<<<12500, 256, 0, stream>>>(Xin, row_ptr, csr_src, aggr);
        k_mlp<<<782, 256, 0, stream>>>(Xin, aggr, Wt + (size_t)l * 49152, mlpB[l],
                                       Wsm + (size_t)(2 * l) * 4096, bb1[l],
                                       Wsm + (size_t)(2 * l + 1) * 4096, bb2[l],
                                       row_ptr, Yb, bnstat + l * 128);
        k_bnfin<<<1, 64, 0, stream>>>(bnstat + l * 128, bng[l], bnb[l], bnss + l * 128);
        k_bnapply<<<3125, 256, 0, stream>>>(Yb, bnss + l * 128, XB, batch, gpool,
                                            (l == 2) ? 1 : 0);
        Xin = XB;
    }
    k_head<<<1, 256, 0, stream>>>(gpool, fc1W, fc1b, fc2W, fc2b, out);
}

// Round 4
// 1310.916 us; speedup vs baseline: 1.0737x; 1.0737x over previous
//
#include <hip/hip_runtime.h>

#define NN 50000
#define NE 1600000
#define DD 64
#define NGRAPH 64
#define DOUT 32
#define DELTA_F 2.5749f
#define BN_EPS_F 1e-5f

// ---------------- init: zero counters / bn stats / pool ----------------
__global__ void k_init(int* __restrict__ counts, float* __restrict__ bnstat,
                       float* __restrict__ gpool) {
    int i = blockIdx.x * 256 + threadIdx.x;
    if (i < NN) counts[i] = 0;
    if (i < 384) bnstat[i] = 0.f;
    if (i < NGRAPH * DD) gpool[i] = 0.f;
}

// ---------------- CSR build ----------------
__global__ void k_count(const int* __restrict__ dst, int* __restrict__ counts) {
    int e = blockIdx.x * 256 + threadIdx.x;
    if (e < NE) atomicAdd(&counts[dst[e]], 1);
}

__global__ void k_scan_a(const int* __restrict__ counts, int* __restrict__ blockSums) {
    __shared__ int red[256];
    int tid = threadIdx.x;
    int gid = blockIdx.x * 256 + tid;
    int v = (gid < NN) ? counts[gid] : 0;
    red[tid] = v;
    __syncthreads();
    for (int s = 128; s > 0; s >>= 1) {
        if (tid < s) red[tid] += red[tid + s];
        __syncthreads();
    }
    if (tid == 0) blockSums[blockIdx.x] = red[0];
}

__global__ void k_scan_b(const int* __restrict__ blockSums, int* __restrict__ blockBase) {
    __shared__ int sh[256];
    int tid = threadIdx.x;
    int v = (tid < 196) ? blockSums[tid] : 0;
    sh[tid] = v;
    __syncthreads();
    for (int off = 1; off < 256; off <<= 1) {
        int t = (tid >= off) ? sh[tid - off] : 0;
        __syncthreads();
        sh[tid] += t;
        __syncthreads();
    }
    blockBase[tid] = sh[tid] - v;  // exclusive
}

__global__ void k_scan_c(const int* __restrict__ counts, const int* __restrict__ blockBase,
                         int* __restrict__ row_ptr, int* __restrict__ cursor) {
    __shared__ int sh[256];
    int tid = threadIdx.x;
    int gid = blockIdx.x * 256 + tid;
    int v = (gid < NN) ? counts[gid] : 0;
    sh[tid] = v;
    __syncthreads();
    for (int off = 1; off < 256; off <<= 1) {
        int t = (tid >= off) ? sh[tid - off] : 0;
        __syncthreads();
        sh[tid] += t;
        __syncthreads();
    }
    int excl = blockBase[blockIdx.x] + sh[tid] - v;
    if (gid <= NN) {
        row_ptr[gid] = excl;
        if (gid < NN) cursor[gid] = excl;
    }
}

__global__ void k_fill(const int* __restrict__ src, const int* __restrict__ dst,
                       int* __restrict__ cursor, int* __restrict__ csr_src) {
    int e = blockIdx.x * 256 + threadIdx.x;
    if (e < NE) {
        int d = dst[e];
        int pos = atomicAdd(&cursor[d], 1);
        csr_src[pos] = src[e];
    }
}

// ---------------- transpose mlp weights (f32 [64,768] -> f32 [3 groups][k 256][o 64]) ----------------
__global__ void k_wt(const float* __restrict__ w0, const float* __restrict__ w1,
                     const float* __restrict__ w2, float* __restrict__ Wt) {
    int i = blockIdx.x * 256 + threadIdx.x;  // < 3*49152
    if (i >= 3 * 49152) return;
    int l = i / 49152, r = i % 49152;
    const float* w = (l == 0) ? w0 : ((l == 1) ? w1 : w2);
    int o = r / 768, kk = r % 768;
    int g = kk >> 8, k = kk & 255;
    Wt[l * 49152 + g * 16384 + k * 64 + o] = w[r];
}

// ---------------- transpose the six 64x64 MLP weights ----------------
__global__ void k_wsmall(const float* __restrict__ a0, const float* __restrict__ a1,
                         const float* __restrict__ a2, const float* __restrict__ a3,
                         const float* __restrict__ a4, const float* __restrict__ a5,
                         float* __restrict__ Wsm) {
    int i = blockIdx.x * 256 + threadIdx.x;  // < 6*4096
    if (i >= 24576) return;
    int l = i >> 12, r = i & 4095;
    const float* w = (l == 0) ? a0 : (l == 1) ? a1 : (l == 2) ? a2
                   : (l == 3) ? a3 : (l == 4) ? a4 : a5;
    int o = r >> 6, j = r & 63;
    Wsm[l * 4096 + j * 64 + o] = w[r];
}

// ======================================================================
// Fused: gather+aggregate (sum/max/var directly into LDS tile, transposed)
//        -> a = W·comb (mean folded into s via 1/c epilogue scale)
//        -> h = x + a -> relu(Lin1) -> relu(Lin2) -> Y + BN partials
// LDS: As[192 rows][66 cols] + 4*64 = 12928 floats = 51.7 KB -> 3 blocks/CU.
// ======================================================================
__global__ __launch_bounds__(256, 3) void k_fused(
    const float* __restrict__ X,
    const int* __restrict__ row_ptr, const int* __restrict__ csr_src,
    const float* __restrict__ Wt, const float* __restrict__ mlp_b,
    const float* __restrict__ W1t, const float* __restrict__ b1,
    const float* __restrict__ W2t, const float* __restrict__ b2,
    float* __restrict__ Y, float* __restrict__ bnstat) {
    __shared__ float2 As2[6464];           // 12928 floats
    float* const Asf = (float*)As2;        // row stride 66 floats
    float* const mbias = Asf + 12672;
    float* const b1s = Asf + 12736;
    float* const b2s = Asf + 12800;
    float* const degs = Asf + 12864;

    const int tid = threadIdx.x;
    const int node0 = blockIdx.x * 64;
    const int lane = tid & 63;
    const int wave = tid >> 6;
    const int l16 = lane & 15;
    const int grp = lane >> 4;

    if (tid < 64) {
        mbias[tid] = mlp_b[tid];
        b1s[tid] = b1[tid];
        b2s[tid] = b2[tid];
    }

    // ---- gather phase: each 16-lane group aggregates one node per pass ----
    for (int p = 0; p < 4; ++p) {
        int n = p * 16 + wave * 4 + grp;        // 0..63
        int node = node0 + n;
        float sx = 0.f, sy = 0.f, sz = 0.f, sw = 0.f;
        float qx = 0.f, qy = 0.f, qz = 0.f, qw = 0.f;
        const float NEG = -3.402823466e38f;
        float mx = NEG, my = NEG, mz = NEG, mw = NEG;
        int beg = 0, end = 0;
        if (node < NN) { beg = row_ptr[node]; end = row_ptr[node + 1]; }
        const float* Xq = X + l16 * 4;
        for (int e = beg; e < end; e += 4) {
            int i0 = csr_src[e];
            int i1 = csr_src[(e + 1 < end) ? e + 1 : e];
            int i2 = csr_src[(e + 2 < end) ? e + 2 : e];
            int i3 = csr_src[(e + 3 < end) ? e + 3 : e];
            float4 r0 = *(const float4*)(Xq + (size_t)i0 * DD);
            float4 r1 = *(const float4*)(Xq + (size_t)i1 * DD);
            float4 r2 = *(const float4*)(Xq + (size_t)i2 * DD);
            float4 r3 = *(const float4*)(Xq + (size_t)i3 * DD);
            sx += r0.x; sy += r0.y; sz += r0.z; sw += r0.w;
            qx += r0.x * r0.x; qy += r0.y * r0.y; qz += r0.z * r0.z; qw += r0.w * r0.w;
            mx = fmaxf(mx, r0.x); my = fmaxf(my, r0.y); mz = fmaxf(mz, r0.z); mw = fmaxf(mw, r0.w);
            if (e + 1 < end) {
                sx += r1.x; sy += r1.y; sz += r1.z; sw += r1.w;
                qx += r1.x * r1.x; qy += r1.y * r1.y; qz += r1.z * r1.z; qw += r1.w * r1.w;
                mx = fmaxf(mx, r1.x); my = fmaxf(my, r1.y); mz = fmaxf(mz, r1.z); mw = fmaxf(mw, r1.w);
            }
            if (e + 2 < end) {
                sx += r2.x; sy += r2.y; sz += r2.z; sw += r2.w;
                qx += r2.x * r2.x; qy += r2.y * r2.y; qz += r2.z * r2.z; qw += r2.w * r2.w;
                mx = fmaxf(mx, r2.x); my = fmaxf(my, r2.y); mz = fmaxf(mz, r2.z); mw = fmaxf(mw, r2.w);
            }
            if (e + 3 < end) {
                sx += r3.x; sy += r3.y; sz += r3.z; sw += r3.w;
                qx += r3.x * r3.x; qy += r3.y * r3.y; qz += r3.z * r3.z; qw += r3.w * r3.w;
                mx = fmaxf(mx, r3.x); my = fmaxf(my, r3.y); mz = fmaxf(mz, r3.z); mw = fmaxf(mw, r3.w);
            }
        }
        float c = (node < NN) ? (float)(end - beg) : 1.f;
        float rc = 1.0f / c;
        float mex = sx * rc, mey = sy * rc, mez = sz * rc, mew = sw * rc;
        float vx = fmaxf(qx * rc - mex * mex, 0.f);
        float vy = fmaxf(qy * rc - mey * mey, 0.f);
        float vz = fmaxf(qz * rc - mez * mez, 0.f);
        float vw = fmaxf(qw * rc - mew * mew, 0.f);
        if (node >= NN) { mx = my = mz = mw = 0.f; vx = vy = vz = vw = 0.f; }
        int f = l16 * 4;
        // rows [0,64)=s  [64,128)=max  [128,192)=var ; col n
        Asf[(f + 0) * 66 + n] = sx;  Asf[(f + 1) * 66 + n] = sy;
        Asf[(f + 2) * 66 + n] = sz;  Asf[(f + 3) * 66 + n] = sw;
        Asf[(64 + f + 0) * 66 + n] = mx;  Asf[(64 + f + 1) * 66 + n] = my;
        Asf[(64 + f + 2) * 66 + n] = mz;  Asf[(64 + f + 3) * 66 + n] = mw;
        Asf[(128 + f + 0) * 66 + n] = vx;  Asf[(128 + f + 1) * 66 + n] = vy;
        Asf[(128 + f + 2) * 66 + n] = vz;  Asf[(128 + f + 3) * 66 + n] = vw;
        if (l16 == 0) degs[n] = c;
    }
    __syncthreads();

    // ---- big GEMM: A over 192 rows (s,max,var), B over 64 s-rows (mean W) ----
    const int tx = tid & 15, ty = tid >> 4;
    const int o0 = tx * 4, n0 = ty * 4;
    const float* Wg0 = Wt;
    const float* Wg1 = Wt + 16384;
    const float* Wg2 = Wt + 32768;

    float A0[16], A1[16], A2[16], B0[16], B1[16], B2[16];
#pragma unroll
    for (int i = 0; i < 16; ++i) { A0[i] = 0.f; A1[i] = 0.f; A2[i] = 0.f;
                                   B0[i] = 0.f; B1[i] = 0.f; B2[i] = 0.f; }

    // loop1: k = 0..127 -> W rows k (sum cols 0..63, max cols 64..127)
#pragma unroll 4
    for (int k = 0; k < 128; ++k) {
        float2 a01 = As2[k * 33 + ty * 2];
        float2 a23 = As2[k * 33 + ty * 2 + 1];
        const float av[4] = {a01.x, a01.y, a23.x, a23.y};
        float4 w0 = *(const float4*)(Wg0 + k * 64 + o0);
        float4 w1 = *(const float4*)(Wg1 + k * 64 + o0);
        float4 w2 = *(const float4*)(Wg2 + k * 64 + o0);
#pragma unroll
        for (int ni = 0; ni < 4; ++ni) {
            A0[ni * 4 + 0] += av[ni] * w0.x; A0[ni * 4 + 1] += av[ni] * w0.y;
            A0[ni * 4 + 2] += av[ni] * w0.z; A0[ni * 4 + 3] += av[ni] * w0.w;
            A1[ni * 4 + 0] += av[ni] * w1.x; A1[ni * 4 + 1] += av[ni] * w1.y;
            A1[ni * 4 + 2] += av[ni] * w1.z; A1[ni * 4 + 3] += av[ni] * w1.w;
            A2[ni * 4 + 0] += av[ni] * w2.x; A2[ni * 4 + 1] += av[ni] * w2.y;
            A2[ni * 4 + 2] += av[ni] * w2.z; A2[ni * 4 + 3] += av[ni] * w2.w;
        }
    }
    // loop2: var rows (As rows 128..191) -> W rows 192..255
#pragma unroll 4
    for (int k = 0; k < 64; ++k) {
        float2 a01 = As2[(128 + k) * 33 + ty * 2];
        float2 a23 = As2[(128 + k) * 33 + ty * 2 + 1];
        const float av[4] = {a01.x, a01.y, a23.x, a23.y};
        float4 w0 = *(const float4*)(Wg0 + (192 + k) * 64 + o0);
        float4 w1 = *(const float4*)(Wg1 + (192 + k) * 64 + o0);
        float4 w2 = *(const float4*)(Wg2 + (192 + k) * 64 + o0);
#pragma unroll
        for (int ni = 0; ni < 4; ++ni) {
            A0[ni * 4 + 0] += av[ni] * w0.x; A0[ni * 4 + 1] += av[ni] * w0.y;
            A0[ni * 4 + 2] += av[ni] * w0.z; A0[ni * 4 + 3] += av[ni] * w0.w;
            A1[ni * 4 + 0] += av[ni] * w1.x; A1[ni * 4 + 1] += av[ni] * w1.y;
            A1[ni * 4 + 2] += av[ni] * w1.z; A1[ni * 4 + 3] += av[ni] * w1.w;
            A2[ni * 4 + 0] += av[ni] * w2.x; A2[ni * 4 + 1] += av[ni] * w2.y;
            A2[ni * 4 + 2] += av[ni] * w2.z; A2[ni * 4 + 3] += av[ni] * w2.w;
        }
    }
    // loop3: mean contributions: s rows (0..63) with W rows 128..191
#pragma unroll 4
    for (int k = 0; k < 64; ++k) {
        float2 a01 = As2[k * 33 + ty * 2];
        float2 a23 = As2[k * 33 + ty * 2 + 1];
        const float av[4] = {a01.x, a01.y, a23.x, a23.y};
        float4 w0 = *(const float4*)(Wg0 + (128 + k) * 64 + o0);
        float4 w1 = *(const float4*)(Wg1 + (128 + k) * 64 + o0);
        float4 w2 = *(const float4*)(Wg2 + (128 + k) * 64 + o0);
#pragma unroll
        for (int ni = 0; ni < 4; ++ni) {
            B0[ni * 4 + 0] += av[ni] * w0.x; B0[ni * 4 + 1] += av[ni] * w0.y;
            B0[ni * 4 + 2] += av[ni] * w0.z; B0[ni * 4 + 3] += av[ni] * w0.w;
            B1[ni * 4 + 0] += av[ni] * w1.x; B1[ni * 4 + 1] += av[ni] * w1.y;
            B1[ni * 4 + 2] += av[ni] * w1.z; B1[ni * 4 + 3] += av[ni] * w1.w;
            B2[ni * 4 + 0] += av[ni] * w2.x; B2[ni * 4 + 1] += av[ni] * w2.y;
            B2[ni * 4 + 2] += av[ni] * w2.z; B2[ni * 4 + 3] += av[ni] * w2.w;
        }
    }
    __syncthreads();  // done reading As region

    // h = x + a (stored transposed: Asf[o][n], rows 0..63)
#pragma unroll
    for (int ni = 0; ni < 4; ++ni) {
        int n = n0 + ni;
        int node = node0 + n;
        float dg = degs[n];
        float rc = 1.0f / dg;
        float cA1 = dg * (1.0f / DELTA_F);
        float cA2 = DELTA_F * rc;
        float cB1 = (1.0f / DELTA_F);
        float cB2 = DELTA_F * rc * rc;
        float4 xv = make_float4(0.f, 0.f, 0.f, 0.f);
        if (node < NN) xv = *(const float4*)(X + (size_t)node * DD + o0);
#pragma unroll
        for (int oi = 0; oi < 4; ++oi) {
            int ii = ni * 4 + oi;
            float xa = (oi == 0) ? xv.x : (oi == 1) ? xv.y : (oi == 2) ? xv.z : xv.w;
            Asf[(o0 + oi) * 66 + n] =
                xa + A0[ii] + cA1 * A1[ii] + cA2 * A2[ii]
                   + rc * B0[ii] + cB1 * B1[ii] + cB2 * B2[ii] + mbias[o0 + oi];
        }
    }
    __syncthreads();

    // Lin1: stream W1t from global, h-quads from LDS
    float l1[16];
#pragma unroll
    for (int i = 0; i < 16; ++i) l1[i] = 0.f;
#pragma unroll 4
    for (int j = 0; j < 64; ++j) {
        float2 a01 = As2[j * 33 + ty * 2];
        float2 a23 = As2[j * 33 + ty * 2 + 1];
        const float av[4] = {a01.x, a01.y, a23.x, a23.y};
        const float4 wv = *(const float4*)(W1t + j * 64 + o0);
#pragma unroll
        for (int ni = 0; ni < 4; ++ni) {
            l1[ni * 4 + 0] += av[ni] * wv.x; l1[ni * 4 + 1] += av[ni] * wv.y;
            l1[ni * 4 + 2] += av[ni] * wv.z; l1[ni * 4 + 3] += av[ni] * wv.w;
        }
    }
    __syncthreads();
#pragma unroll
    for (int ni = 0; ni < 4; ++ni)
#pragma unroll
        for (int oi = 0; oi < 4; ++oi)
            Asf[(o0 + oi) * 66 + n0 + ni] = fmaxf(l1[ni * 4 + oi] + b1s[o0 + oi], 0.f);
    __syncthreads();

    // Lin2 + outer relu
    float l2[16];
#pragma unroll
    for (int i = 0; i < 16; ++i) l2[i] = 0.f;
#pragma unroll 4
    for (int j = 0; j < 64; ++j) {
        float2 a01 = As2[j * 33 + ty * 2];
        float2 a23 = As2[j * 33 + ty * 2 + 1];
        const float av[4] = {a01.x, a01.y, a23.x, a23.y};
        const float4 wv = *(const float4*)(W2t + j * 64 + o0);
#pragma unroll
        for (int ni = 0; ni < 4; ++ni) {
            l2[ni * 4 + 0] += av[ni] * wv.x; l2[ni * 4 + 1] += av[ni] * wv.y;
            l2[ni * 4 + 2] += av[ni] * wv.z; l2[ni * 4 + 3] += av[ni] * wv.w;
        }
    }
    __syncthreads();
#pragma unroll
    for (int ni = 0; ni < 4; ++ni) {
        int node = node0 + n0 + ni;
        float4 yv;
        yv.x = fmaxf(l2[ni * 4 + 0] + b2s[o0 + 0], 0.f);
        yv.y = fmaxf(l2[ni * 4 + 1] + b2s[o0 + 1], 0.f);
        yv.z = fmaxf(l2[ni * 4 + 2] + b2s[o0 + 2], 0.f);
        yv.w = fmaxf(l2[ni * 4 + 3] + b2s[o0 + 3], 0.f);
        if (node < NN) *(float4*)(Y + (size_t)node * DD + o0) = yv;
        Asf[(o0 + 0) * 66 + n0 + ni] = yv.x;
        Asf[(o0 + 1) * 66 + n0 + ni] = yv.y;
        Asf[(o0 + 2) * 66 + n0 + ni] = yv.z;
        Asf[(o0 + 3) * 66 + n0 + ni] = yv.w;
    }
    __syncthreads();

    // BN partial sums for this tile (feature f = tid)
    if (tid < 64) {
        float s = 0.f, sq = 0.f;
        int lim = NN - node0;
        if (lim > 64) lim = 64;
        for (int n = 0; n < lim; ++n) {
            float v = Asf[tid * 66 + n];
            s += v;
            sq += v * v;
        }
        atomicAdd(&bnstat[tid], s);
        atomicAdd(&bnstat[64 + tid], sq);
    }
}

// ---------------- BN finalize: scale/shift per feature ----------------
__global__ void k_bnfin(const float* __restrict__ bs, const float* __restrict__ g,
                        const float* __restrict__ b, float* __restrict__ ss) {
    int f = threadIdx.x;
    if (f < 64) {
        float mean = bs[f] * (1.f / NN);
        float var = fmaxf(bs[64 + f] * (1.f / NN) - mean * mean, 0.f);
        float inv = rsqrtf(var + BN_EPS_F);
        float sc = g[f] * inv;
        ss[f] = sc;
        ss[64 + f] = b[f] - mean * sc;
    }
}

// ---------------- BN apply (+ optional fused global add pool) ----------------
__global__ __launch_bounds__(256) void k_bnapply(const float* __restrict__ Y,
                                                 const float* __restrict__ ss,
                                                 float* __restrict__ XO,
                                                 const int* __restrict__ batch,
                                                 float* __restrict__ gpool, int do_pool) {
    int i = blockIdx.x * 256 + threadIdx.x;  // float4 index
    if (i >= NN * 16) return;
    int n = i >> 4, fq = (i & 15) * 4;
    float4 y = *(const float4*)(Y + (size_t)i * 4);
    float4 sc = *(const float4*)(ss + fq);
    float4 sh = *(const float4*)(ss + 64 + fq);
    float4 r;
    r.x = y.x * sc.x + sh.x;
    r.y = y.y * sc.y + sh.y;
    r.z = y.z * sc.z + sh.z;
    r.w = y.w * sc.w + sh.w;
    *(float4*)(XO + (size_t)i * 4) = r;
    if (do_pool) {
        float* gp = gpool + (size_t)batch[n] * DD + fq;
        atomicAdd(gp + 0, r.x);
        atomicAdd(gp + 1, r.y);
        atomicAdd(gp + 2, r.z);
        atomicAdd(gp + 3, r.w);
    }
}

// ---------------- head: fc1+relu, fc2, log_softmax ----------------
__global__ __launch_bounds__(256) void k_head(const float* __restrict__ gpool,
                                              const float* __restrict__ fc1W, const float* __restrict__ fc1b,
                                              const float* __restrict__ fc2W, const float* __restrict__ fc2b,
                                              float* __restrict__ out) {
    __shared__ float sh[12576];
    float* const gs = sh;
    float* const w1t = sh + 4096;
    float* const z1s = sh + 8256;
    float* const b1s = sh + 12416;
    float* const b2s = sh + 12480;
    float* const w2t = sh;
    float* const z2s = sh + 4096;

    int tid = threadIdx.x;
    for (int i = tid; i < 4096; i += 256) {
        gs[i] = gpool[i];
        int o = i >> 6, j = i & 63;
        w1t[j * 65 + o] = fc1W[i];
    }
    if (tid < 64) b1s[tid] = fc1b[tid];
    if (tid < 32) b2s[tid] = fc2b[tid];
    __syncthreads();
    {
        int tx = tid & 15, ty = tid >> 4, o0 = tx * 4, g0 = ty * 4;
        float acc[16];
#pragma unroll
        for (int i = 0; i < 16; ++i) acc[i] = 0.f;
        for (int j = 0; j < 64; ++j) {
            float w0 = w1t[j * 65 + o0 + 0], w1 = w1t[j * 65 + o0 + 1];
            float w2 = w1t[j * 65 + o0 + 2], w3 = w1t[j * 65 + o0 + 3];
#pragma unroll
            for (int gi = 0; gi < 4; ++gi) {
                float a = gs[(g0 + gi) * 64 + j];
                acc[gi * 4 + 0] += a * w0; acc[gi * 4 + 1] += a * w1;
                acc[gi * 4 + 2] += a * w2; acc[gi * 4 + 3] += a * w3;
            }
        }
        __syncthreads();
#pragma unroll
        for (int gi = 0; gi < 4; ++gi)
#pragma unroll
            for (int oi = 0; oi < 4; ++oi)
                z1s[(g0 + gi) * 65 + o0 + oi] = fmaxf(acc[gi * 4 + oi] + b1s[o0 + oi], 0.f);
    }
    for (int i = tid; i < 2048; i += 256) {
        int o = i >> 6, j = i & 63;
        w2t[j * 33 + o] = fc2W[i];
    }
    __syncthreads();
    {
        int tx = tid & 7, ty = tid >> 3, o0 = tx * 4, g0 = ty * 2;
        float acc[8];
#pragma unroll
        for (int i = 0; i < 8; ++i) acc[i] = 0.f;
        for (int j = 0; j < 64; ++j) {
            float w0 = w2t[j * 33 + o0 + 0], w1 = w2t[j * 33 + o0 + 1];
            float w2 = w2t[j * 33 + o0 + 2], w3 = w2t[j * 33 + o0 + 3];
            float a0 = z1s[(g0 + 0) * 65 + j];
            float a1 = z1s[(g0 + 1) * 65 + j];
            acc[0] += a0 * w0; acc[1] += a0 * w1; acc[2] += a0 * w2; acc[3] += a0 * w3;
            acc[4] += a1 * w0; acc[5] += a1 * w1; acc[6] += a1 * w2; acc[7] += a1 * w3;
        }
#pragma unroll
        for (int gi = 0; gi < 2; ++gi)
#pragma unroll
            for (int oi = 0; oi < 4; ++oi)
                z2s[(g0 + gi) * 33 + o0 + oi] = acc[gi * 4 + oi] + b2s[o0 + oi];
    }
    __syncthreads();
    if (tid < 64) {
        float m = -3.402823466e38f;
        for (int c = 0; c < DOUT; ++c) m = fmaxf(m, z2s[tid * 33 + c]);
        float s = 0.f;
        for (int c = 0; c < DOUT; ++c) s += expf(z2s[tid * 33 + c] - m);
        float lse = m + logf(s);
        for (int c = 0; c < DOUT; ++c)
            out[tid * DOUT + c] = z2s[tid * 33 + c] - lse;
    }
}

extern "C" void kernel_launch(void* const* d_in, const int* in_sizes, int n_in,
                              void* d_out, int out_size, void* d_ws, size_t ws_size,
                              hipStream_t stream) {
    const float* x = (const float*)d_in[0];
    const int* ei = (const int*)d_in[1];
    const int* src = ei;
    const int* dst = ei + NE;
    const int* batch = (const int*)d_in[2];
    const float *mlpW[3], *mlpB[3], *w1[3], *bb1[3], *w2[3], *bb2[3], *bng[3], *bnb[3];
    for (int l = 0; l < 3; ++l) {
        mlpW[l] = (const float*)d_in[3 + 6 * l];
        mlpB[l] = (const float*)d_in[4 + 6 * l];
        w1[l]   = (const float*)d_in[5 + 6 * l];
        bb1[l]  = (const float*)d_in[6 + 6 * l];
        w2[l]   = (const float*)d_in[7 + 6 * l];
        bb2[l]  = (const float*)d_in[8 + 6 * l];
        bng[l]  = (const float*)d_in[21 + 2 * l];
        bnb[l]  = (const float*)d_in[22 + 2 * l];
    }
    const float* fc1W = (const float*)d_in[27];
    const float* fc1b = (const float*)d_in[28];
    const float* fc2W = (const float*)d_in[29];
    const float* fc2b = (const float*)d_in[30];
    float* out = (float*)d_out;

    char* ws = (char*)d_ws;
    size_t off = 0;
    auto alloc = [&](size_t bytes) -> void* {
        void* p = ws + off;
        off = (off + bytes + 511) & ~(size_t)511;
        return p;
    };
    int* counts    = (int*)alloc((size_t)NN * 4);
    int* row_ptr   = (int*)alloc((size_t)(NN + 1) * 4);
    int* cursor    = (int*)alloc((size_t)NN * 4);
    int* blockSums = (int*)alloc(256 * 4);
    int* blockBase = (int*)alloc(256 * 4);
    int* csr_src   = (int*)alloc((size_t)NE * 4);
    float* XB      = (float*)alloc((size_t)NN * DD * 4);
    float* Yb      = (float*)alloc((size_t)NN * DD * 4);
    float* Wt      = (float*)alloc((size_t)3 * 49152 * 4);
    float* Wsm     = (float*)alloc((size_t)6 * 4096 * 4);
    float* bnstat  = (float*)alloc(384 * 4);
    float* bnss    = (float*)alloc((size_t)3 * 128 * 4);
    float* gpool   = (float*)alloc((size_t)NGRAPH * DD * 4);
    (void)ws_size; (void)in_sizes; (void)n_in; (void)out_size;

    k_init<<<196, 256, 0, stream>>>(counts, bnstat, gpool);
    k_count<<<6250, 256, 0, stream>>>(dst, counts);
    k_scan_a<<<196, 256, 0, stream>>>(counts, blockSums);
    k_scan_b<<<1, 256, 0, stream>>>(blockSums, blockBase);
    k_scan_c<<<196, 256, 0, stream>>>(counts, blockBase, row_ptr, cursor);
    k_fill<<<6250, 256, 0, stream>>>(src, dst, cursor, csr_src);
    k_wt<<<576, 256, 0, stream>>>(mlpW[0], mlpW[1], mlpW[2], Wt);
    k_wsmall<<<96, 256, 0, stream>>>(w1[0], w2[0], w1[1], w2[1], w1[2], w2[2], Wsm);

    const float* Xin = x;
    for (int l = 0; l < 3; ++l) {
        k_fused<<<782, 256, 0, stream>>>(Xin, row_ptr, csr_src,
                                         Wt + (size_t)l * 49152, mlpB[l],
                                         Wsm + (size_t)(2 * l) * 4096, bb1[l],
                                         Wsm + (size_t)(2 * l + 1) * 4096, bb2[l],
                                         Yb, bnstat + l * 128);
        k_bnfin<<<1, 64, 0, stream>>>(bnstat + l * 128, bng[l], bnb[l], bnss + l * 128);
        k_bnapply<<<3125, 256, 0, stream>>>(Yb, bnss + l * 128, XB, batch, gpool,
                                            (l == 2) ? 1 : 0);
        Xin = XB;
    }
    k_head<<<1, 256, 0, stream>>>(gpool, fc1W, fc1b, fc2W, fc2b, out);
}

// Round 5
// 1051.659 us; speedup vs baseline: 1.3384x; 1.2465x over previous
//
#include <hip/hip_runtime.h>

#define NN 50000
#define NE 1600000
#define DD 64
#define NGRAPH 64
#define DOUT 32
#define DELTA_F 2.5749f
#define BN_EPS_F 1e-5f

typedef unsigned short ushort;

static __device__ __forceinline__ float bu2f(ushort u) {
    return __uint_as_float(((unsigned)u) << 16);
}
static __device__ __forceinline__ ushort f2bu(float f) {
    unsigned u = __float_as_uint(f);
    unsigned r = (u + 0x7FFF + ((u >> 16) & 1)) >> 16;   // round-to-nearest-even
    return (ushort)r;
}

// ---------------- init: zero counters / bn stats / pool ----------------
__global__ void k_init(int* __restrict__ counts, float* __restrict__ bnstat,
                       float* __restrict__ gpool) {
    int i = blockIdx.x * 256 + threadIdx.x;
    if (i < NN) counts[i] = 0;
    if (i < 384) bnstat[i] = 0.f;
    if (i < NGRAPH * DD) gpool[i] = 0.f;
}

// ---------------- CSR build ----------------
__global__ void k_count(const int* __restrict__ dst, int* __restrict__ counts) {
    int e = blockIdx.x * 256 + threadIdx.x;
    if (e < NE) atomicAdd(&counts[dst[e]], 1);
}

__global__ void k_scan_a(const int* __restrict__ counts, int* __restrict__ blockSums) {
    __shared__ int red[256];
    int tid = threadIdx.x;
    int gid = blockIdx.x * 256 + tid;
    int v = (gid < NN) ? counts[gid] : 0;
    red[tid] = v;
    __syncthreads();
    for (int s = 128; s > 0; s >>= 1) {
        if (tid < s) red[tid] += red[tid + s];
        __syncthreads();
    }
    if (tid == 0) blockSums[blockIdx.x] = red[0];
}

__global__ void k_scan_b(const int* __restrict__ blockSums, int* __restrict__ blockBase) {
    __shared__ int sh[256];
    int tid = threadIdx.x;
    int v = (tid < 196) ? blockSums[tid] : 0;
    sh[tid] = v;
    __syncthreads();
    for (int off = 1; off < 256; off <<= 1) {
        int t = (tid >= off) ? sh[tid - off] : 0;
        __syncthreads();
        sh[tid] += t;
        __syncthreads();
    }
    blockBase[tid] = sh[tid] - v;  // exclusive
}

__global__ void k_scan_c(const int* __restrict__ counts, const int* __restrict__ blockBase,
                         int* __restrict__ row_ptr, int* __restrict__ cursor) {
    __shared__ int sh[256];
    int tid = threadIdx.x;
    int gid = blockIdx.x * 256 + tid;
    int v = (gid < NN) ? counts[gid] : 0;
    sh[tid] = v;
    __syncthreads();
    for (int off = 1; off < 256; off <<= 1) {
        int t = (tid >= off) ? sh[tid - off] : 0;
        __syncthreads();
        sh[tid] += t;
        __syncthreads();
    }
    int excl = blockBase[blockIdx.x] + sh[tid] - v;
    if (gid <= NN) {
        row_ptr[gid] = excl;
        if (gid < NN) cursor[gid] = excl;
    }
}

__global__ void k_fill(const int* __restrict__ src, const int* __restrict__ dst,
                       int* __restrict__ cursor, int* __restrict__ csr_src) {
    int e = blockIdx.x * 256 + threadIdx.x;
    if (e < NE) {
        int d = dst[e];
        int pos = atomicAdd(&cursor[d], 1);
        csr_src[pos] = src[e];
    }
}

// ---------------- weight prep: big transpose + six 64x64 transposes ----------------
__global__ void k_wprep(const float* __restrict__ w0, const float* __restrict__ w1,
                        const float* __restrict__ w2,
                        const float* __restrict__ a0, const float* __restrict__ a1,
                        const float* __restrict__ a2, const float* __restrict__ a3,
                        const float* __restrict__ a4, const float* __restrict__ a5,
                        float* __restrict__ Wt, float* __restrict__ Wsm) {
    int i = blockIdx.x * 256 + threadIdx.x;
    if (i < 3 * 49152) {
        int l = i / 49152, r = i % 49152;
        const float* w = (l == 0) ? w0 : ((l == 1) ? w1 : w2);
        int o = r / 768, kk = r % 768;
        int g = kk >> 8, k = kk & 255;
        Wt[l * 49152 + g * 16384 + k * 64 + o] = w[r];
    } else if (i < 3 * 49152 + 6 * 4096) {
        int r2 = i - 3 * 49152;
        int l = r2 >> 12, r = r2 & 4095;
        const float* w = (l == 0) ? a0 : (l == 1) ? a1 : (l == 2) ? a2
                       : (l == 3) ? a3 : (l == 4) ? a4 : a5;
        int o = r >> 6, j = r & 63;
        Wsm[l * 4096 + j * 64 + o] = w[r];
    }
}

// ---------------- x (f32) -> bf16 gather table ----------------
__global__ void k_x2h(const float* __restrict__ x, ushort* __restrict__ XH) {
    int i = blockIdx.x * 256 + threadIdx.x;
    if (i < NN * 16) {
        float4 v = *(const float4*)(x + (size_t)i * 4);
        ushort4 h;
        h.x = f2bu(v.x); h.y = f2bu(v.y); h.z = f2bu(v.z); h.w = f2bu(v.w);
        *(ushort4*)(XH + (size_t)i * 4) = h;
    }
}

// ======================================================================
// Fused: gather+aggregate (bf16 rows, sum/max/var into LDS tile, transposed)
//        -> a = W·comb (mean folded into s via 1/c epilogue scale)
//        -> h = x + a -> relu(Lin1) -> relu(Lin2) -> Y + BN partials
// LDS: As[192 rows][66 cols] + 4*64 = 12928 floats = 51.7 KB -> 3 blocks/CU.
// ======================================================================
__global__ __launch_bounds__(256, 3) void k_fused(
    const float* __restrict__ X, const ushort* __restrict__ XH,
    const int* __restrict__ row_ptr, const int* __restrict__ csr_src,
    const float* __restrict__ Wt, const float* __restrict__ mlp_b,
    const float* __restrict__ W1t, const float* __restrict__ b1,
    const float* __restrict__ W2t, const float* __restrict__ b2,
    float* __restrict__ Y, float* __restrict__ bnstat) {
    __shared__ float2 As2[6464];           // 12928 floats
    float* const Asf = (float*)As2;        // row stride 66 floats
    float* const mbias = Asf + 12672;
    float* const b1s = Asf + 12736;
    float* const b2s = Asf + 12800;
    float* const degs = Asf + 12864;

    const int tid = threadIdx.x;
    const int node0 = blockIdx.x * 64;
    const int lane = tid & 63;
    const int wave = tid >> 6;
    const int l16 = lane & 15;
    const int grp = lane >> 4;

    if (tid < 64) {
        mbias[tid] = mlp_b[tid];
        b1s[tid] = b1[tid];
        b2s[tid] = b2[tid];
    }

    const ushort* Xrow = XH + l16 * 4;     // + idx*64

    // ---- gather phase: each 16-lane group aggregates one node per pass ----
    for (int p = 0; p < 4; ++p) {
        int n = p * 16 + wave * 4 + grp;        // 0..63
        int node = node0 + n;
        float sx = 0.f, sy = 0.f, sz = 0.f, sw = 0.f;
        float qx = 0.f, qy = 0.f, qz = 0.f, qw = 0.f;
        const float NEG = -3.402823466e38f;
        float mx = NEG, my = NEG, mz = NEG, mw = NEG;
        int beg = 0, end = 0;
        if (node < NN) { beg = row_ptr[node]; end = row_ptr[node + 1]; }

        int e = beg;
        int c0 = 0, c1 = 0, c2 = 0, c3 = 0;
        if (e < end) {
            c0 = csr_src[e];
            c1 = csr_src[(e + 1 < end) ? e + 1 : beg];
            c2 = csr_src[(e + 2 < end) ? e + 2 : beg];
            c3 = csr_src[(e + 3 < end) ? e + 3 : beg];
        }
        while (e < end) {
            int en = e + 4;
            int b0v = c0, b1v = c1, b2v = c2, b3v = c3;
            if (en < end) {                       // prefetch next batch of indices
                c0 = csr_src[en];
                c1 = csr_src[(en + 1 < end) ? en + 1 : beg];
                c2 = csr_src[(en + 2 < end) ? en + 2 : beg];
                c3 = csr_src[(en + 3 < end) ? en + 3 : beg];
            }
            ushort4 r0 = *(const ushort4*)(Xrow + (size_t)b0v * 64);
            ushort4 r1 = *(const ushort4*)(Xrow + (size_t)b1v * 64);
            ushort4 r2 = *(const ushort4*)(Xrow + (size_t)b2v * 64);
            ushort4 r3 = *(const ushort4*)(Xrow + (size_t)b3v * 64);
            {
                float x0 = bu2f(r0.x), x1 = bu2f(r0.y), x2 = bu2f(r0.z), x3 = bu2f(r0.w);
                sx += x0; sy += x1; sz += x2; sw += x3;
                qx += x0 * x0; qy += x1 * x1; qz += x2 * x2; qw += x3 * x3;
                mx = fmaxf(mx, x0); my = fmaxf(my, x1); mz = fmaxf(mz, x2); mw = fmaxf(mw, x3);
            }
            if (e + 1 < end) {
                float x0 = bu2f(r1.x), x1 = bu2f(r1.y), x2 = bu2f(r1.z), x3 = bu2f(r1.w);
                sx += x0; sy += x1; sz += x2; sw += x3;
                qx += x0 * x0; qy += x1 * x1; qz += x2 * x2; qw += x3 * x3;
                mx = fmaxf(mx, x0); my = fmaxf(my, x1); mz = fmaxf(mz, x2); mw = fmaxf(mw, x3);
            }
            if (e + 2 < end) {
                float x0 = bu2f(r2.x), x1 = bu2f(r2.y), x2 = bu2f(r2.z), x3 = bu2f(r2.w);
                sx += x0; sy += x1; sz += x2; sw += x3;
                qx += x0 * x0; qy += x1 * x1; qz += x2 * x2; qw += x3 * x3;
                mx = fmaxf(mx, x0); my = fmaxf(my, x1); mz = fmaxf(mz, x2); mw = fmaxf(mw, x3);
            }
            if (e + 3 < end) {
                float x0 = bu2f(r3.x), x1 = bu2f(r3.y), x2 = bu2f(r3.z), x3 = bu2f(r3.w);
                sx += x0; sy += x1; sz += x2; sw += x3;
                qx += x0 * x0; qy += x1 * x1; qz += x2 * x2; qw += x3 * x3;
                mx = fmaxf(mx, x0); my = fmaxf(my, x1); mz = fmaxf(mz, x2); mw = fmaxf(mw, x3);
            }
            e = en;
        }
        float c = (node < NN) ? (float)(end - beg) : 1.f;
        float rc = 1.0f / c;
        float mex = sx * rc, mey = sy * rc, mez = sz * rc, mew = sw * rc;
        float vx = fmaxf(qx * rc - mex * mex, 0.f);
        float vy = fmaxf(qy * rc - mey * mey, 0.f);
        float vz = fmaxf(qz * rc - mez * mez, 0.f);
        float vw = fmaxf(qw * rc - mew * mew, 0.f);
        if (node >= NN) { mx = my = mz = mw = 0.f; vx = vy = vz = vw = 0.f; }
        int f = l16 * 4;
        // rows [0,64)=s  [64,128)=max  [128,192)=var ; col n
        Asf[(f + 0) * 66 + n] = sx;  Asf[(f + 1) * 66 + n] = sy;
        Asf[(f + 2) * 66 + n] = sz;  Asf[(f + 3) * 66 + n] = sw;
        Asf[(64 + f + 0) * 66 + n] = mx;  Asf[(64 + f + 1) * 66 + n] = my;
        Asf[(64 + f + 2) * 66 + n] = mz;  Asf[(64 + f + 3) * 66 + n] = mw;
        Asf[(128 + f + 0) * 66 + n] = vx;  Asf[(128 + f + 1) * 66 + n] = vy;
        Asf[(128 + f + 2) * 66 + n] = vz;  Asf[(128 + f + 3) * 66 + n] = vw;
        if (l16 == 0) degs[n] = c;
    }
    __syncthreads();

    // ---- big GEMM: A over 192 rows (s,max,var), B over 64 s-rows (mean W) ----
    const int tx = tid & 15, ty = tid >> 4;
    const int o0 = tx * 4, n0 = ty * 4;
    const float* Wg0 = Wt;
    const float* Wg1 = Wt + 16384;
    const float* Wg2 = Wt + 32768;

    float A0[16], A1[16], A2[16], B0[16], B1[16], B2[16];
#pragma unroll
    for (int i = 0; i < 16; ++i) { A0[i] = 0.f; A1[i] = 0.f; A2[i] = 0.f;
                                   B0[i] = 0.f; B1[i] = 0.f; B2[i] = 0.f; }

    // loop1: k = 0..127 -> W rows k (sum cols 0..63, max cols 64..127)
#pragma unroll 4
    for (int k = 0; k < 128; ++k) {
        float2 a01 = As2[k * 33 + ty * 2];
        float2 a23 = As2[k * 33 + ty * 2 + 1];
        const float av[4] = {a01.x, a01.y, a23.x, a23.y};
        float4 w0 = *(const float4*)(Wg0 + k * 64 + o0);
        float4 w1 = *(const float4*)(Wg1 + k * 64 + o0);
        float4 w2 = *(const float4*)(Wg2 + k * 64 + o0);
#pragma unroll
        for (int ni = 0; ni < 4; ++ni) {
            A0[ni * 4 + 0] += av[ni] * w0.x; A0[ni * 4 + 1] += av[ni] * w0.y;
            A0[ni * 4 + 2] += av[ni] * w0.z; A0[ni * 4 + 3] += av[ni] * w0.w;
            A1[ni * 4 + 0] += av[ni] * w1.x; A1[ni * 4 + 1] += av[ni] * w1.y;
            A1[ni * 4 + 2] += av[ni] * w1.z; A1[ni * 4 + 3] += av[ni] * w1.w;
            A2[ni * 4 + 0] += av[ni] * w2.x; A2[ni * 4 + 1] += av[ni] * w2.y;
            A2[ni * 4 + 2] += av[ni] * w2.z; A2[ni * 4 + 3] += av[ni] * w2.w;
        }
    }
    // loop2: var rows (As rows 128..191) -> W rows 192..255
#pragma unroll 4
    for (int k = 0; k < 64; ++k) {
        float2 a01 = As2[(128 + k) * 33 + ty * 2];
        float2 a23 = As2[(128 + k) * 33 + ty * 2 + 1];
        const float av[4] = {a01.x, a01.y, a23.x, a23.y};
        float4 w0 = *(const float4*)(Wg0 + (192 + k) * 64 + o0);
        float4 w1 = *(const float4*)(Wg1 + (192 + k) * 64 + o0);
        float4 w2 = *(const float4*)(Wg2 + (192 + k) * 64 + o0);
#pragma unroll
        for (int ni = 0; ni < 4; ++ni) {
            A0[ni * 4 + 0] += av[ni] * w0.x; A0[ni * 4 + 1] += av[ni] * w0.y;
            A0[ni * 4 + 2] += av[ni] * w0.z; A0[ni * 4 + 3] += av[ni] * w0.w;
            A1[ni * 4 + 0] += av[ni] * w1.x; A1[ni * 4 + 1] += av[ni] * w1.y;
            A1[ni * 4 + 2] += av[ni] * w1.z; A1[ni * 4 + 3] += av[ni] * w1.w;
            A2[ni * 4 + 0] += av[ni] * w2.x; A2[ni * 4 + 1] += av[ni] * w2.y;
            A2[ni * 4 + 2] += av[ni] * w2.z; A2[ni * 4 + 3] += av[ni] * w2.w;
        }
    }
    // loop3: mean contributions: s rows (0..63) with W rows 128..191
#pragma unroll 4
    for (int k = 0; k < 64; ++k) {
        float2 a01 = As2[k * 33 + ty * 2];
        float2 a23 = As2[k * 33 + ty * 2 + 1];
        const float av[4] = {a01.x, a01.y, a23.x, a23.y};
        float4 w0 = *(const float4*)(Wg0 + (128 + k) * 64 + o0);
        float4 w1 = *(const float4*)(Wg1 + (128 + k) * 64 + o0);
        float4 w2 = *(const float4*)(Wg2 + (128 + k) * 64 + o0);
#pragma unroll
        for (int ni = 0; ni < 4; ++ni) {
            B0[ni * 4 + 0] += av[ni] * w0.x; B0[ni * 4 + 1] += av[ni] * w0.y;
            B0[ni * 4 + 2] += av[ni] * w0.z; B0[ni * 4 + 3] += av[ni] * w0.w;
            B1[ni * 4 + 0] += av[ni] * w1.x; B1[ni * 4 + 1] += av[ni] * w1.y;
            B1[ni * 4 + 2] += av[ni] * w1.z; B1[ni * 4 + 3] += av[ni] * w1.w;
            B2[ni * 4 + 0] += av[ni] * w2.x; B2[ni * 4 + 1] += av[ni] * w2.y;
            B2[ni * 4 + 2] += av[ni] * w2.z; B2[ni * 4 + 3] += av[ni] * w2.w;
        }
    }
    __syncthreads();  // done reading As region

    // h = x + a (stored transposed: Asf[o][n], rows 0..63)
#pragma unroll
    for (int ni = 0; ni < 4; ++ni) {
        int n = n0 + ni;
        int node = node0 + n;
        float dg = degs[n];
        float rc = 1.0f / dg;
        float cA1 = dg * (1.0f / DELTA_F);
        float cA2 = DELTA_F * rc;
        float cB1 = (1.0f / DELTA_F);
        float cB2 = DELTA_F * rc * rc;
        float4 xv = make_float4(0.f, 0.f, 0.f, 0.f);
        if (node < NN) xv = *(const float4*)(X + (size_t)node * DD + o0);
#pragma unroll
        for (int oi = 0; oi < 4; ++oi) {
            int ii = ni * 4 + oi;
            float xa = (oi == 0) ? xv.x : (oi == 1) ? xv.y : (oi == 2) ? xv.z : xv.w;
            Asf[(o0 + oi) * 66 + n] =
                xa + A0[ii] + cA1 * A1[ii] + cA2 * A2[ii]
                   + rc * B0[ii] + cB1 * B1[ii] + cB2 * B2[ii] + mbias[o0 + oi];
        }
    }
    __syncthreads();

    // Lin1: stream W1t from global, h-quads from LDS
    float l1[16];
#pragma unroll
    for (int i = 0; i < 16; ++i) l1[i] = 0.f;
#pragma unroll 4
    for (int j = 0; j < 64; ++j) {
        float2 a01 = As2[j * 33 + ty * 2];
        float2 a23 = As2[j * 33 + ty * 2 + 1];
        const float av[4] = {a01.x, a01.y, a23.x, a23.y};
        const float4 wv = *(const float4*)(W1t + j * 64 + o0);
#pragma unroll
        for (int ni = 0; ni < 4; ++ni) {
            l1[ni * 4 + 0] += av[ni] * wv.x; l1[ni * 4 + 1] += av[ni] * wv.y;
            l1[ni * 4 + 2] += av[ni] * wv.z; l1[ni * 4 + 3] += av[ni] * wv.w;
        }
    }
    __syncthreads();
#pragma unroll
    for (int ni = 0; ni < 4; ++ni)
#pragma unroll
        for (int oi = 0; oi < 4; ++oi)
            Asf[(o0 + oi) * 66 + n0 + ni] = fmaxf(l1[ni * 4 + oi] + b1s[o0 + oi], 0.f);
    __syncthreads();

    // Lin2 + outer relu
    float l2[16];
#pragma unroll
    for (int i = 0; i < 16; ++i) l2[i] = 0.f;
#pragma unroll 4
    for (int j = 0; j < 64; ++j) {
        float2 a01 = As2[j * 33 + ty * 2];
        float2 a23 = As2[j * 33 + ty * 2 + 1];
        const float av[4] = {a01.x, a01.y, a23.x, a23.y};
        const float4 wv = *(const float4*)(W2t + j * 64 + o0);
#pragma unroll
        for (int ni = 0; ni < 4; ++ni) {
            l2[ni * 4 + 0] += av[ni] * wv.x; l2[ni * 4 + 1] += av[ni] * wv.y;
            l2[ni * 4 + 2] += av[ni] * wv.z; l2[ni * 4 + 3] += av[ni] * wv.w;
        }
    }
    __syncthreads();
#pragma unroll
    for (int ni = 0; ni < 4; ++ni) {
        int node = node0 + n0 + ni;
        float4 yv;
        yv.x = fmaxf(l2[ni * 4 + 0] + b2s[o0 + 0], 0.f);
        yv.y = fmaxf(l2[ni * 4 + 1] + b2s[o0 + 1], 0.f);
        yv.z = fmaxf(l2[ni * 4 + 2] + b2s[o0 + 2], 0.f);
        yv.w = fmaxf(l2[ni * 4 + 3] + b2s[o0 + 3], 0.f);
        if (node < NN) *(float4*)(Y + (size_t)node * DD + o0) = yv;
        Asf[(o0 + 0) * 66 + n0 + ni] = yv.x;
        Asf[(o0 + 1) * 66 + n0 + ni] = yv.y;
        Asf[(o0 + 2) * 66 + n0 + ni] = yv.z;
        Asf[(o0 + 3) * 66 + n0 + ni] = yv.w;
    }
    __syncthreads();

    // BN partial sums for this tile (feature f = tid)
    if (tid < 64) {
        float s = 0.f, sq = 0.f;
        int lim = NN - node0;
        if (lim > 64) lim = 64;
        for (int n = 0; n < lim; ++n) {
            float v = Asf[tid * 66 + n];
            s += v;
            sq += v * v;
        }
        atomicAdd(&bnstat[tid], s);
        atomicAdd(&bnstat[64 + tid], sq);
    }
}

// ---------------- BN finalize+apply (+bf16 table write, + fused pool) ----------------
__global__ __launch_bounds__(256) void k_bnapply(
    const float* __restrict__ Y, const float* __restrict__ bs,
    const float* __restrict__ g, const float* __restrict__ b,
    float* __restrict__ XO, ushort* __restrict__ XH,
    const int* __restrict__ batch, float* __restrict__ gpool, int do_pool) {
    __shared__ float sc[64], shf[64], pool[512];
    int tid = threadIdx.x;
    if (tid < 64) {
        float mean = bs[tid] * (1.f / NN);
        float var = fmaxf(bs[64 + tid] * (1.f / NN) - mean * mean, 0.f);
        float inv = rsqrtf(var + BN_EPS_F);
        float s = g[tid] * inv;
        sc[tid] = s;
        shf[tid] = b[tid] - mean * s;
    }
    __syncthreads();
    int i = blockIdx.x * 256 + tid;  // float4 index
    int n = i >> 4, fq = (i & 15) * 4;
    float4 r = make_float4(0.f, 0.f, 0.f, 0.f);
    bool valid = i < NN * 16;
    if (valid) {
        float4 y = *(const float4*)(Y + (size_t)i * 4);
        r.x = y.x * sc[fq + 0] + shf[fq + 0];
        r.y = y.y * sc[fq + 1] + shf[fq + 1];
        r.z = y.z * sc[fq + 2] + shf[fq + 2];
        r.w = y.w * sc[fq + 3] + shf[fq + 3];
        *(float4*)(XO + (size_t)i * 4) = r;
        ushort4 h;
        h.x = f2bu(r.x); h.y = f2bu(r.y); h.z = f2bu(r.z); h.w = f2bu(r.w);
        *(ushort4*)(XH + (size_t)i * 4) = h;
    }
    if (do_pool) {
        int nfirst = blockIdx.x * 16;
        int nlast = nfirst + 15;
        if (nlast >= NN) nlast = NN - 1;
        int gmin = batch[nfirst], gmax = batch[nlast];
        int span = gmax - gmin + 1;
        if (span <= 8) {
            for (int j = tid; j < span * 64; j += 256) pool[j] = 0.f;
            __syncthreads();
            if (valid) {
                int gb = batch[n] - gmin;
                atomicAdd(&pool[gb * 64 + fq + 0], r.x);
                atomicAdd(&pool[gb * 64 + fq + 1], r.y);
                atomicAdd(&pool[gb * 64 + fq + 2], r.z);
                atomicAdd(&pool[gb * 64 + fq + 3], r.w);
            }
            __syncthreads();
            for (int j = tid; j < span * 64; j += 256)
                atomicAdd(&gpool[(size_t)(gmin + (j >> 6)) * 64 + (j & 63)], pool[j]);
        } else {
            if (valid) {
                float* gp = gpool + (size_t)batch[n] * DD + fq;
                atomicAdd(gp + 0, r.x);
                atomicAdd(gp + 1, r.y);
                atomicAdd(gp + 2, r.z);
                atomicAdd(gp + 3, r.w);
            }
        }
    }
}

// ---------------- head: fc1+relu, fc2, log_softmax ----------------
__global__ __launch_bounds__(256) void k_head(const float* __restrict__ gpool,
                                              const float* __restrict__ fc1W, const float* __restrict__ fc1b,
                                              const float* __restrict__ fc2W, const float* __restrict__ fc2b,
                                              float* __restrict__ out) {
    __shared__ float sh[12576];
    float* const gs = sh;
    float* const w1t = sh + 4096;
    float* const z1s = sh + 8256;
    float* const b1s = sh + 12416;
    float* const b2s = sh + 12480;
    float* const w2t = sh;
    float* const z2s = sh + 4096;

    int tid = threadIdx.x;
    for (int i = tid; i < 4096; i += 256) {
        gs[i] = gpool[i];
        int o = i >> 6, j = i & 63;
        w1t[j * 65 + o] = fc1W[i];
    }
    if (tid < 64) b1s[tid] = fc1b[tid];
    if (tid < 32) b2s[tid] = fc2b[tid];
    __syncthreads();
    {
        int tx = tid & 15, ty = tid >> 4, o0 = tx * 4, g0 = ty * 4;
        float acc[16];
#pragma unroll
        for (int i = 0; i < 16; ++i) acc[i] = 0.f;
        for (int j = 0; j < 64; ++j) {
            float w0 = w1t[j * 65 + o0 + 0], w1 = w1t[j * 65 + o0 + 1];
            float w2 = w1t[j * 65 + o0 + 2], w3 = w1t[j * 65 + o0 + 3];
#pragma unroll
            for (int gi = 0; gi < 4; ++gi) {
                float a = gs[(g0 + gi) * 64 + j];
                acc[gi * 4 + 0] += a * w0; acc[gi * 4 + 1] += a * w1;
                acc[gi * 4 + 2] += a * w2; acc[gi * 4 + 3] += a * w3;
            }
        }
        __syncthreads();
#pragma unroll
        for (int gi = 0; gi < 4; ++gi)
#pragma unroll
            for (int oi = 0; oi < 4; ++oi)
                z1s[(g0 + gi) * 65 + o0 + oi] = fmaxf(acc[gi * 4 + oi] + b1s[o0 + oi], 0.f);
    }
    for (int i = tid; i < 2048; i += 256) {
        int o = i >> 6, j = i & 63;
        w2t[j * 33 + o] = fc2W[i];
    }
    __syncthreads();
    {
        int tx = tid & 7, ty = tid >> 3, o0 = tx * 4, g0 = ty * 2;
        float acc[8];
#pragma unroll
        for (int i = 0; i < 8; ++i) acc[i] = 0.f;
        for (int j = 0; j < 64; ++j) {
            float w0 = w2t[j * 33 + o0 + 0], w1 = w2t[j * 33 + o0 + 1];
            float w2 = w2t[j * 33 + o0 + 2], w3 = w2t[j * 33 + o0 + 3];
            float a0 = z1s[(g0 + 0) * 65 + j];
            float a1 = z1s[(g0 + 1) * 65 + j];
            acc[0] += a0 * w0; acc[1] += a0 * w1; acc[2] += a0 * w2; acc[3] += a0 * w3;
            acc[4] += a1 * w0; acc[5] += a1 * w1; acc[6] += a1 * w2; acc[7] += a1 * w3;
        }
#pragma unroll
        for (int gi = 0; gi < 2; ++gi)
#pragma unroll
            for (int oi = 0; oi < 4; ++oi)
                z2s[(g0 + gi) * 33 + o0 + oi] = acc[gi * 4 + oi] + b2s[o0 + oi];
    }
    __syncthreads();
    if (tid < 64) {
        float m = -3.402823466e38f;
        for (int c = 0; c < DOUT; ++c) m = fmaxf(m, z2s[tid * 33 + c]);
        float s = 0.f;
        for (int c = 0; c < DOUT; ++c) s += expf(z2s[tid * 33 + c] - m);
        float lse = m + logf(s);
        for (int c = 0; c < DOUT; ++c)
            out[tid * DOUT + c] = z2s[tid * 33 + c] - lse;
    }
}

extern "C" void kernel_launch(void* const* d_in, const int* in_sizes, int n_in,
                              void* d_out, int out_size, void* d_ws, size_t ws_size,
                              hipStream_t stream) {
    const float* x = (const float*)d_in[0];
    const int* ei = (const int*)d_in[1];
    const int* src = ei;
    const int* dst = ei + NE;
    const int* batch = (const int*)d_in[2];
    const float *mlpW[3], *mlpB[3], *w1[3], *bb1[3], *w2[3], *bb2[3], *bng[3], *bnb[3];
    for (int l = 0; l < 3; ++l) {
        mlpW[l] = (const float*)d_in[3 + 6 * l];
        mlpB[l] = (const float*)d_in[4 + 6 * l];
        w1[l]   = (const float*)d_in[5 + 6 * l];
        bb1[l]  = (const float*)d_in[6 + 6 * l];
        w2[l]   = (const float*)d_in[7 + 6 * l];
        bb2[l]  = (const float*)d_in[8 + 6 * l];
        bng[l]  = (const float*)d_in[21 + 2 * l];
        bnb[l]  = (const float*)d_in[22 + 2 * l];
    }
    const float* fc1W = (const float*)d_in[27];
    const float* fc1b = (const float*)d_in[28];
    const float* fc2W = (const float*)d_in[29];
    const float* fc2b = (const float*)d_in[30];
    float* out = (float*)d_out;

    char* ws = (char*)d_ws;
    size_t off = 0;
    auto alloc = [&](size_t bytes) -> void* {
        void* p = ws + off;
        off = (off + bytes + 511) & ~(size_t)511;
        return p;
    };
    int* counts    = (int*)alloc((size_t)NN * 4);
    int* row_ptr   = (int*)alloc((size_t)(NN + 1) * 4);
    int* cursor    = (int*)alloc((size_t)NN * 4);
    int* blockSums = (int*)alloc(256 * 4);
    int* blockBase = (int*)alloc(256 * 4);
    int* csr_src   = (int*)alloc((size_t)NE * 4);
    float* XB      = (float*)alloc((size_t)NN * DD * 4);
    float* Yb      = (float*)alloc((size_t)NN * DD * 4);
    ushort* XH     = (ushort*)alloc((size_t)NN * DD * 2);
    float* Wt      = (float*)alloc((size_t)3 * 49152 * 4);
    float* Wsm     = (float*)alloc((size_t)6 * 4096 * 4);
    float* bnstat  = (float*)alloc(384 * 4);
    float* gpool   = (float*)alloc((size_t)NGRAPH * DD * 4);
    (void)ws_size; (void)in_sizes; (void)n_in; (void)out_size;

    k_init<<<196, 256, 0, stream>>>(counts, bnstat, gpool);
    k_count<<<6250, 256, 0, stream>>>(dst, counts);
    k_scan_a<<<196, 256, 0, stream>>>(counts, blockSums);
    k_scan_b<<<1, 256, 0, stream>>>(blockSums, blockBase);
    k_scan_c<<<196, 256, 0, stream>>>(counts, blockBase, row_ptr, cursor);
    k_fill<<<6250, 256, 0, stream>>>(src, dst, cursor, csr_src);
    k_wprep<<<672, 256, 0, stream>>>(mlpW[0], mlpW[1], mlpW[2],
                                     w1[0], w2[0], w1[1], w2[1], w1[2], w2[2],
                                     Wt, Wsm);
    k_x2h<<<3125, 256, 0, stream>>>(x, XH);

    const float* Xin = x;
    for (int l = 0; l < 3; ++l) {
        k_fused<<<782, 256, 0, stream>>>(Xin, XH, row_ptr, csr_src,
                                         Wt + (size_t)l * 49152, mlpB[l],
                                         Wsm + (size_t)(2 * l) * 4096, bb1[l],
                                         Wsm + (size_t)(2 * l + 1) * 4096, bb2[l],
                                         Yb, bnstat + l * 128);
        k_bnapply<<<3125, 256, 0, stream>>>(Yb, bnstat + l * 128, bng[l], bnb[l],
                                            XB, XH, batch, gpool, (l == 2) ? 1 : 0);
        Xin = XB;
    }
    k_head<<<1, 256, 0, stream>>>(gpool, fc1W, fc1b, fc2W, fc2b, out);
}

// Round 6
// 986.000 us; speedup vs baseline: 1.4275x; 1.0666x over previous
//
#include <hip/hip_runtime.h>

#define NN 50000
#define NE 1600000
#define DD 64
#define NGRAPH 64
#define DOUT 32
#define DELTA_F 2.5749f
#define BN_EPS_F 1e-5f

typedef unsigned short ushort;

static __device__ __forceinline__ float bu2f(ushort u) {
    return __uint_as_float(((unsigned)u) << 16);
}
static __device__ __forceinline__ float blo(unsigned u) {
    return __uint_as_float(u << 16);
}
static __device__ __forceinline__ float bhi(unsigned u) {
    return __uint_as_float(u & 0xFFFF0000u);
}
static __device__ __forceinline__ ushort f2bu(float f) {
    unsigned u = __float_as_uint(f);
    unsigned r = (u + 0x7FFF + ((u >> 16) & 1)) >> 16;   // round-to-nearest-even
    return (ushort)r;
}

// ---------------- init: zero counters / bn stats / pool ----------------
__global__ void k_init(int* __restrict__ counts, float* __restrict__ bnstat,
                       float* __restrict__ gpool) {
    int i = blockIdx.x * 256 + threadIdx.x;
    if (i < NN) counts[i] = 0;
    if (i < 384) bnstat[i] = 0.f;
    if (i < NGRAPH * DD) gpool[i] = 0.f;
}

// ---------------- CSR build ----------------
__global__ void k_count(const int* __restrict__ dst, int* __restrict__ counts) {
    int e = blockIdx.x * 256 + threadIdx.x;
    if (e < NE) atomicAdd(&counts[dst[e]], 1);
}

__global__ void k_scan_a(const int* __restrict__ counts, int* __restrict__ blockSums) {
    __shared__ int red[256];
    int tid = threadIdx.x;
    int gid = blockIdx.x * 256 + tid;
    int v = (gid < NN) ? counts[gid] : 0;
    red[tid] = v;
    __syncthreads();
    for (int s = 128; s > 0; s >>= 1) {
        if (tid < s) red[tid] += red[tid + s];
        __syncthreads();
    }
    if (tid == 0) blockSums[blockIdx.x] = red[0];
}

__global__ void k_scan_b(const int* __restrict__ blockSums, int* __restrict__ blockBase) {
    __shared__ int sh[256];
    int tid = threadIdx.x;
    int v = (tid < 196) ? blockSums[tid] : 0;
    sh[tid] = v;
    __syncthreads();
    for (int off = 1; off < 256; off <<= 1) {
        int t = (tid >= off) ? sh[tid - off] : 0;
        __syncthreads();
        sh[tid] += t;
        __syncthreads();
    }
    blockBase[tid] = sh[tid] - v;  // exclusive
}

__global__ void k_scan_c(const int* __restrict__ counts, const int* __restrict__ blockBase,
                         int* __restrict__ row_ptr, int* __restrict__ cursor) {
    __shared__ int sh[256];
    int tid = threadIdx.x;
    int gid = blockIdx.x * 256 + tid;
    int v = (gid < NN) ? counts[gid] : 0;
    sh[tid] = v;
    __syncthreads();
    for (int off = 1; off < 256; off <<= 1) {
        int t = (tid >= off) ? sh[tid - off] : 0;
        __syncthreads();
        sh[tid] += t;
        __syncthreads();
    }
    int excl = blockBase[blockIdx.x] + sh[tid] - v;
    if (gid <= NN) {
        row_ptr[gid] = excl;
        if (gid < NN) cursor[gid] = excl;
    }
}

__global__ void k_fill(const int* __restrict__ src, const int* __restrict__ dst,
                       int* __restrict__ cursor, int* __restrict__ csr_src) {
    int e = blockIdx.x * 256 + threadIdx.x;
    if (e < NE) {
        int d = dst[e];
        int pos = atomicAdd(&cursor[d], 1);
        csr_src[pos] = src[e];
    }
}

// ---------------- weight prep: big transpose + six 64x64 transposes ----------------
__global__ void k_wprep(const float* __restrict__ w0, const float* __restrict__ w1,
                        const float* __restrict__ w2,
                        const float* __restrict__ a0, const float* __restrict__ a1,
                        const float* __restrict__ a2, const float* __restrict__ a3,
                        const float* __restrict__ a4, const float* __restrict__ a5,
                        float* __restrict__ Wt, float* __restrict__ Wsm) {
    int i = blockIdx.x * 256 + threadIdx.x;
    if (i < 3 * 49152) {
        int l = i / 49152, r = i % 49152;
        const float* w = (l == 0) ? w0 : ((l == 1) ? w1 : w2);
        int o = r / 768, kk = r % 768;
        int g = kk >> 8, k = kk & 255;
        Wt[l * 49152 + g * 16384 + k * 64 + o] = w[r];
    } else if (i < 3 * 49152 + 6 * 4096) {
        int r2 = i - 3 * 49152;
        int l = r2 >> 12, r = r2 & 4095;
        const float* w = (l == 0) ? a0 : (l == 1) ? a1 : (l == 2) ? a2
                       : (l == 3) ? a3 : (l == 4) ? a4 : a5;
        int o = r >> 6, j = r & 63;
        Wsm[l * 4096 + j * 64 + o] = w[r];
    }
}

// ---------------- x (f32) -> bf16 gather table ----------------
__global__ void k_x2h(const float* __restrict__ x, ushort* __restrict__ XH) {
    int i = blockIdx.x * 256 + threadIdx.x;
    if (i < NN * 16) {
        float4 v = *(const float4*)(x + (size_t)i * 4);
        ushort4 h;
        h.x = f2bu(v.x); h.y = f2bu(v.y); h.z = f2bu(v.z); h.w = f2bu(v.w);
        *(ushort4*)(XH + (size_t)i * 4) = h;
    }
}

// ======================================================================
// Fused layer kernel, Ntile = 32 nodes/block.
// Gather: 8-lane groups, uint4 (8 bf16) per lane, 8 edges in flight.
// LDS: As[192 rows][34 cols] + 224 tail = 6752 floats = 27.0 KB -> 4-5 blk/CU.
// ======================================================================
__global__ __launch_bounds__(256, 4) void k_fused(
    const float* __restrict__ X, const ushort* __restrict__ XH,
    const int* __restrict__ row_ptr, const int* __restrict__ csr_src,
    const float* __restrict__ Wt, const float* __restrict__ mlp_b,
    const float* __restrict__ W1t, const float* __restrict__ b1,
    const float* __restrict__ W2t, const float* __restrict__ b2,
    float* __restrict__ Y, float* __restrict__ bnstat) {
    __shared__ float2 As2[3376];           // 6752 floats
    float* const Asf = (float*)As2;        // row stride 34 floats
    float* const mbias = Asf + 6528;
    float* const b1s = Asf + 6592;
    float* const b2s = Asf + 6656;
    float* const degs = Asf + 6720;        // 32

    const int tid = threadIdx.x;
    const int node0 = blockIdx.x * 32;

    if (tid < 64) {
        mbias[tid] = mlp_b[tid];
        b1s[tid] = b1[tid];
        b2s[tid] = b2[tid];
    }

    // ---- gather phase: 32 groups of 8 lanes; group g -> node node0+g ----
    {
        const int l8 = tid & 7;
        const int n = tid >> 3;             // 0..31
        const int node = node0 + n;
        const int f0 = l8 * 8;
        const ushort* Xp = XH + f0;

        float s[8], q[8], m[8];
#pragma unroll
        for (int i = 0; i < 8; ++i) { s[i] = 0.f; q[i] = 0.f; m[i] = -3.402823466e38f; }

        int beg = 0, end = 0;
        if (node < NN) { beg = row_ptr[node]; end = row_ptr[node + 1]; }
        const int deg = end - beg;
        const int efull = beg + (deg & ~7);

        int c[8];
        if (beg < efull) {
#pragma unroll
            for (int j = 0; j < 8; ++j) c[j] = csr_src[beg + j];
        }
        for (int e = beg; e < efull; e += 8) {
            int b[8];
#pragma unroll
            for (int j = 0; j < 8; ++j) b[j] = c[j];
            if (e + 8 < efull) {
#pragma unroll
                for (int j = 0; j < 8; ++j) c[j] = csr_src[e + 8 + j];
            }
            uint4 r[8];
#pragma unroll
            for (int j = 0; j < 8; ++j)
                r[j] = *(const uint4*)(Xp + (size_t)b[j] * 64);
#pragma unroll
            for (int j = 0; j < 8; ++j) {
                float v0 = blo(r[j].x), v1 = bhi(r[j].x);
                float v2 = blo(r[j].y), v3 = bhi(r[j].y);
                float v4 = blo(r[j].z), v5 = bhi(r[j].z);
                float v6 = blo(r[j].w), v7 = bhi(r[j].w);
                s[0] += v0; q[0] = fmaf(v0, v0, q[0]); m[0] = fmaxf(m[0], v0);
                s[1] += v1; q[1] = fmaf(v1, v1, q[1]); m[1] = fmaxf(m[1], v1);
                s[2] += v2; q[2] = fmaf(v2, v2, q[2]); m[2] = fmaxf(m[2], v2);
                s[3] += v3; q[3] = fmaf(v3, v3, q[3]); m[3] = fmaxf(m[3], v3);
                s[4] += v4; q[4] = fmaf(v4, v4, q[4]); m[4] = fmaxf(m[4], v4);
                s[5] += v5; q[5] = fmaf(v5, v5, q[5]); m[5] = fmaxf(m[5], v5);
                s[6] += v6; q[6] = fmaf(v6, v6, q[6]); m[6] = fmaxf(m[6], v6);
                s[7] += v7; q[7] = fmaf(v7, v7, q[7]); m[7] = fmaxf(m[7], v7);
            }
        }
        for (int e = efull; e < end; ++e) {
            int idx = csr_src[e];
            uint4 r = *(const uint4*)(Xp + (size_t)idx * 64);
            float v0 = blo(r.x), v1 = bhi(r.x);
            float v2 = blo(r.y), v3 = bhi(r.y);
            float v4 = blo(r.z), v5 = bhi(r.z);
            float v6 = blo(r.w), v7 = bhi(r.w);
            s[0] += v0; q[0] = fmaf(v0, v0, q[0]); m[0] = fmaxf(m[0], v0);
            s[1] += v1; q[1] = fmaf(v1, v1, q[1]); m[1] = fmaxf(m[1], v1);
            s[2] += v2; q[2] = fmaf(v2, v2, q[2]); m[2] = fmaxf(m[2], v2);
            s[3] += v3; q[3] = fmaf(v3, v3, q[3]); m[3] = fmaxf(m[3], v3);
            s[4] += v4; q[4] = fmaf(v4, v4, q[4]); m[4] = fmaxf(m[4], v4);
            s[5] += v5; q[5] = fmaf(v5, v5, q[5]); m[5] = fmaxf(m[5], v5);
            s[6] += v6; q[6] = fmaf(v6, v6, q[6]); m[6] = fmaxf(m[6], v6);
            s[7] += v7; q[7] = fmaf(v7, v7, q[7]); m[7] = fmaxf(m[7], v7);
        }

        float cdeg = (node < NN) ? (float)deg : 1.f;
        float rc = 1.0f / cdeg;
#pragma unroll
        for (int i = 0; i < 8; ++i) {
            float mean = s[i] * rc;
            float var = fmaxf(q[i] * rc - mean * mean, 0.f);
            float mv = m[i];
            if (node >= NN) { mv = 0.f; var = 0.f; }
            Asf[(f0 + i) * 34 + n] = s[i];
            Asf[(64 + f0 + i) * 34 + n] = mv;
            Asf[(128 + f0 + i) * 34 + n] = var;
        }
        if (l8 == 0) degs[n] = cdeg;
    }
    __syncthreads();

    // ---- big GEMM: A over 192 rows (s,max,var), B over 64 s-rows (mean W) ----
    const int tx = tid & 15, ty = tid >> 4;
    const int o0 = tx * 4, n0 = ty * 2;
    const float* Wg0 = Wt;
    const float* Wg1 = Wt + 16384;
    const float* Wg2 = Wt + 32768;

    float A0[8], A1[8], A2[8], B0[8], B1[8], B2[8];
#pragma unroll
    for (int i = 0; i < 8; ++i) { A0[i] = 0.f; A1[i] = 0.f; A2[i] = 0.f;
                                  B0[i] = 0.f; B1[i] = 0.f; B2[i] = 0.f; }

    // loop1: k = 0..127 -> W rows k (sum cols 0..63, max cols 64..127)
#pragma unroll 4
    for (int k = 0; k < 128; ++k) {
        float2 a = As2[k * 17 + ty];
        const float av[2] = {a.x, a.y};
        float4 w0 = *(const float4*)(Wg0 + k * 64 + o0);
        float4 w1 = *(const float4*)(Wg1 + k * 64 + o0);
        float4 w2 = *(const float4*)(Wg2 + k * 64 + o0);
#pragma unroll
        for (int ni = 0; ni < 2; ++ni) {
            A0[ni * 4 + 0] += av[ni] * w0.x; A0[ni * 4 + 1] += av[ni] * w0.y;
            A0[ni * 4 + 2] += av[ni] * w0.z; A0[ni * 4 + 3] += av[ni] * w0.w;
            A1[ni * 4 + 0] += av[ni] * w1.x; A1[ni * 4 + 1] += av[ni] * w1.y;
            A1[ni * 4 + 2] += av[ni] * w1.z; A1[ni * 4 + 3] += av[ni] * w1.w;
            A2[ni * 4 + 0] += av[ni] * w2.x; A2[ni * 4 + 1] += av[ni] * w2.y;
            A2[ni * 4 + 2] += av[ni] * w2.z; A2[ni * 4 + 3] += av[ni] * w2.w;
        }
    }
    // loop2: var rows (As rows 128..191) -> W rows 192..255
#pragma unroll 4
    for (int k = 0; k < 64; ++k) {
        float2 a = As2[(128 + k) * 17 + ty];
        const float av[2] = {a.x, a.y};
        float4 w0 = *(const float4*)(Wg0 + (192 + k) * 64 + o0);
        float4 w1 = *(const float4*)(Wg1 + (192 + k) * 64 + o0);
        float4 w2 = *(const float4*)(Wg2 + (192 + k) * 64 + o0);
#pragma unroll
        for (int ni = 0; ni < 2; ++ni) {
            A0[ni * 4 + 0] += av[ni] * w0.x; A0[ni * 4 + 1] += av[ni] * w0.y;
            A0[ni * 4 + 2] += av[ni] * w0.z; A0[ni * 4 + 3] += av[ni] * w0.w;
            A1[ni * 4 + 0] += av[ni] * w1.x; A1[ni * 4 + 1] += av[ni] * w1.y;
            A1[ni * 4 + 2] += av[ni] * w1.z; A1[ni * 4 + 3] += av[ni] * w1.w;
            A2[ni * 4 + 0] += av[ni] * w2.x; A2[ni * 4 + 1] += av[ni] * w2.y;
            A2[ni * 4 + 2] += av[ni] * w2.z; A2[ni * 4 + 3] += av[ni] * w2.w;
        }
    }
    // loop3: mean contributions: s rows (0..63) with W rows 128..191
#pragma unroll 4
    for (int k = 0; k < 64; ++k) {
        float2 a = As2[k * 17 + ty];
        const float av[2] = {a.x, a.y};
        float4 w0 = *(const float4*)(Wg0 + (128 + k) * 64 + o0);
        float4 w1 = *(const float4*)(Wg1 + (128 + k) * 64 + o0);
        float4 w2 = *(const float4*)(Wg2 + (128 + k) * 64 + o0);
#pragma unroll
        for (int ni = 0; ni < 2; ++ni) {
            B0[ni * 4 + 0] += av[ni] * w0.x; B0[ni * 4 + 1] += av[ni] * w0.y;
            B0[ni * 4 + 2] += av[ni] * w0.z; B0[ni * 4 + 3] += av[ni] * w0.w;
            B1[ni * 4 + 0] += av[ni] * w1.x; B1[ni * 4 + 1] += av[ni] * w1.y;
            B1[ni * 4 + 2] += av[ni] * w1.z; B1[ni * 4 + 3] += av[ni] * w1.w;
            B2[ni * 4 + 0] += av[ni] * w2.x; B2[ni * 4 + 1] += av[ni] * w2.y;
            B2[ni * 4 + 2] += av[ni] * w2.z; B2[ni * 4 + 3] += av[ni] * w2.w;
        }
    }
    __syncthreads();  // done reading As region

    // h = x + a (stored transposed: Asf[o][n], rows 0..63)
#pragma unroll
    for (int ni = 0; ni < 2; ++ni) {
        int n = n0 + ni;
        int node = node0 + n;
        float dg = degs[n];
        float rc = 1.0f / dg;
        float cA1 = dg * (1.0f / DELTA_F);
        float cA2 = DELTA_F * rc;
        float cB1 = (1.0f / DELTA_F);
        float cB2 = DELTA_F * rc * rc;
        float4 xv = make_float4(0.f, 0.f, 0.f, 0.f);
        if (node < NN) xv = *(const float4*)(X + (size_t)node * DD + o0);
#pragma unroll
        for (int oi = 0; oi < 4; ++oi) {
            int ii = ni * 4 + oi;
            float xa = (oi == 0) ? xv.x : (oi == 1) ? xv.y : (oi == 2) ? xv.z : xv.w;
            Asf[(o0 + oi) * 34 + n] =
                xa + A0[ii] + cA1 * A1[ii] + cA2 * A2[ii]
                   + rc * B0[ii] + cB1 * B1[ii] + cB2 * B2[ii] + mbias[o0 + oi];
        }
    }
    __syncthreads();

    // Lin1: stream W1t from global, h-pairs from LDS
    float l1[8];
#pragma unroll
    for (int i = 0; i < 8; ++i) l1[i] = 0.f;
#pragma unroll 4
    for (int j = 0; j < 64; ++j) {
        float2 a = As2[j * 17 + ty];
        const float av[2] = {a.x, a.y};
        const float4 wv = *(const float4*)(W1t + j * 64 + o0);
#pragma unroll
        for (int ni = 0; ni < 2; ++ni) {
            l1[ni * 4 + 0] += av[ni] * wv.x; l1[ni * 4 + 1] += av[ni] * wv.y;
            l1[ni * 4 + 2] += av[ni] * wv.z; l1[ni * 4 + 3] += av[ni] * wv.w;
        }
    }
    __syncthreads();
#pragma unroll
    for (int ni = 0; ni < 2; ++ni)
#pragma unroll
        for (int oi = 0; oi < 4; ++oi)
            Asf[(o0 + oi) * 34 + n0 + ni] = fmaxf(l1[ni * 4 + oi] + b1s[o0 + oi], 0.f);
    __syncthreads();

    // Lin2 + outer relu
    float l2[8];
#pragma unroll
    for (int i = 0; i < 8; ++i) l2[i] = 0.f;
#pragma unroll 4
    for (int j = 0; j < 64; ++j) {
        float2 a = As2[j * 17 + ty];
        const float av[2] = {a.x, a.y};
        const float4 wv = *(const float4*)(W2t + j * 64 + o0);
#pragma unroll
        for (int ni = 0; ni < 2; ++ni) {
            l2[ni * 4 + 0] += av[ni] * wv.x; l2[ni * 4 + 1] += av[ni] * wv.y;
            l2[ni * 4 + 2] += av[ni] * wv.z; l2[ni * 4 + 3] += av[ni] * wv.w;
        }
    }
    __syncthreads();
#pragma unroll
    for (int ni = 0; ni < 2; ++ni) {
        int node = node0 + n0 + ni;
        float4 yv;
        yv.x = fmaxf(l2[ni * 4 + 0] + b2s[o0 + 0], 0.f);
        yv.y = fmaxf(l2[ni * 4 + 1] + b2s[o0 + 1], 0.f);
        yv.z = fmaxf(l2[ni * 4 + 2] + b2s[o0 + 2], 0.f);
        yv.w = fmaxf(l2[ni * 4 + 3] + b2s[o0 + 3], 0.f);
        if (node < NN) *(float4*)(Y + (size_t)node * DD + o0) = yv;
        Asf[(o0 + 0) * 34 + n0 + ni] = yv.x;
        Asf[(o0 + 1) * 34 + n0 + ni] = yv.y;
        Asf[(o0 + 2) * 34 + n0 + ni] = yv.z;
        Asf[(o0 + 3) * 34 + n0 + ni] = yv.w;
    }
    __syncthreads();

    // BN partial sums for this tile (feature f = tid)
    if (tid < 64) {
        float s = 0.f, sq = 0.f;
        int lim = NN - node0;
        if (lim > 32) lim = 32;
        for (int n = 0; n < lim; ++n) {
            float v = Asf[tid * 34 + n];
            s += v;
            sq += v * v;
        }
        atomicAdd(&bnstat[tid], s);
        atomicAdd(&bnstat[64 + tid], sq);
    }
}

// ---------------- BN finalize+apply (+bf16 table write, + fused pool) ----------------
__global__ __launch_bounds__(256) void k_bnapply(
    const float* __restrict__ Y, const float* __restrict__ bs,
    const float* __restrict__ g, const float* __restrict__ b,
    float* __restrict__ XO, ushort* __restrict__ XH,
    const int* __restrict__ batch, float* __restrict__ gpool, int do_pool) {
    __shared__ float sc[64], shf[64], pool[512];
    int tid = threadIdx.x;
    if (tid < 64) {
        float mean = bs[tid] * (1.f / NN);
        float var = fmaxf(bs[64 + tid] * (1.f / NN) - mean * mean, 0.f);
        float inv = rsqrtf(var + BN_EPS_F);
        float s = g[tid] * inv;
        sc[tid] = s;
        shf[tid] = b[tid] - mean * s;
    }
    __syncthreads();
    int i = blockIdx.x * 256 + tid;  // float4 index
    int n = i >> 4, fq = (i & 15) * 4;
    float4 r = make_float4(0.f, 0.f, 0.f, 0.f);
    bool valid = i < NN * 16;
    if (valid) {
        float4 y = *(const float4*)(Y + (size_t)i * 4);
        r.x = y.x * sc[fq + 0] + shf[fq + 0];
        r.y = y.y * sc[fq + 1] + shf[fq + 1];
        r.z = y.z * sc[fq + 2] + shf[fq + 2];
        r.w = y.w * sc[fq + 3] + shf[fq + 3];
        *(float4*)(XO + (size_t)i * 4) = r;
        ushort4 h;
        h.x = f2bu(r.x); h.y = f2bu(r.y); h.z = f2bu(r.z); h.w = f2bu(r.w);
        *(ushort4*)(XH + (size_t)i * 4) = h;
    }
    if (do_pool) {
        int nfirst = blockIdx.x * 16;
        int nlast = nfirst + 15;
        if (nlast >= NN) nlast = NN - 1;
        int gmin = batch[nfirst], gmax = batch[nlast];
        int span = gmax - gmin + 1;
        if (span <= 8) {
            for (int j = tid; j < span * 64; j += 256) pool[j] = 0.f;
            __syncthreads();
            if (valid) {
                int gb = batch[n] - gmin;
                atomicAdd(&pool[gb * 64 + fq + 0], r.x);
                atomicAdd(&pool[gb * 64 + fq + 1], r.y);
                atomicAdd(&pool[gb * 64 + fq + 2], r.z);
                atomicAdd(&pool[gb * 64 + fq + 3], r.w);
            }
            __syncthreads();
            for (int j = tid; j < span * 64; j += 256)
                atomicAdd(&gpool[(size_t)(gmin + (j >> 6)) * 64 + (j & 63)], pool[j]);
        } else {
            if (valid) {
                float* gp = gpool + (size_t)batch[n] * DD + fq;
                atomicAdd(gp + 0, r.x);
                atomicAdd(gp + 1, r.y);
                atomicAdd(gp + 2, r.z);
                atomicAdd(gp + 3, r.w);
            }
        }
    }
}

// ---------------- head: fc1+relu, fc2, log_softmax ----------------
__global__ __launch_bounds__(256) void k_head(const float* __restrict__ gpool,
                                              const float* __restrict__ fc1W, const float* __restrict__ fc1b,
                                              const float* __restrict__ fc2W, const float* __restrict__ fc2b,
                                              float* __restrict__ out) {
    __shared__ float sh[12576];
    float* const gs = sh;
    float* const w1t = sh + 4096;
    float* const z1s = sh + 8256;
    float* const b1s = sh + 12416;
    float* const b2s = sh + 12480;
    float* const w2t = sh;
    float* const z2s = sh + 4096;

    int tid = threadIdx.x;
    for (int i = tid; i < 4096; i += 256) {
        gs[i] = gpool[i];
        int o = i >> 6, j = i & 63;
        w1t[j * 65 + o] = fc1W[i];
    }
    if (tid < 64) b1s[tid] = fc1b[tid];
    if (tid < 32) b2s[tid] = fc2b[tid];
    __syncthreads();
    {
        int tx = tid & 15, ty = tid >> 4, o0 = tx * 4, g0 = ty * 4;
        float acc[16];
#pragma unroll
        for (int i = 0; i < 16; ++i) acc[i] = 0.f;
        for (int j = 0; j < 64; ++j) {
            float w0 = w1t[j * 65 + o0 + 0], w1 = w1t[j * 65 + o0 + 1];
            float w2 = w1t[j * 65 + o0 + 2], w3 = w1t[j * 65 + o0 + 3];
#pragma unroll
            for (int gi = 0; gi < 4; ++gi) {
                float a = gs[(g0 + gi) * 64 + j];
                acc[gi * 4 + 0] += a * w0; acc[gi * 4 + 1] += a * w1;
                acc[gi * 4 + 2] += a * w2; acc[gi * 4 + 3] += a * w3;
            }
        }
        __syncthreads();
#pragma unroll
        for (int gi = 0; gi < 4; ++gi)
#pragma unroll
            for (int oi = 0; oi < 4; ++oi)
                z1s[(g0 + gi) * 65 + o0 + oi] = fmaxf(acc[gi * 4 + oi] + b1s[o0 + oi], 0.f);
    }
    for (int i = tid; i < 2048; i += 256) {
        int o = i >> 6, j = i & 63;
        w2t[j * 33 + o] = fc2W[i];
    }
    __syncthreads();
    {
        int tx = tid & 7, ty = tid >> 3, o0 = tx * 4, g0 = ty * 2;
        float acc[8];
#pragma unroll
        for (int i = 0; i < 8; ++i) acc[i] = 0.f;
        for (int j = 0; j < 64; ++j) {
            float w0 = w2t[j * 33 + o0 + 0], w1 = w2t[j * 33 + o0 + 1];
            float w2 = w2t[j * 33 + o0 + 2], w3 = w2t[j * 33 + o0 + 3];
            float a0 = z1s[(g0 + 0) * 65 + j];
            float a1 = z1s[(g0 + 1) * 65 + j];
            acc[0] += a0 * w0; acc[1] += a0 * w1; acc[2] += a0 * w2; acc[3] += a0 * w3;
            acc[4] += a1 * w0; acc[5] += a1 * w1; acc[6] += a1 * w2; acc[7] += a1 * w3;
        }
#pragma unroll
        for (int gi = 0; gi < 2; ++gi)
#pragma unroll
            for (int oi = 0; oi < 4; ++oi)
                z2s[(g0 + gi) * 33 + o0 + oi] = acc[gi * 4 + oi] + b2s[o0 + oi];
    }
    __syncthreads();
    if (tid < 64) {
        float m = -3.402823466e38f;
        for (int c = 0; c < DOUT; ++c) m = fmaxf(m, z2s[tid * 33 + c]);
        float s = 0.f;
        for (int c = 0; c < DOUT; ++c) s += expf(z2s[tid * 33 + c] - m);
        float lse = m + logf(s);
        for (int c = 0; c < DOUT; ++c)
            out[tid * DOUT + c] = z2s[tid * 33 + c] - lse;
    }
}

extern "C" void kernel_launch(void* const* d_in, const int* in_sizes, int n_in,
                              void* d_out, int out_size, void* d_ws, size_t ws_size,
                              hipStream_t stream) {
    const float* x = (const float*)d_in[0];
    const int* ei = (const int*)d_in[1];
    const int* src = ei;
    const int* dst = ei + NE;
    const int* batch = (const int*)d_in[2];
    const float *mlpW[3], *mlpB[3], *w1[3], *bb1[3], *w2[3], *bb2[3], *bng[3], *bnb[3];
    for (int l = 0; l < 3; ++l) {
        mlpW[l] = (const float*)d_in[3 + 6 * l];
        mlpB[l] = (const float*)d_in[4 + 6 * l];
        w1[l]   = (const float*)d_in[5 + 6 * l];
        bb1[l]  = (const float*)d_in[6 + 6 * l];
        w2[l]   = (const float*)d_in[7 + 6 * l];
        bb2[l]  = (const float*)d_in[8 + 6 * l];
        bng[l]  = (const float*)d_in[21 + 2 * l];
        bnb[l]  = (const float*)d_in[22 + 2 * l];
    }
    const float* fc1W = (const float*)d_in[27];
    const float* fc1b = (const float*)d_in[28];
    const float* fc2W = (const float*)d_in[29];
    const float* fc2b = (const float*)d_in[30];
    float* out = (float*)d_out;

    char* ws = (char*)d_ws;
    size_t off = 0;
    auto alloc = [&](size_t bytes) -> void* {
        void* p = ws + off;
        off = (off + bytes + 511) & ~(size_t)511;
        return p;
    };
    int* counts    = (int*)alloc((size_t)NN * 4);
    int* row_ptr   = (int*)alloc((size_t)(NN + 1) * 4);
    int* cursor    = (int*)alloc((size_t)NN * 4);
    int* blockSums = (int*)alloc(256 * 4);
    int* blockBase = (int*)alloc(256 * 4);
    int* csr_src   = (int*)alloc((size_t)NE * 4);
    float* XB      = (float*)alloc((size_t)NN * DD * 4);
    float* Yb      = (float*)alloc((size_t)NN * DD * 4);
    ushort* XH     = (ushort*)alloc((size_t)NN * DD * 2);
    float* Wt      = (float*)alloc((size_t)3 * 49152 * 4);
    float* Wsm     = (float*)alloc((size_t)6 * 4096 * 4);
    float* bnstat  = (float*)alloc(384 * 4);
    float* gpool   = (float*)alloc((size_t)NGRAPH * DD * 4);
    (void)ws_size; (void)in_sizes; (void)n_in; (void)out_size;

    k_init<<<196, 256, 0, stream>>>(counts, bnstat, gpool);
    k_count<<<6250, 256, 0, stream>>>(dst, counts);
    k_scan_a<<<196, 256, 0, stream>>>(counts, blockSums);
    k_scan_b<<<1, 256, 0, stream>>>(blockSums, blockBase);
    k_scan_c<<<196, 256, 0, stream>>>(counts, blockBase, row_ptr, cursor);
    k_fill<<<6250, 256, 0, stream>>>(src, dst, cursor, csr_src);
    k_wprep<<<672, 256, 0, stream>>>(mlpW[0], mlpW[1], mlpW[2],
                                     w1[0], w2[0], w1[1], w2[1], w1[2], w2[2],
                                     Wt, Wsm);
    k_x2h<<<3125, 256, 0, stream>>>(x, XH);

    const float* Xin = x;
    for (int l = 0; l < 3; ++l) {
        k_fused<<<1563, 256, 0, stream>>>(Xin, XH, row_ptr, csr_src,
                                          Wt + (size_t)l * 49152, mlpB[l],
                                          Wsm + (size_t)(2 * l) * 4096, bb1[l],
                                          Wsm + (size_t)(2 * l + 1) * 4096, bb2[l],
                                          Yb, bnstat + l * 128);
        k_bnapply<<<3125, 256, 0, stream>>>(Yb, bnstat + l * 128, bng[l], bnb[l],
                                            XB, XH, batch, gpool, (l == 2) ? 1 : 0);
        Xin = XB;
    }
    k_head<<<1, 256, 0, stream>>>(gpool, fc1W, fc1b, fc2W, fc2b, out);
}

// Round 10
// 971.850 us; speedup vs baseline: 1.4483x; 1.0146x over previous
//
#include <hip/hip_runtime.h>

#define NN 50000
#define NE 1600000
#define DD 64
#define NGRAPH 64
#define DOUT 32
#define DELTA_F 2.5749f
#define BN_EPS_F 1e-5f

typedef unsigned short ushort;
typedef __attribute__((ext_vector_type(8))) short short8;
typedef __attribute__((ext_vector_type(4))) float floatx4;

static __device__ __forceinline__ float blo(unsigned u) {
    return __uint_as_float(u << 16);
}
static __device__ __forceinline__ float bhi(unsigned u) {
    return __uint_as_float(u & 0xFFFF0000u);
}
static __device__ __forceinline__ ushort f2bu(float f) {
    unsigned u = __float_as_uint(f);
    unsigned r = (u + 0x7FFF + ((u >> 16) & 1)) >> 16;   // round-to-nearest-even
    return (ushort)r;
}
static __device__ __forceinline__ unsigned pk(float a, float b) {
    return ((unsigned)f2bu(b) << 16) | (unsigned)f2bu(a);
}

// ---------------- init ----------------
__global__ void k_init(int* __restrict__ counts, float* __restrict__ bnstat,
                       float* __restrict__ gpool) {
    int i = blockIdx.x * 256 + threadIdx.x;
    if (i < NN) counts[i] = 0;
    if (i < 384) bnstat[i] = 0.f;
    if (i < NGRAPH * DD) gpool[i] = 0.f;
}

// ---------------- CSR build ----------------
__global__ void k_count(const int* __restrict__ dst, int* __restrict__ counts) {
    int e = blockIdx.x * 256 + threadIdx.x;
    if (e < NE) atomicAdd(&counts[dst[e]], 1);
}

__global__ void k_scan_a(const int* __restrict__ counts, int* __restrict__ blockSums) {
    __shared__ int red[256];
    int tid = threadIdx.x;
    int gid = blockIdx.x * 256 + tid;
    int v = (gid < NN) ? counts[gid] : 0;
    red[tid] = v;
    __syncthreads();
    for (int s = 128; s > 0; s >>= 1) {
        if (tid < s) red[tid] += red[tid + s];
        __syncthreads();
    }
    if (tid == 0) blockSums[blockIdx.x] = red[0];
}

__global__ void k_scan_b(const int* __restrict__ blockSums, int* __restrict__ blockBase) {
    __shared__ int sh[256];
    int tid = threadIdx.x;
    int v = (tid < 196) ? blockSums[tid] : 0;
    sh[tid] = v;
    __syncthreads();
    for (int off = 1; off < 256; off <<= 1) {
        int t = (tid >= off) ? sh[tid - off] : 0;
        __syncthreads();
        sh[tid] += t;
        __syncthreads();
    }
    blockBase[tid] = sh[tid] - v;  // exclusive
}

__global__ void k_scan_c(const int* __restrict__ counts, const int* __restrict__ blockBase,
                         int* __restrict__ row_ptr, int* __restrict__ cursor) {
    __shared__ int sh[256];
    int tid = threadIdx.x;
    int gid = blockIdx.x * 256 + tid;
    int v = (gid < NN) ? counts[gid] : 0;
    sh[tid] = v;
    __syncthreads();
    for (int off = 1; off < 256; off <<= 1) {
        int t = (tid >= off) ? sh[tid - off] : 0;
        __syncthreads();
        sh[tid] += t;
        __syncthreads();
    }
    int excl = blockBase[blockIdx.x] + sh[tid] - v;
    if (gid <= NN) {
        row_ptr[gid] = excl;
        if (gid < NN) cursor[gid] = excl;
    }
}

__global__ void k_fill(const int* __restrict__ src, const int* __restrict__ dst,
                       int* __restrict__ cursor, int* __restrict__ csr_src) {
    int e = blockIdx.x * 256 + threadIdx.x;
    if (e < NE) {
        int d = dst[e];
        int pos = atomicAdd(&cursor[d], 1);
        csr_src[pos] = src[e];
    }
}

// ---------------- weight prep ----------------
// Wb: bf16 MFMA B-fragment order (hi only). Per layer: [g 3][kb 8][t 4][lane 64][j 8]
//   value = W[o=t*16+(lane&15)][k_global = g*256 + kb*32 + (lane>>4)*8 + j]
// Wt1: f32 g=1 chunk transposed [layer][k 256][o 64]  (the cnt/DELTA-amplified chunk)
// Wsm: f32 transposed 64x64 (Lin1/Lin2).
__global__ void k_wprep(const float* __restrict__ w0, const float* __restrict__ w1,
                        const float* __restrict__ w2,
                        const float* __restrict__ a0, const float* __restrict__ a1,
                        const float* __restrict__ a2, const float* __restrict__ a3,
                        const float* __restrict__ a4, const float* __restrict__ a5,
                        ushort* __restrict__ Wb, float* __restrict__ Wt1,
                        float* __restrict__ Wsm) {
    int i = blockIdx.x * 256 + threadIdx.x;
    if (i < 3 * 49152) {
        int layer = i / 49152, r = i % 49152;
        const float* w = (layer == 0) ? w0 : ((layer == 1) ? w1 : w2);
        int g = r / 16384, r2 = r % 16384;
        int kb = r2 >> 11, r3 = r2 & 2047;
        int t = r3 >> 9, r4 = r3 & 511;
        int l = r4 >> 3, j = r4 & 7;
        int k = kb * 32 + (l >> 4) * 8 + j;
        int o = t * 16 + (l & 15);
        Wb[i] = f2bu(w[o * 768 + g * 256 + k]);
    } else if (i < 3 * 49152 + 3 * 16384) {
        int i2 = i - 3 * 49152;
        int layer = i2 / 16384, r = i2 % 16384;
        const float* w = (layer == 0) ? w0 : ((layer == 1) ? w1 : w2);
        int k = r >> 6, o = r & 63;
        Wt1[i2] = w[o * 768 + 256 + k];
    } else if (i < 3 * 49152 + 3 * 16384 + 6 * 4096) {
        int r2 = i - 3 * 49152 - 3 * 16384;
        int l = r2 >> 12, r = r2 & 4095;
        const float* w = (l == 0) ? a0 : (l == 1) ? a1 : (l == 2) ? a2
                       : (l == 3) ? a3 : (l == 4) ? a4 : a5;
        int o = r >> 6, j = r & 63;
        Wsm[l * 4096 + j * 64 + o] = w[r];
    }
}

// ---------------- x (f32) -> bf16 gather table ----------------
__global__ void k_x2h(const float* __restrict__ x, ushort* __restrict__ XH) {
    int i = blockIdx.x * 256 + threadIdx.x;
    if (i < NN * 16) {
        float4 v = *(const float4*)(x + (size_t)i * 4);
        ushort4 h;
        h.x = f2bu(v.x); h.y = f2bu(v.y); h.z = f2bu(v.z); h.w = f2bu(v.w);
        *(ushort4*)(XH + (size_t)i * 4) = h;
    }
}

// ======================================================================
// Fused layer, Ntile = 32 nodes/block.  Hybrid GEMM:
//   g=1 (cnt/DELTA-amplified chunk): f32 VALU from f32 stats (error-critical)
//   g=0,2 (scales 1, DELTA/cnt):     MFMA bf16-hi (error ≤ ~0.1 at output)
// LDS (39808 B): Af32[k192][pad34] f32 | Ag[32][200] bf16 (overlaid by hsf
//   after frag loads) | biases/degs.   4 blocks/CU.
// ======================================================================
__global__ __launch_bounds__(256, 4) void k_fused(
    const float* __restrict__ X, const ushort* __restrict__ XH,
    const int* __restrict__ row_ptr, const int* __restrict__ csr_src,
    const ushort* __restrict__ Wbh, const float* __restrict__ Wt1,
    const float* __restrict__ mlp_b,
    const float* __restrict__ W1t, const float* __restrict__ b1,
    const float* __restrict__ W2t, const float* __restrict__ b2,
    float* __restrict__ Y, float* __restrict__ bnstat) {
    __shared__ __align__(16) char smem[39808];
    float* const Af32 = (float*)smem;                 // 192 x 34 f32 = 26112 B
    ushort* const Ag = (ushort*)(smem + 26112);       // 32 x 200 bf16 = 12800 B
    float* const hsf = (float*)(smem + 26112);        // overlays Ag (8704 B)
    float* const mbias = (float*)(smem + 38912);
    float* const b1s = mbias + 64;
    float* const b2s = mbias + 128;
    float* const degs = mbias + 192;                  // 32

    const int tid = threadIdx.x;
    const int node0 = blockIdx.x * 32;

    if (tid < 64) {
        mbias[tid] = mlp_b[tid];
        b1s[tid] = b1[tid];
        b2s[tid] = b2[tid];
    }

    // ---- gather: 32 groups of 8 lanes; group -> node; dbl-buffered rows ----
    {
        const int l8 = tid & 7;
        const int m = tid >> 3;                // 0..31
        const int node = node0 + m;
        const int f0 = l8 * 8;
        const ushort* Xp = XH + f0;

        float s[8], q[8], mx[8];
#pragma unroll
        for (int i = 0; i < 8; ++i) { s[i] = 0.f; q[i] = 0.f; mx[i] = -3.402823466e38f; }

        auto acc8 = [&](const uint4& rr) {
            float v0 = blo(rr.x), v1 = bhi(rr.x);
            float v2 = blo(rr.y), v3 = bhi(rr.y);
            float v4 = blo(rr.z), v5 = bhi(rr.z);
            float v6 = blo(rr.w), v7 = bhi(rr.w);
            s[0] += v0; q[0] = fmaf(v0, v0, q[0]); mx[0] = fmaxf(mx[0], v0);
            s[1] += v1; q[1] = fmaf(v1, v1, q[1]); mx[1] = fmaxf(mx[1], v1);
            s[2] += v2; q[2] = fmaf(v2, v2, q[2]); mx[2] = fmaxf(mx[2], v2);
            s[3] += v3; q[3] = fmaf(v3, v3, q[3]); mx[3] = fmaxf(mx[3], v3);
            s[4] += v4; q[4] = fmaf(v4, v4, q[4]); mx[4] = fmaxf(mx[4], v4);
            s[5] += v5; q[5] = fmaf(v5, v5, q[5]); mx[5] = fmaxf(mx[5], v5);
            s[6] += v6; q[6] = fmaf(v6, v6, q[6]); mx[6] = fmaxf(mx[6], v6);
            s[7] += v7; q[7] = fmaf(v7, v7, q[7]); mx[7] = fmaxf(mx[7], v7);
        };

        int beg = 0, end = 0;
        if (node < NN) { beg = row_ptr[node]; end = row_ptr[node + 1]; }
        const int deg = end - beg;
        const int nb = (deg + 7) >> 3;

        uint4 ra[8], rb[8];
        int ia[8];
        if (nb > 0) {
#pragma unroll
            for (int j = 0; j < 8; ++j) {
                int e = beg + j;
                ia[j] = csr_src[(e < end) ? e : end - 1];
            }
#pragma unroll
            for (int j = 0; j < 8; ++j)
                ra[j] = *(const uint4*)(Xp + (size_t)ia[j] * 64);
            if (nb > 1) {
#pragma unroll
                for (int j = 0; j < 8; ++j) {
                    int e = beg + 8 + j;
                    ia[j] = csr_src[(e < end) ? e : end - 1];
                }
            }
        }
        for (int t = 0; t < nb; ++t) {
            if (t + 1 < nb) {
#pragma unroll
                for (int j = 0; j < 8; ++j)
                    rb[j] = *(const uint4*)(Xp + (size_t)ia[j] * 64);
            }
            if (t + 2 < nb) {
                int b2e = beg + (t + 2) * 8;
#pragma unroll
                for (int j = 0; j < 8; ++j) {
                    int e = b2e + j;
                    ia[j] = csr_src[(e < end) ? e : end - 1];
                }
            }
            int cnt = end - (beg + t * 8);
            if (cnt >= 8) {
#pragma unroll
                for (int j = 0; j < 8; ++j) acc8(ra[j]);
            } else {
#pragma unroll
                for (int j = 0; j < 8; ++j) if (j < cnt) acc8(ra[j]);
            }
            if (t + 1 < nb) {
#pragma unroll
                for (int j = 0; j < 8; ++j) ra[j] = rb[j];
            }
        }

        float cdeg = (node < NN) ? (float)deg : 1.f;
        float rc = 1.0f / cdeg;
        float var[8];
#pragma unroll
        for (int i = 0; i < 8; ++i) {
            float mean = s[i] * rc;
            var[i] = fmaxf(q[i] * rc - mean * mean, 0.f);
            if (node >= NN) { mx[i] = 0.f; var[i] = 0.f; }
        }
        // f32 stats (for the VALU g=1 GEMM): [k][n] stride 34
#pragma unroll
        for (int i = 0; i < 8; ++i) {
            Af32[(f0 + i) * 34 + m] = s[i];
            Af32[(64 + f0 + i) * 34 + m] = mx[i];
            Af32[(128 + f0 + i) * 34 + m] = var[i];
        }
        // bf16-hi stats (for the MFMA g=0,2 GEMM): [m][k] pitch 200
        uint4 hv;
        hv.x = pk(s[0], s[1]); hv.y = pk(s[2], s[3]);
        hv.z = pk(s[4], s[5]); hv.w = pk(s[6], s[7]);
        *(uint4*)&Ag[m * 200 + f0] = hv;
        hv.x = pk(mx[0], mx[1]); hv.y = pk(mx[2], mx[3]);
        hv.z = pk(mx[4], mx[5]); hv.w = pk(mx[6], mx[7]);
        *(uint4*)&Ag[m * 200 + 64 + f0] = hv;
        hv.x = pk(var[0], var[1]); hv.y = pk(var[2], var[3]);
        hv.z = pk(var[4], var[5]); hv.w = pk(var[6], var[7]);
        *(uint4*)&Ag[m * 200 + 128 + f0] = hv;
        if (l8 == 0) degs[m] = cdeg;
    }
    __syncthreads();

    // ---- load MFMA A fragments (then Ag is dead; hsf overlays it) ----
    const int ln = tid & 63, wvi = tid >> 6;
    const int quad = ln >> 4, l16 = ln & 15;
    const int mtile = wvi >> 1;          // 0..1
    const int nt0 = (wvi & 1) * 2;       // ntiles nt0, nt0+1

    const ushort* Arow = Ag + (mtile * 16 + l16) * 200 + quad * 8;
    short8 afh[6];
    afh[0] = *(const short8*)(Arow + 0);    // s    k 0..31
    afh[1] = *(const short8*)(Arow + 32);   // s    k 32..63
    afh[2] = *(const short8*)(Arow + 64);   // max  k 0..31
    afh[3] = *(const short8*)(Arow + 96);   // max  k 32..63
    afh[4] = *(const short8*)(Arow + 128);  // var  k 0..31
    afh[5] = *(const short8*)(Arow + 160);  // var  k 32..63
    __syncthreads();   // all frag loads done -> hsf region free

    // ---- MFMA: g=0 and g=2 chunks, bf16-hi ----
    floatx4 accA[2][2], accB[2][2];
#pragma unroll
    for (int gi = 0; gi < 2; ++gi)
#pragma unroll
        for (int n = 0; n < 2; ++n) {
            accA[gi][n] = (floatx4){0.f, 0.f, 0.f, 0.f};
            accB[gi][n] = (floatx4){0.f, 0.f, 0.f, 0.f};
        }
#pragma unroll
    for (int gi = 0; gi < 2; ++gi) {
        const int g = gi * 2;
#pragma unroll
        for (int kb = 0; kb < 8; ++kb) {
            const int am = (kb < 4) ? kb : ((kb < 6) ? (kb - 4) : (kb - 2));
            const int boff = (((g * 8 + kb) * 4 + nt0) * 512) + ln * 8;
            short8 bh0 = *(const short8*)(Wbh + boff);
            short8 bh1 = *(const short8*)(Wbh + boff + 512);
            if (kb == 4 || kb == 5) {
                accB[gi][0] = __builtin_amdgcn_mfma_f32_16x16x32_bf16(afh[am], bh0, accB[gi][0], 0, 0, 0);
                accB[gi][1] = __builtin_amdgcn_mfma_f32_16x16x32_bf16(afh[am], bh1, accB[gi][1], 0, 0, 0);
            } else {
                accA[gi][0] = __builtin_amdgcn_mfma_f32_16x16x32_bf16(afh[am], bh0, accA[gi][0], 0, 0, 0);
                accA[gi][1] = __builtin_amdgcn_mfma_f32_16x16x32_bf16(afh[am], bh1, accA[gi][1], 0, 0, 0);
            }
        }
    }
    // MFMA partial (scales for g=0: 1 and 1/c; g=2: D/c and D/c^2) -> hsf[n][m]
#pragma unroll
    for (int r = 0; r < 4; ++r) {
        int m = mtile * 16 + quad * 4 + r;
        float dg = degs[m], rcd = 1.f / dg;
        float cA2 = DELTA_F * rcd;
        float cB2 = DELTA_F * rcd * rcd;
#pragma unroll
        for (int nt = 0; nt < 2; ++nt) {
            int n = (nt0 + nt) * 16 + l16;
            hsf[n * 34 + m] = accA[0][nt][r] + cA2 * accA[1][nt][r]
                            + rcd * accB[0][nt][r] + cB2 * accB[1][nt][r];
        }
    }

    // ---- f32 VALU GEMM for g=1 chunk (amplified by cnt/DELTA) ----
    const int tx = tid & 15, ty = tid >> 4;
    const int o0 = tx * 4, n0 = ty * 2;
    const float2* const Af2 = (const float2*)Af32;   // stride 17 float2

    float A1[8], B1[8];
#pragma unroll
    for (int i = 0; i < 8; ++i) { A1[i] = 0.f; B1[i] = 0.f; }
#pragma unroll 4
    for (int k = 0; k < 128; ++k) {          // s rows(0..63) + max rows(64..127)
        float2 a = Af2[k * 17 + ty];
        const float4 w = *(const float4*)(Wt1 + k * 64 + o0);
        A1[0] += a.x * w.x; A1[1] += a.x * w.y; A1[2] += a.x * w.z; A1[3] += a.x * w.w;
        A1[4] += a.y * w.x; A1[5] += a.y * w.y; A1[6] += a.y * w.z; A1[7] += a.y * w.w;
    }
#pragma unroll 4
    for (int k = 0; k < 64; ++k) {           // var rows x W rows 192..255
        float2 a = Af2[(128 + k) * 17 + ty];
        const float4 w = *(const float4*)(Wt1 + (192 + k) * 64 + o0);
        A1[0] += a.x * w.x; A1[1] += a.x * w.y; A1[2] += a.x * w.z; A1[3] += a.x * w.w;
        A1[4] += a.y * w.x; A1[5] += a.y * w.y; A1[6] += a.y * w.z; A1[7] += a.y * w.w;
    }
#pragma unroll 4
    for (int k = 0; k < 64; ++k) {           // mean fold: s rows x W rows 128..191
        float2 a = Af2[k * 17 + ty];
        const float4 w = *(const float4*)(Wt1 + (128 + k) * 64 + o0);
        B1[0] += a.x * w.x; B1[1] += a.x * w.y; B1[2] += a.x * w.z; B1[3] += a.x * w.w;
        B1[4] += a.y * w.x; B1[5] += a.y * w.y; B1[6] += a.y * w.z; B1[7] += a.y * w.w;
    }
    __syncthreads();   // all MFMA partials in hsf

    // ---- combine: h = partial + (c/D)*A1 + (1/D)*B1 + x + bias ----
#pragma unroll
    for (int ni = 0; ni < 2; ++ni) {
        int n = n0 + ni;
        int node = node0 + n;
        float dg = degs[n];
        float cA1 = dg * (1.0f / DELTA_F);
        const float cB1 = (1.0f / DELTA_F);
        float4 xv = make_float4(0.f, 0.f, 0.f, 0.f);
        if (node < NN) xv = *(const float4*)(X + (size_t)node * DD + o0);
#pragma unroll
        for (int oi = 0; oi < 4; ++oi) {
            int idx = (o0 + oi) * 34 + n;
            float xa = (oi == 0) ? xv.x : (oi == 1) ? xv.y : (oi == 2) ? xv.z : xv.w;
            hsf[idx] = hsf[idx] + cA1 * A1[ni * 4 + oi] + cB1 * B1[ni * 4 + oi]
                     + xa + mbias[o0 + oi];
        }
    }
    __syncthreads();

    // ---- Lin1 (f32): stream W1t from global, h-pairs from LDS ----
    const float2* const hs2 = (const float2*)hsf;
    float l1[8];
#pragma unroll
    for (int i = 0; i < 8; ++i) l1[i] = 0.f;
#pragma unroll 4
    for (int j = 0; j < 64; ++j) {
        float2 a = hs2[j * 17 + ty];
        const float4 wv4 = *(const float4*)(W1t + j * 64 + o0);
        l1[0] += a.x * wv4.x; l1[1] += a.x * wv4.y; l1[2] += a.x * wv4.z; l1[3] += a.x * wv4.w;
        l1[4] += a.y * wv4.x; l1[5] += a.y * wv4.y; l1[6] += a.y * wv4.z; l1[7] += a.y * wv4.w;
    }
    __syncthreads();
#pragma unroll
    for (int ni = 0; ni < 2; ++ni)
#pragma unroll
        for (int oi = 0; oi < 4; ++oi)
            hsf[(o0 + oi) * 34 + n0 + ni] = fmaxf(l1[ni * 4 + oi] + b1s[o0 + oi], 0.f);
    __syncthreads();

    // ---- Lin2 + outer relu ----
    float l2[8];
#pragma unroll
    for (int i = 0; i < 8; ++i) l2[i] = 0.f;
#pragma unroll 4
    for (int j = 0; j < 64; ++j) {
        float2 a = hs2[j * 17 + ty];
        const float4 wv4 = *(const float4*)(W2t + j * 64 + o0);
        l2[0] += a.x * wv4.x; l2[1] += a.x * wv4.y; l2[2] += a.x * wv4.z; l2[3] += a.x * wv4.w;
        l2[4] += a.y * wv4.x; l2[5] += a.y * wv4.y; l2[6] += a.y * wv4.z; l2[7] += a.y * wv4.w;
    }
    __syncthreads();
#pragma unroll
    for (int ni = 0; ni < 2; ++ni) {
        int node = node0 + n0 + ni;
        float4 yv;
        yv.x = fmaxf(l2[ni * 4 + 0] + b2s[o0 + 0], 0.f);
        yv.y = fmaxf(l2[ni * 4 + 1] + b2s[o0 + 1], 0.f);
        yv.z = fmaxf(l2[ni * 4 + 2] + b2s[o0 + 2], 0.f);
        yv.w = fmaxf(l2[ni * 4 + 3] + b2s[o0 + 3], 0.f);
        if (node < NN) *(float4*)(Y + (size_t)node * DD + o0) = yv;
        hsf[(o0 + 0) * 34 + n0 + ni] = yv.x;
        hsf[(o0 + 1) * 34 + n0 + ni] = yv.y;
        hsf[(o0 + 2) * 34 + n0 + ni] = yv.z;
        hsf[(o0 + 3) * 34 + n0 + ni] = yv.w;
    }
    __syncthreads();

    // ---- BN partial sums ----
    if (tid < 64) {
        float s = 0.f, sq = 0.f;
        int lim = NN - node0;
        if (lim > 32) lim = 32;
        for (int n = 0; n < lim; ++n) {
            float v = hsf[tid * 34 + n];
            s += v;
            sq += v * v;
        }
        atomicAdd(&bnstat[tid], s);
        atomicAdd(&bnstat[64 + tid], sq);
    }
}

// ---------------- BN finalize+apply (+bf16 table write, + fused pool) ----------------
__global__ __launch_bounds__(256) void k_bnapply(
    const float* __restrict__ Y, const float* __restrict__ bs,
    const float* __restrict__ g, const float* __restrict__ b,
    float* __restrict__ XO, ushort* __restrict__ XH,
    const int* __restrict__ batch, float* __restrict__ gpool, int do_pool) {
    __shared__ float sc[64], shf[64], pool[512];
    int tid = threadIdx.x;
    if (tid < 64) {
        float mean = bs[tid] * (1.f / NN);
        float var = fmaxf(bs[64 + tid] * (1.f / NN) - mean * mean, 0.f);
        float inv = rsqrtf(var + BN_EPS_F);
        float s = g[tid] * inv;
        sc[tid] = s;
        shf[tid] = b[tid] - mean * s;
    }
    __syncthreads();
    int i = blockIdx.x * 256 + tid;  // float4 index
    int n = i >> 4, fq = (i & 15) * 4;
    float4 r = make_float4(0.f, 0.f, 0.f, 0.f);
    bool valid = i < NN * 16;
    if (valid) {
        float4 y = *(const float4*)(Y + (size_t)i * 4);
        r.x = y.x * sc[fq + 0] + shf[fq + 0];
        r.y = y.y * sc[fq + 1] + shf[fq + 1];
        r.z = y.z * sc[fq + 2] + shf[fq + 2];
        r.w = y.w * sc[fq + 3] + shf[fq + 3];
        *(float4*)(XO + (size_t)i * 4) = r;
        ushort4 h;
        h.x = f2bu(r.x); h.y = f2bu(r.y); h.z = f2bu(r.z); h.w = f2bu(r.w);
        *(ushort4*)(XH + (size_t)i * 4) = h;
    }
    if (do_pool) {
        int nfirst = blockIdx.x * 16;
        int nlast = nfirst + 15;
        if (nlast >= NN) nlast = NN - 1;
        int gmin = batch[nfirst], gmax = batch[nlast];
        int span = gmax - gmin + 1;
        if (span <= 8) {
            for (int j = tid; j < span * 64; j += 256) pool[j] = 0.f;
            __syncthreads();
            if (valid) {
                int gb = batch[n] - gmin;
                atomicAdd(&pool[gb * 64 + fq + 0], r.x);
                atomicAdd(&pool[gb * 64 + fq + 1], r.y);
                atomicAdd(&pool[gb * 64 + fq + 2], r.z);
                atomicAdd(&pool[gb * 64 + fq + 3], r.w);
            }
            __syncthreads();
            for (int j = tid; j < span * 64; j += 256)
                atomicAdd(&gpool[(size_t)(gmin + (j >> 6)) * 64 + (j & 63)], pool[j]);
        } else {
            if (valid) {
                float* gp = gpool + (size_t)batch[n] * DD + fq;
                atomicAdd(gp + 0, r.x);
                atomicAdd(gp + 1, r.y);
                atomicAdd(gp + 2, r.z);
                atomicAdd(gp + 3, r.w);
            }
        }
    }
}

// ---------------- head: fc1+relu, fc2, log_softmax ----------------
__global__ __launch_bounds__(256) void k_head(const float* __restrict__ gpool,
                                              const float* __restrict__ fc1W, const float* __restrict__ fc1b,
                                              const float* __restrict__ fc2W, const float* __restrict__ fc2b,
                                              float* __restrict__ out) {
    __shared__ float sh[12576];
    float* const gs = sh;
    float* const w1t = sh + 4096;
    float* const z1s = sh + 8256;
    float* const b1s = sh + 12416;
    float* const b2s = sh + 12480;
    float* const w2t = sh;
    float* const z2s = sh + 4096;

    int tid = threadIdx.x;
    for (int i = tid; i < 4096; i += 256) {
        gs[i] = gpool[i];
        int o = i >> 6, j = i & 63;
        w1t[j * 65 + o] = fc1W[i];
    }
    if (tid < 64) b1s[tid] = fc1b[tid];
    if (tid < 32) b2s[tid] = fc2b[tid];
    __syncthreads();
    {
        int tx = tid & 15, ty = tid >> 4, o0 = tx * 4, g0 = ty * 4;
        float acc[16];
#pragma unroll
        for (int i = 0; i < 16; ++i) acc[i] = 0.f;
        for (int j = 0; j < 64; ++j) {
            float w0 = w1t[j * 65 + o0 + 0], w1 = w1t[j * 65 + o0 + 1];
            float w2 = w1t[j * 65 + o0 + 2], w3 = w1t[j * 65 + o0 + 3];
#pragma unroll
            for (int gi = 0; gi < 4; ++gi) {
                float a = gs[(g0 + gi) * 64 + j];
                acc[gi * 4 + 0] += a * w0; acc[gi * 4 + 1] += a * w1;
                acc[gi * 4 + 2] += a * w2; acc[gi * 4 + 3] += a * w3;
            }
        }
        __syncthreads();
#pragma unroll
        for (int gi = 0; gi < 4; ++gi)
#pragma unroll
            for (int oi = 0; oi < 4; ++oi)
                z1s[(g0 + gi) * 65 + o0 + oi] = fmaxf(acc[gi * 4 + oi] + b1s[o0 + oi], 0.f);
    }
    for (int i = tid; i < 2048; i += 256) {
        int o = i >> 6, j = i & 63;
        w2t[j * 33 + o] = fc2W[i];
    }
    __syncthreads();
    {
        int tx = tid & 7, ty = tid >> 3, o0 = tx * 4, g0 = ty * 2;
        float acc[8];
#pragma unroll
        for (int i = 0; i < 8; ++i) acc[i] = 0.f;
        for (int j = 0; j < 64; ++j) {
            float w0 = w2t[j * 33 + o0 + 0], w1 = w2t[j * 33 + o0 + 1];
            float w2 = w2t[j * 33 + o0 + 2], w3 = w2t[j * 33 + o0 + 3];
            float a0 = z1s[(g0 + 0) * 65 + j];
            float a1 = z1s[(g0 + 1) * 65 + j];
            acc[0] += a0 * w0; acc[1] += a0 * w1; acc[2] += a0 * w2; acc[3] += a0 * w3;
            acc[4] += a1 * w0; acc[5] += a1 * w1; acc[6] += a1 * w2; acc[7] += a1 * w3;
        }
#pragma unroll
        for (int gi = 0; gi < 2; ++gi)
#pragma unroll
            for (int oi = 0; oi < 4; ++oi)
                z2s[(g0 + gi) * 33 + o0 + oi] = acc[gi * 4 + oi] + b2s[o0 + oi];
    }
    __syncthreads();
    if (tid < 64) {
        float m = -3.402823466e38f;
        for (int c = 0; c < DOUT; ++c) m = fmaxf(m, z2s[tid * 33 + c]);
        float s = 0.f;
        for (int c = 0; c < DOUT; ++c) s += expf(z2s[tid * 33 + c] - m);
        float lse = m + logf(s);
        for (int c = 0; c < DOUT; ++c)
            out[tid * DOUT + c] = z2s[tid * 33 + c] - lse;
    }
}

extern "C" void kernel_launch(void* const* d_in, const int* in_sizes, int n_in,
                              void* d_out, int out_size, void* d_ws, size_t ws_size,
                              hipStream_t stream) {
    const float* x = (const float*)d_in[0];
    const int* ei = (const int*)d_in[1];
    const int* src = ei;
    const int* dst = ei + NE;
    const int* batch = (const int*)d_in[2];
    const float *mlpW[3], *mlpB[3], *w1[3], *bb1[3], *w2[3], *bb2[3], *bng[3], *bnb[3];
    for (int l = 0; l < 3; ++l) {
        mlpW[l] = (const float*)d_in[3 + 6 * l];
        mlpB[l] = (const float*)d_in[4 + 6 * l];
        w1[l]   = (const float*)d_in[5 + 6 * l];
        bb1[l]  = (const float*)d_in[6 + 6 * l];
        w2[l]   = (const float*)d_in[7 + 6 * l];
        bb2[l]  = (const float*)d_in[8 + 6 * l];
        bng[l]  = (const float*)d_in[21 + 2 * l];
        bnb[l]  = (const float*)d_in[22 + 2 * l];
    }
    const float* fc1W = (const float*)d_in[27];
    const float* fc1b = (const float*)d_in[28];
    const float* fc2W = (const float*)d_in[29];
    const float* fc2b = (const float*)d_in[30];
    float* out = (float*)d_out;

    char* ws = (char*)d_ws;
    size_t off = 0;
    auto alloc = [&](size_t bytes) -> void* {
        void* p = ws + off;
        off = (off + bytes + 511) & ~(size_t)511;
        return p;
    };
    int* counts    = (int*)alloc((size_t)NN * 4);
    int* row_ptr   = (int*)alloc((size_t)(NN + 1) * 4);
    int* cursor    = (int*)alloc((size_t)NN * 4);
    int* blockSums = (int*)alloc(256 * 4);
    int* blockBase = (int*)alloc(256 * 4);
    int* csr_src   = (int*)alloc((size_t)NE * 4);
    float* XB      = (float*)alloc((size_t)NN * DD * 4);
    float* Yb      = (float*)alloc((size_t)NN * DD * 4);
    ushort* XH     = (ushort*)alloc((size_t)NN * DD * 2);
    ushort* Wb     = (ushort*)alloc((size_t)3 * 49152 * 2);
    float* Wt1     = (float*)alloc((size_t)3 * 16384 * 4);
    float* Wsm     = (float*)alloc((size_t)6 * 4096 * 4);
    float* bnstat  = (float*)alloc(384 * 4);
    float* gpool   = (float*)alloc((size_t)NGRAPH * DD * 4);
    (void)ws_size; (void)in_sizes; (void)n_in; (void)out_size;

    k_init<<<196, 256, 0, stream>>>(counts, bnstat, gpool);
    k_count<<<6250, 256, 0, stream>>>(dst, counts);
    k_scan_a<<<196, 256, 0, stream>>>(counts, blockSums);
    k_scan_b<<<1, 256, 0, stream>>>(blockSums, blockBase);
    k_scan_c<<<196, 256, 0, stream>>>(counts, blockBase, row_ptr, cursor);
    k_fill<<<6250, 256, 0, stream>>>(src, dst, cursor, csr_src);
    k_wprep<<<864, 256, 0, stream>>>(mlpW[0], mlpW[1], mlpW[2],
                                     w1[0], w2[0], w1[1], w2[1], w1[2], w2[2],
                                     Wb, Wt1, Wsm);
    k_x2h<<<3125, 256, 0, stream>>>(x, XH);

    const float* Xin = x;
    for (int l = 0; l < 3; ++l) {
        k_fused<<<1563, 256, 0, stream>>>(Xin, XH, row_ptr, csr_src,
                                          Wb + (size_t)l * 49152,
                                          Wt1 + (size_t)l * 16384,
                                          mlpB[l],
                                          Wsm + (size_t)(2 * l) * 4096, bb1[l],
                                          Wsm + (size_t)(2 * l + 1) * 4096, bb2[l],
                                          Yb, bnstat + l * 128);
        k_bnapply<<<3125, 256, 0, stream>>>(Yb, bnstat + l * 128, bng[l], bnb[l],
                                            XB, XH, batch, gpool, (l == 2) ? 1 : 0);
        Xin = XB;
    }
    k_head<<<1, 256, 0, stream>>>(gpool, fc1W, fc1b, fc2W, fc2b, out);
}

// Round 11
// 748.589 us; speedup vs baseline: 1.8802x; 1.2982x over previous
//
#include <hip/hip_runtime.h>

#define NN 50000
#define NE 1600000
#define DD 64
#define NGRAPH 64
#define DOUT 32
#define DELTA_F 2.5749f
#define BN_EPS_F 1e-5f

typedef unsigned short ushort;
typedef __attribute__((ext_vector_type(8))) short short8;
typedef __attribute__((ext_vector_type(4))) float floatx4;

static __device__ __forceinline__ float blo(unsigned u) {
    return __uint_as_float(u << 16);
}
static __device__ __forceinline__ float bhi(unsigned u) {
    return __uint_as_float(u & 0xFFFF0000u);
}
static __device__ __forceinline__ ushort f2bu(float f) {
    unsigned u = __float_as_uint(f);
    unsigned r = (u + 0x7FFF + ((u >> 16) & 1)) >> 16;   // round-to-nearest-even
    return (ushort)r;
}
static __device__ __forceinline__ unsigned pk(float a, float b) {
    return ((unsigned)f2bu(b) << 16) | (unsigned)f2bu(a);
}

// ---------------- init ----------------
__global__ void k_init(int* __restrict__ counts, float* __restrict__ bnstat,
                       float* __restrict__ gpool) {
    int i = blockIdx.x * 256 + threadIdx.x;
    if (i < NN) counts[i] = 0;
    if (i < 384) bnstat[i] = 0.f;
    if (i < NGRAPH * DD) gpool[i] = 0.f;
}

// ---------------- CSR build ----------------
__global__ void k_count(const int* __restrict__ dst, int* __restrict__ counts) {
    int e = blockIdx.x * 256 + threadIdx.x;
    if (e < NE) atomicAdd(&counts[dst[e]], 1);
}

__global__ void k_scan_a(const int* __restrict__ counts, int* __restrict__ blockSums) {
    __shared__ int red[256];
    int tid = threadIdx.x;
    int gid = blockIdx.x * 256 + tid;
    int v = (gid < NN) ? counts[gid] : 0;
    red[tid] = v;
    __syncthreads();
    for (int s = 128; s > 0; s >>= 1) {
        if (tid < s) red[tid] += red[tid + s];
        __syncthreads();
    }
    if (tid == 0) blockSums[blockIdx.x] = red[0];
}

__global__ void k_scan_b(const int* __restrict__ blockSums, int* __restrict__ blockBase) {
    __shared__ int sh[256];
    int tid = threadIdx.x;
    int v = (tid < 196) ? blockSums[tid] : 0;
    sh[tid] = v;
    __syncthreads();
    for (int off = 1; off < 256; off <<= 1) {
        int t = (tid >= off) ? sh[tid - off] : 0;
        __syncthreads();
        sh[tid] += t;
        __syncthreads();
    }
    blockBase[tid] = sh[tid] - v;  // exclusive
}

__global__ void k_scan_c(const int* __restrict__ counts, const int* __restrict__ blockBase,
                         int* __restrict__ row_ptr, int* __restrict__ cursor) {
    __shared__ int sh[256];
    int tid = threadIdx.x;
    int gid = blockIdx.x * 256 + tid;
    int v = (gid < NN) ? counts[gid] : 0;
    sh[tid] = v;
    __syncthreads();
    for (int off = 1; off < 256; off <<= 1) {
        int t = (tid >= off) ? sh[tid - off] : 0;
        __syncthreads();
        sh[tid] += t;
        __syncthreads();
    }
    int excl = blockBase[blockIdx.x] + sh[tid] - v;
    if (gid <= NN) {
        row_ptr[gid] = excl;
        if (gid < NN) cursor[gid] = excl;
    }
}

__global__ void k_fill(const int* __restrict__ src, const int* __restrict__ dst,
                       int* __restrict__ cursor, int* __restrict__ csr_src) {
    int e = blockIdx.x * 256 + threadIdx.x;
    if (e < NE) {
        int d = dst[e];
        int pos = atomicAdd(&cursor[d], 1);
        csr_src[pos] = src[e];
    }
}

// ---------------- weight prep ----------------
// Wb: bf16 MFMA B-fragment order (hi only). Per layer: [g 3][kb 8][t 4][lane 64][j 8]
//   value = W[o=t*16+(lane&15)][k_global = g*256 + kb*32 + (lane>>4)*8 + j]
// Wt1: f32 g=1 chunk transposed [layer][k 256][o 64]  (the cnt/DELTA-amplified chunk)
// Wsm: f32 transposed 64x64 (Lin1/Lin2).
__global__ void k_wprep(const float* __restrict__ w0, const float* __restrict__ w1,
                        const float* __restrict__ w2,
                        const float* __restrict__ a0, const float* __restrict__ a1,
                        const float* __restrict__ a2, const float* __restrict__ a3,
                        const float* __restrict__ a4, const float* __restrict__ a5,
                        ushort* __restrict__ Wb, float* __restrict__ Wt1,
                        float* __restrict__ Wsm) {
    int i = blockIdx.x * 256 + threadIdx.x;
    if (i < 3 * 49152) {
        int layer = i / 49152, r = i % 49152;
        const float* w = (layer == 0) ? w0 : ((layer == 1) ? w1 : w2);
        int g = r / 16384, r2 = r % 16384;
        int kb = r2 >> 11, r3 = r2 & 2047;
        int t = r3 >> 9, r4 = r3 & 511;
        int l = r4 >> 3, j = r4 & 7;
        int k = kb * 32 + (l >> 4) * 8 + j;
        int o = t * 16 + (l & 15);
        Wb[i] = f2bu(w[o * 768 + g * 256 + k]);
    } else if (i < 3 * 49152 + 3 * 16384) {
        int i2 = i - 3 * 49152;
        int layer = i2 / 16384, r = i2 % 16384;
        const float* w = (layer == 0) ? w0 : ((layer == 1) ? w1 : w2);
        int k = r >> 6, o = r & 63;
        Wt1[i2] = w[o * 768 + 256 + k];
    } else if (i < 3 * 49152 + 3 * 16384 + 6 * 4096) {
        int r2 = i - 3 * 49152 - 3 * 16384;
        int l = r2 >> 12, r = r2 & 4095;
        const float* w = (l == 0) ? a0 : (l == 1) ? a1 : (l == 2) ? a2
                       : (l == 3) ? a3 : (l == 4) ? a4 : a5;
        int o = r >> 6, j = r & 63;
        Wsm[l * 4096 + j * 64 + o] = w[r];
    }
}

// ---------------- x (f32) -> bf16 gather table ----------------
__global__ void k_x2h(const float* __restrict__ x, ushort* __restrict__ XH) {
    int i = blockIdx.x * 256 + threadIdx.x;
    if (i < NN * 16) {
        float4 v = *(const float4*)(x + (size_t)i * 4);
        ushort4 h;
        h.x = f2bu(v.x); h.y = f2bu(v.y); h.z = f2bu(v.z); h.w = f2bu(v.w);
        *(ushort4*)(XH + (size_t)i * 4) = h;
    }
}

// ======================================================================
// Fused layer, Ntile = 32 nodes/block.  Hybrid GEMM:
//   g=1 (cnt/DELTA-amplified chunk): f32 VALU from f32 stats (error-critical)
//   g=0,2 (scales 1, DELTA/cnt):     MFMA bf16-hi (error ≤ ~0.1 at output)
// Gather: 8-lane groups, 4-row double-buffered batches (low VGPR pressure;
//   R10's 8-row buffers spilled to scratch -> 400+ MB HBM traffic).
// LDS (39808 B): Af32[k192][pad34] f32 | Ag[32][200] bf16 (overlaid by hsf
//   after frag loads) | biases/degs.
// __launch_bounds__(256,3): VGPR cap ~168 so the gather pipeline never spills;
//   LDS still admits up to 4 blocks/CU at runtime.
// ======================================================================
__global__ __launch_bounds__(256, 3) void k_fused(
    const float* __restrict__ X, const ushort* __restrict__ XH,
    const int* __restrict__ row_ptr, const int* __restrict__ csr_src,
    const ushort* __restrict__ Wbh, const float* __restrict__ Wt1,
    const float* __restrict__ mlp_b,
    const float* __restrict__ W1t, const float* __restrict__ b1,
    const float* __restrict__ W2t, const float* __restrict__ b2,
    float* __restrict__ Y, float* __restrict__ bnstat) {
    __shared__ __align__(16) char smem[39808];
    float* const Af32 = (float*)smem;                 // 192 x 34 f32 = 26112 B
    ushort* const Ag = (ushort*)(smem + 26112);       // 32 x 200 bf16 = 12800 B
    float* const hsf = (float*)(smem + 26112);        // overlays Ag (8704 B)
    float* const mbias = (float*)(smem + 38912);
    float* const b1s = mbias + 64;
    float* const b2s = mbias + 128;
    float* const degs = mbias + 192;                  // 32

    const int tid = threadIdx.x;
    const int node0 = blockIdx.x * 32;

    if (tid < 64) {
        mbias[tid] = mlp_b[tid];
        b1s[tid] = b1[tid];
        b2s[tid] = b2[tid];
    }

    // ---- gather: 32 groups of 8 lanes; 4-row double-buffered batches ----
    {
        const int l8 = tid & 7;
        const int m = tid >> 3;                // 0..31
        const int node = node0 + m;
        const int f0 = l8 * 8;
        const ushort* Xp = XH + f0;

        float s[8], q[8], mx[8];
#pragma unroll
        for (int i = 0; i < 8; ++i) { s[i] = 0.f; q[i] = 0.f; mx[i] = -3.402823466e38f; }

        auto acc8 = [&](const uint4& rr) {
            float v0 = blo(rr.x), v1 = bhi(rr.x);
            float v2 = blo(rr.y), v3 = bhi(rr.y);
            float v4 = blo(rr.z), v5 = bhi(rr.z);
            float v6 = blo(rr.w), v7 = bhi(rr.w);
            s[0] += v0; q[0] = fmaf(v0, v0, q[0]); mx[0] = fmaxf(mx[0], v0);
            s[1] += v1; q[1] = fmaf(v1, v1, q[1]); mx[1] = fmaxf(mx[1], v1);
            s[2] += v2; q[2] = fmaf(v2, v2, q[2]); mx[2] = fmaxf(mx[2], v2);
            s[3] += v3; q[3] = fmaf(v3, v3, q[3]); mx[3] = fmaxf(mx[3], v3);
            s[4] += v4; q[4] = fmaf(v4, v4, q[4]); mx[4] = fmaxf(mx[4], v4);
            s[5] += v5; q[5] = fmaf(v5, v5, q[5]); mx[5] = fmaxf(mx[5], v5);
            s[6] += v6; q[6] = fmaf(v6, v6, q[6]); mx[6] = fmaxf(mx[6], v6);
            s[7] += v7; q[7] = fmaf(v7, v7, q[7]); mx[7] = fmaxf(mx[7], v7);
        };

        int beg = 0, end = 0;
        if (node < NN) { beg = row_ptr[node]; end = row_ptr[node + 1]; }
        const int deg = end - beg;
        const int nb = (deg + 3) >> 2;

        uint4 ra[4], rb[4];
        int ia[4];
        if (nb > 0) {
#pragma unroll
            for (int j = 0; j < 4; ++j) {
                int e = beg + j;
                ia[j] = csr_src[(e < end) ? e : end - 1];
            }
#pragma unroll
            for (int j = 0; j < 4; ++j)
                ra[j] = *(const uint4*)(Xp + (size_t)ia[j] * 64);
            if (nb > 1) {
#pragma unroll
                for (int j = 0; j < 4; ++j) {
                    int e = beg + 4 + j;
                    ia[j] = csr_src[(e < end) ? e : end - 1];
                }
            }
        }
        for (int t = 0; t < nb; ++t) {
            if (t + 1 < nb) {
#pragma unroll
                for (int j = 0; j < 4; ++j)
                    rb[j] = *(const uint4*)(Xp + (size_t)ia[j] * 64);
            }
            if (t + 2 < nb) {
                int b2e = beg + (t + 2) * 4;
#pragma unroll
                for (int j = 0; j < 4; ++j) {
                    int e = b2e + j;
                    ia[j] = csr_src[(e < end) ? e : end - 1];
                }
            }
            int cnt = end - (beg + t * 4);
            if (cnt >= 4) {
#pragma unroll
                for (int j = 0; j < 4; ++j) acc8(ra[j]);
            } else {
#pragma unroll
                for (int j = 0; j < 4; ++j) if (j < cnt) acc8(ra[j]);
            }
            if (t + 1 < nb) {
#pragma unroll
                for (int j = 0; j < 4; ++j) ra[j] = rb[j];
            }
        }

        float cdeg = (node < NN) ? (float)deg : 1.f;
        float rc = 1.0f / cdeg;
        float var[8];
#pragma unroll
        for (int i = 0; i < 8; ++i) {
            float mean = s[i] * rc;
            var[i] = fmaxf(q[i] * rc - mean * mean, 0.f);
            if (node >= NN) { mx[i] = 0.f; var[i] = 0.f; }
        }
        // f32 stats (for the VALU g=1 GEMM): [k][n] stride 34
#pragma unroll
        for (int i = 0; i < 8; ++i) {
            Af32[(f0 + i) * 34 + m] = s[i];
            Af32[(64 + f0 + i) * 34 + m] = mx[i];
            Af32[(128 + f0 + i) * 34 + m] = var[i];
        }
        // bf16-hi stats (for the MFMA g=0,2 GEMM): [m][k] pitch 200
        uint4 hv;
        hv.x = pk(s[0], s[1]); hv.y = pk(s[2], s[3]);
        hv.z = pk(s[4], s[5]); hv.w = pk(s[6], s[7]);
        *(uint4*)&Ag[m * 200 + f0] = hv;
        hv.x = pk(mx[0], mx[1]); hv.y = pk(mx[2], mx[3]);
        hv.z = pk(mx[4], mx[5]); hv.w = pk(mx[6], mx[7]);
        *(uint4*)&Ag[m * 200 + 64 + f0] = hv;
        hv.x = pk(var[0], var[1]); hv.y = pk(var[2], var[3]);
        hv.z = pk(var[4], var[5]); hv.w = pk(var[6], var[7]);
        *(uint4*)&Ag[m * 200 + 128 + f0] = hv;
        if (l8 == 0) degs[m] = cdeg;
    }
    __syncthreads();

    // ---- load MFMA A fragments (then Ag is dead; hsf overlays it) ----
    const int ln = tid & 63, wvi = tid >> 6;
    const int quad = ln >> 4, l16 = ln & 15;
    const int mtile = wvi >> 1;          // 0..1
    const int nt0 = (wvi & 1) * 2;       // ntiles nt0, nt0+1

    const ushort* Arow = Ag + (mtile * 16 + l16) * 200 + quad * 8;
    short8 afh[6];
    afh[0] = *(const short8*)(Arow + 0);    // s    k 0..31
    afh[1] = *(const short8*)(Arow + 32);   // s    k 32..63
    afh[2] = *(const short8*)(Arow + 64);   // max  k 0..31
    afh[3] = *(const short8*)(Arow + 96);   // max  k 32..63
    afh[4] = *(const short8*)(Arow + 128);  // var  k 0..31
    afh[5] = *(const short8*)(Arow + 160);  // var  k 32..63
    __syncthreads();   // all frag loads done -> hsf region free

    // ---- MFMA: g=0 and g=2 chunks, bf16-hi ----
    floatx4 accA[2][2], accB[2][2];
#pragma unroll
    for (int gi = 0; gi < 2; ++gi)
#pragma unroll
        for (int n = 0; n < 2; ++n) {
            accA[gi][n] = (floatx4){0.f, 0.f, 0.f, 0.f};
            accB[gi][n] = (floatx4){0.f, 0.f, 0.f, 0.f};
        }
#pragma unroll
    for (int gi = 0; gi < 2; ++gi) {
        const int g = gi * 2;
#pragma unroll
        for (int kb = 0; kb < 8; ++kb) {
            const int am = (kb < 4) ? kb : ((kb < 6) ? (kb - 4) : (kb - 2));
            const int boff = (((g * 8 + kb) * 4 + nt0) * 512) + ln * 8;
            short8 bh0 = *(const short8*)(Wbh + boff);
            short8 bh1 = *(const short8*)(Wbh + boff + 512);
            if (kb == 4 || kb == 5) {
                accB[gi][0] = __builtin_amdgcn_mfma_f32_16x16x32_bf16(afh[am], bh0, accB[gi][0], 0, 0, 0);
                accB[gi][1] = __builtin_amdgcn_mfma_f32_16x16x32_bf16(afh[am], bh1, accB[gi][1], 0, 0, 0);
            } else {
                accA[gi][0] = __builtin_amdgcn_mfma_f32_16x16x32_bf16(afh[am], bh0, accA[gi][0], 0, 0, 0);
                accA[gi][1] = __builtin_amdgcn_mfma_f32_16x16x32_bf16(afh[am], bh1, accA[gi][1], 0, 0, 0);
            }
        }
    }
    // MFMA partial (scales for g=0: 1 and 1/c; g=2: D/c and D/c^2) -> hsf[n][m]
#pragma unroll
    for (int r = 0; r < 4; ++r) {
        int m = mtile * 16 + quad * 4 + r;
        float dg = degs[m], rcd = 1.f / dg;
        float cA2 = DELTA_F * rcd;
        float cB2 = DELTA_F * rcd * rcd;
#pragma unroll
        for (int nt = 0; nt < 2; ++nt) {
            int n = (nt0 + nt) * 16 + l16;
            hsf[n * 34 + m] = accA[0][nt][r] + cA2 * accA[1][nt][r]
                            + rcd * accB[0][nt][r] + cB2 * accB[1][nt][r];
        }
    }

    // ---- f32 VALU GEMM for g=1 chunk (amplified by cnt/DELTA) ----
    const int tx = tid & 15, ty = tid >> 4;
    const int o0 = tx * 4, n0 = ty * 2;
    const float2* const Af2 = (const float2*)Af32;   // stride 17 float2

    float A1[8], B1[8];
#pragma unroll
    for (int i = 0; i < 8; ++i) { A1[i] = 0.f; B1[i] = 0.f; }
#pragma unroll 4
    for (int k = 0; k < 128; ++k) {          // s rows(0..63) + max rows(64..127)
        float2 a = Af2[k * 17 + ty];
        const float4 w = *(const float4*)(Wt1 + k * 64 + o0);
        A1[0] += a.x * w.x; A1[1] += a.x * w.y; A1[2] += a.x * w.z; A1[3] += a.x * w.w;
        A1[4] += a.y * w.x; A1[5] += a.y * w.y; A1[6] += a.y * w.z; A1[7] += a.y * w.w;
    }
#pragma unroll 4
    for (int k = 0; k < 64; ++k) {           // var rows x W rows 192..255
        float2 a = Af2[(128 + k) * 17 + ty];
        const float4 w = *(const float4*)(Wt1 + (192 + k) * 64 + o0);
        A1[0] += a.x * w.x; A1[1] += a.x * w.y; A1[2] += a.x * w.z; A1[3] += a.x * w.w;
        A1[4] += a.y * w.x; A1[5] += a.y * w.y; A1[6] += a.y * w.z; A1[7] += a.y * w.w;
    }
#pragma unroll 4
    for (int k = 0; k < 64; ++k) {           // mean fold: s rows x W rows 128..191
        float2 a = Af2[k * 17 + ty];
        const float4 w = *(const float4*)(Wt1 + (128 + k) * 64 + o0);
        B1[0] += a.x * w.x; B1[1] += a.x * w.y; B1[2] += a.x * w.z; B1[3] += a.x * w.w;
        B1[4] += a.y * w.x; B1[5] += a.y * w.y; B1[6] += a.y * w.z; B1[7] += a.y * w.w;
    }
    __syncthreads();   // all MFMA partials in hsf

    // ---- combine: h = partial + (c/D)*A1 + (1/D)*B1 + x + bias ----
#pragma unroll
    for (int ni = 0; ni < 2; ++ni) {
        int n = n0 + ni;
        int node = node0 + n;
        float dg = degs[n];
        float cA1 = dg * (1.0f / DELTA_F);
        const float cB1 = (1.0f / DELTA_F);
        float4 xv = make_float4(0.f, 0.f, 0.f, 0.f);
        if (node < NN) xv = *(const float4*)(X + (size_t)node * DD + o0);
#pragma unroll
        for (int oi = 0; oi < 4; ++oi) {
            int idx = (o0 + oi) * 34 + n;
            float xa = (oi == 0) ? xv.x : (oi == 1) ? xv.y : (oi == 2) ? xv.z : xv.w;
            hsf[idx] = hsf[idx] + cA1 * A1[ni * 4 + oi] + cB1 * B1[ni * 4 + oi]
                     + xa + mbias[o0 + oi];
        }
    }
    __syncthreads();

    // ---- Lin1 (f32): stream W1t from global, h-pairs from LDS ----
    const float2* const hs2 = (const float2*)hsf;
    float l1[8];
#pragma unroll
    for (int i = 0; i < 8; ++i) l1[i] = 0.f;
#pragma unroll 4
    for (int j = 0; j < 64; ++j) {
        float2 a = hs2[j * 17 + ty];
        const float4 wv4 = *(const float4*)(W1t + j * 64 + o0);
        l1[0] += a.x * wv4.x; l1[1] += a.x * wv4.y; l1[2] += a.x * wv4.z; l1[3] += a.x * wv4.w;
        l1[4] += a.y * wv4.x; l1[5] += a.y * wv4.y; l1[6] += a.y * wv4.z; l1[7] += a.y * wv4.w;
    }
    __syncthreads();
#pragma unroll
    for (int ni = 0; ni < 2; ++ni)
#pragma unroll
        for (int oi = 0; oi < 4; ++oi)
            hsf[(o0 + oi) * 34 + n0 + ni] = fmaxf(l1[ni * 4 + oi] + b1s[o0 + oi], 0.f);
    __syncthreads();

    // ---- Lin2 + outer relu ----
    float l2[8];
#pragma unroll
    for (int i = 0; i < 8; ++i) l2[i] = 0.f;
#pragma unroll 4
    for (int j = 0; j < 64; ++j) {
        float2 a = hs2[j * 17 + ty];
        const float4 wv4 = *(const float4*)(W2t + j * 64 + o0);
        l2[0] += a.x * wv4.x; l2[1] += a.x * wv4.y; l2[2] += a.x * wv4.z; l2[3] += a.x * wv4.w;
        l2[4] += a.y * wv4.x; l2[5] += a.y * wv4.y; l2[6] += a.y * wv4.z; l2[7] += a.y * wv4.w;
    }
    __syncthreads();
#pragma unroll
    for (int ni = 0; ni < 2; ++ni) {
        int node = node0 + n0 + ni;
        float4 yv;
        yv.x = fmaxf(l2[ni * 4 + 0] + b2s[o0 + 0], 0.f);
        yv.y = fmaxf(l2[ni * 4 + 1] + b2s[o0 + 1], 0.f);
        yv.z = fmaxf(l2[ni * 4 + 2] + b2s[o0 + 2], 0.f);
        yv.w = fmaxf(l2[ni * 4 + 3] + b2s[o0 + 3], 0.f);
        if (node < NN) *(float4*)(Y + (size_t)node * DD + o0) = yv;
        hsf[(o0 + 0) * 34 + n0 + ni] = yv.x;
        hsf[(o0 + 1) * 34 + n0 + ni] = yv.y;
        hsf[(o0 + 2) * 34 + n0 + ni] = yv.z;
        hsf[(o0 + 3) * 34 + n0 + ni] = yv.w;
    }
    __syncthreads();

    // ---- BN partial sums ----
    if (tid < 64) {
        float s = 0.f, sq = 0.f;
        int lim = NN - node0;
        if (lim > 32) lim = 32;
        for (int n = 0; n < lim; ++n) {
            float v = hsf[tid * 34 + n];
            s += v;
            sq += v * v;
        }
        atomicAdd(&bnstat[tid], s);
        atomicAdd(&bnstat[64 + tid], sq);
    }
}

// ---------------- BN finalize+apply (+bf16 table write, + fused pool) ----------------
__global__ __launch_bounds__(256) void k_bnapply(
    const float* __restrict__ Y, const float* __restrict__ bs,
    const float* __restrict__ g, const float* __restrict__ b,
    float* __restrict__ XO, ushort* __restrict__ XH,
    const int* __restrict__ batch, float* __restrict__ gpool, int do_pool) {
    __shared__ float sc[64], shf[64], pool[512];
    int tid = threadIdx.x;
    if (tid < 64) {
        float mean = bs[tid] * (1.f / NN);
        float var = fmaxf(bs[64 + tid] * (1.f / NN) - mean * mean, 0.f);
        float inv = rsqrtf(var + BN_EPS_F);
        float s = g[tid] * inv;
        sc[tid] = s;
        shf[tid] = b[tid] - mean * s;
    }
    __syncthreads();
    int i = blockIdx.x * 256 + tid;  // float4 index
    int n = i >> 4, fq = (i & 15) * 4;
    float4 r = make_float4(0.f, 0.f, 0.f, 0.f);
    bool valid = i < NN * 16;
    if (valid) {
        float4 y = *(const float4*)(Y + (size_t)i * 4);
        r.x = y.x * sc[fq + 0] + shf[fq + 0];
        r.y = y.y * sc[fq + 1] + shf[fq + 1];
        r.z = y.z * sc[fq + 2] + shf[fq + 2];
        r.w = y.w * sc[fq + 3] + shf[fq + 3];
        *(float4*)(XO + (size_t)i * 4) = r;
        ushort4 h;
        h.x = f2bu(r.x); h.y = f2bu(r.y); h.z = f2bu(r.z); h.w = f2bu(r.w);
        *(ushort4*)(XH + (size_t)i * 4) = h;
    }
    if (do_pool) {
        int nfirst = blockIdx.x * 16;
        int nlast = nfirst + 15;
        if (nlast >= NN) nlast = NN - 1;
        int gmin = batch[nfirst], gmax = batch[nlast];
        int span = gmax - gmin + 1;
        if (span <= 8) {
            for (int j = tid; j < span * 64; j += 256) pool[j] = 0.f;
            __syncthreads();
            if (valid) {
                int gb = batch[n] - gmin;
                atomicAdd(&pool[gb * 64 + fq + 0], r.x);
                atomicAdd(&pool[gb * 64 + fq + 1], r.y);
                atomicAdd(&pool[gb * 64 + fq + 2], r.z);
                atomicAdd(&pool[gb * 64 + fq + 3], r.w);
            }
            __syncthreads();
            for (int j = tid; j < span * 64; j += 256)
                atomicAdd(&gpool[(size_t)(gmin + (j >> 6)) * 64 + (j & 63)], pool[j]);
        } else {
            if (valid) {
                float* gp = gpool + (size_t)batch[n] * DD + fq;
                atomicAdd(gp + 0, r.x);
                atomicAdd(gp + 1, r.y);
                atomicAdd(gp + 2, r.z);
                atomicAdd(gp + 3, r.w);
            }
        }
    }
}

// ---------------- head: fc1+relu, fc2, log_softmax ----------------
__global__ __launch_bounds__(256) void k_head(const float* __restrict__ gpool,
                                              const float* __restrict__ fc1W, const float* __restrict__ fc1b,
                                              const float* __restrict__ fc2W, const float* __restrict__ fc2b,
                                              float* __restrict__ out) {
    __shared__ float sh[12576];
    float* const gs = sh;
    float* const w1t = sh + 4096;
    float* const z1s = sh + 8256;
    float* const b1s = sh + 12416;
    float* const b2s = sh + 12480;
    float* const w2t = sh;
    float* const z2s = sh + 4096;

    int tid = threadIdx.x;
    for (int i = tid; i < 4096; i += 256) {
        gs[i] = gpool[i];
        int o = i >> 6, j = i & 63;
        w1t[j * 65 + o] = fc1W[i];
    }
    if (tid < 64) b1s[tid] = fc1b[tid];
    if (tid < 32) b2s[tid] = fc2b[tid];
    __syncthreads();
    {
        int tx = tid & 15, ty = tid >> 4, o0 = tx * 4, g0 = ty * 4;
        float acc[16];
#pragma unroll
        for (int i = 0; i < 16; ++i) acc[i] = 0.f;
        for (int j = 0; j < 64; ++j) {
            float w0 = w1t[j * 65 + o0 + 0], w1 = w1t[j * 65 + o0 + 1];
            float w2 = w1t[j * 65 + o0 + 2], w3 = w1t[j * 65 + o0 + 3];
#pragma unroll
            for (int gi = 0; gi < 4; ++gi) {
                float a = gs[(g0 + gi) * 64 + j];
                acc[gi * 4 + 0] += a * w0; acc[gi * 4 + 1] += a * w1;
                acc[gi * 4 + 2] += a * w2; acc[gi * 4 + 3] += a * w3;
            }
        }
        __syncthreads();
#pragma unroll
        for (int gi = 0; gi < 4; ++gi)
#pragma unroll
            for (int oi = 0; oi < 4; ++oi)
                z1s[(g0 + gi) * 65 + o0 + oi] = fmaxf(acc[gi * 4 + oi] + b1s[o0 + oi], 0.f);
    }
    for (int i = tid; i < 2048; i += 256) {
        int o = i >> 6, j = i & 63;
        w2t[j * 33 + o] = fc2W[i];
    }
    __syncthreads();
    {
        int tx = tid & 7, ty = tid >> 3, o0 = tx * 4, g0 = ty * 2;
        float acc[8];
#pragma unroll
        for (int i = 0; i < 8; ++i) acc[i] = 0.f;
        for (int j = 0; j < 64; ++j) {
            float w0 = w2t[j * 33 + o0 + 0], w1 = w2t[j * 33 + o0 + 1];
            float w2 = w2t[j * 33 + o0 + 2], w3 = w2t[j * 33 + o0 + 3];
            float a0 = z1s[(g0 + 0) * 65 + j];
            float a1 = z1s[(g0 + 1) * 65 + j];
            acc[0] += a0 * w0; acc[1] += a0 * w1; acc[2] += a0 * w2; acc[3] += a0 * w3;
            acc[4] += a1 * w0; acc[5] += a1 * w1; acc[6] += a1 * w2; acc[7] += a1 * w3;
        }
#pragma unroll
        for (int gi = 0; gi < 2; ++gi)
#pragma unroll
            for (int oi = 0; oi < 4; ++oi)
                z2s[(g0 + gi) * 33 + o0 + oi] = acc[gi * 4 + oi] + b2s[o0 + oi];
    }
    __syncthreads();
    if (tid < 64) {
        float m = -3.402823466e38f;
        for (int c = 0; c < DOUT; ++c) m = fmaxf(m, z2s[tid * 33 + c]);
        float s = 0.f;
        for (int c = 0; c < DOUT; ++c) s += expf(z2s[tid * 33 + c] - m);
        float lse = m + logf(s);
        for (int c = 0; c < DOUT; ++c)
            out[tid * DOUT + c] = z2s[tid * 33 + c] - lse;
    }
}

extern "C" void kernel_launch(void* const* d_in, const int* in_sizes, int n_in,
                              void* d_out, int out_size, void* d_ws, size_t ws_size,
                              hipStream_t stream) {
    const float* x = (const float*)d_in[0];
    const int* ei = (const int*)d_in[1];
    const int* src = ei;
    const int* dst = ei + NE;
    const int* batch = (const int*)d_in[2];
    const float *mlpW[3], *mlpB[3], *w1[3], *bb1[3], *w2[3], *bb2[3], *bng[3], *bnb[3];
    for (int l = 0; l < 3; ++l) {
        mlpW[l] = (const float*)d_in[3 + 6 * l];
        mlpB[l] = (const float*)d_in[4 + 6 * l];
        w1[l]   = (const float*)d_in[5 + 6 * l];
        bb1[l]  = (const float*)d_in[6 + 6 * l];
        w2[l]   = (const float*)d_in[7 + 6 * l];
        bb2[l]  = (const float*)d_in[8 + 6 * l];
        bng[l]  = (const float*)d_in[21 + 2 * l];
        bnb[l]  = (const float*)d_in[22 + 2 * l];
    }
    const float* fc1W = (const float*)d_in[27];
    const float* fc1b = (const float*)d_in[28];
    const float* fc2W = (const float*)d_in[29];
    const float* fc2b = (const float*)d_in[30];
    float* out = (float*)d_out;

    char* ws = (char*)d_ws;
    size_t off = 0;
    auto alloc = [&](size_t bytes) -> void* {
        void* p = ws + off;
        off = (off + bytes + 511) & ~(size_t)511;
        return p;
    };
    int* counts    = (int*)alloc((size_t)NN * 4);
    int* row_ptr   = (int*)alloc((size_t)(NN + 1) * 4);
    int* cursor    = (int*)alloc((size_t)NN * 4);
    int* blockSums = (int*)alloc(256 * 4);
    int* blockBase = (int*)alloc(256 * 4);
    int* csr_src   = (int*)alloc((size_t)NE * 4);
    float* XB      = (float*)alloc((size_t)NN * DD * 4);
    float* Yb      = (float*)alloc((size_t)NN * DD * 4);
    ushort* XH     = (ushort*)alloc((size_t)NN * DD * 2);
    ushort* Wb     = (ushort*)alloc((size_t)3 * 49152 * 2);
    float* Wt1     = (float*)alloc((size_t)3 * 16384 * 4);
    float* Wsm     = (float*)alloc((size_t)6 * 4096 * 4);
    float* bnstat  = (float*)alloc(384 * 4);
    float* gpool   = (float*)alloc((size_t)NGRAPH * DD * 4);
    (void)ws_size; (void)in_sizes; (void)n_in; (void)out_size;

    k_init<<<196, 256, 0, stream>>>(counts, bnstat, gpool);
    k_count<<<6250, 256, 0, stream>>>(dst, counts);
    k_scan_a<<<196, 256, 0, stream>>>(counts, blockSums);
    k_scan_b<<<1, 256, 0, stream>>>(blockSums, blockBase);
    k_scan_c<<<196, 256, 0, stream>>>(counts, blockBase, row_ptr, cursor);
    k_fill<<<6250, 256, 0, stream>>>(src, dst, cursor, csr_src);
    k_wprep<<<864, 256, 0, stream>>>(mlpW[0], mlpW[1], mlpW[2],
                                     w1[0], w2[0], w1[1], w2[1], w1[2], w2[2],
                                     Wb, Wt1, Wsm);
    k_x2h<<<3125, 256, 0, stream>>>(x, XH);

    const float* Xin = x;
    for (int l = 0; l < 3; ++l) {
        k_fused<<<1563, 256, 0, stream>>>(Xin, XH, row_ptr, csr_src,
                                          Wb + (size_t)l * 49152,
                                          Wt1 + (size_t)l * 16384,
                                          mlpB[l],
                                          Wsm + (size_t)(2 * l) * 4096, bb1[l],
                                          Wsm + (size_t)(2 * l + 1) * 4096, bb2[l],
                                          Yb, bnstat + l * 128);
        k_bnapply<<<3125, 256, 0, stream>>>(Yb, bnstat + l * 128, bng[l], bnb[l],
                                            XB, XH, batch, gpool, (l == 2) ? 1 : 0);
        Xin = XB;
    }
    k_head<<<1, 256, 0, stream>>>(gpool, fc1W, fc1b, fc2W, fc2b, out);
}

// Round 12
// 640.476 us; speedup vs baseline: 2.1976x; 1.1688x over previous
//
#include <hip/hip_runtime.h>

#define NN 50000
#define NE 1600000
#define DD 64
#define NGRAPH 64
#define DOUT 32
#define DELTA_F 2.5749f
#define BN_EPS_F 1e-5f

typedef unsigned short ushort;
typedef __attribute__((ext_vector_type(8))) short short8;
typedef __attribute__((ext_vector_type(4))) float floatx4;

static __device__ __forceinline__ float blo(unsigned u) {
    return __uint_as_float(u << 16);
}
static __device__ __forceinline__ float bhi(unsigned u) {
    return __uint_as_float(u & 0xFFFF0000u);
}
static __device__ __forceinline__ ushort f2bu(float f) {
    unsigned u = __float_as_uint(f);
    unsigned r = (u + 0x7FFF + ((u >> 16) & 1)) >> 16;   // round-to-nearest-even
    return (ushort)r;
}
static __device__ __forceinline__ unsigned pk(float a, float b) {
    return ((unsigned)f2bu(b) << 16) | (unsigned)f2bu(a);
}

// ---------------- init ----------------
__global__ void k_init(int* __restrict__ counts, float* __restrict__ bnstat,
                       float* __restrict__ gpool) {
    int i = blockIdx.x * 256 + threadIdx.x;
    if (i < NN) counts[i] = 0;
    if (i < 384) bnstat[i] = 0.f;
    if (i < NGRAPH * DD) gpool[i] = 0.f;
}

// ---------------- CSR build (rank/scan/place — single atomic pass) ----------------
__global__ void k_rank(const int* __restrict__ dst, int* __restrict__ counts,
                       int* __restrict__ rank) {
    int e = blockIdx.x * 256 + threadIdx.x;
    if (e < NE) rank[e] = atomicAdd(&counts[dst[e]], 1);
}

__global__ void k_scan_a(const int* __restrict__ counts, int* __restrict__ blockSums) {
    __shared__ int red[256];
    int tid = threadIdx.x;
    int gid = blockIdx.x * 256 + tid;
    int v = (gid < NN) ? counts[gid] : 0;
    red[tid] = v;
    __syncthreads();
    for (int s = 128; s > 0; s >>= 1) {
        if (tid < s) red[tid] += red[tid + s];
        __syncthreads();
    }
    if (tid == 0) blockSums[blockIdx.x] = red[0];
}

__global__ void k_scan_b(const int* __restrict__ blockSums, int* __restrict__ blockBase) {
    __shared__ int sh[256];
    int tid = threadIdx.x;
    int v = (tid < 196) ? blockSums[tid] : 0;
    sh[tid] = v;
    __syncthreads();
    for (int off = 1; off < 256; off <<= 1) {
        int t = (tid >= off) ? sh[tid - off] : 0;
        __syncthreads();
        sh[tid] += t;
        __syncthreads();
    }
    blockBase[tid] = sh[tid] - v;  // exclusive
}

__global__ void k_scan_c(const int* __restrict__ counts, const int* __restrict__ blockBase,
                         int* __restrict__ row_ptr) {
    __shared__ int sh[256];
    int tid = threadIdx.x;
    int gid = blockIdx.x * 256 + tid;
    int v = (gid < NN) ? counts[gid] : 0;
    sh[tid] = v;
    __syncthreads();
    for (int off = 1; off < 256; off <<= 1) {
        int t = (tid >= off) ? sh[tid - off] : 0;
        __syncthreads();
        sh[tid] += t;
        __syncthreads();
    }
    int excl = blockBase[blockIdx.x] + sh[tid] - v;
    if (gid <= NN) row_ptr[gid] = excl;
}

__global__ void k_place(const int* __restrict__ src, const int* __restrict__ dst,
                        const int* __restrict__ rank, const int* __restrict__ row_ptr,
                        int* __restrict__ csr_src) {
    int e = blockIdx.x * 256 + threadIdx.x;
    if (e < NE) csr_src[row_ptr[dst[e]] + rank[e]] = src[e];
}

// ---------------- weight prep ----------------
// Wb: bf16 MFMA B-fragment order (hi only). Per layer: [g 3][kb 8][t 4][lane 64][j 8]
//   value = W[o=t*16+(lane&15)][k_global = g*256 + kb*32 + (lane>>4)*8 + j]
// Wt1: f32 g=1 chunk transposed [layer][k 256][o 64]  (the cnt/DELTA-amplified chunk)
// Wsm: f32 transposed 64x64 (Lin1/Lin2).
__global__ void k_wprep(const float* __restrict__ w0, const float* __restrict__ w1,
                        const float* __restrict__ w2,
                        const float* __restrict__ a0, const float* __restrict__ a1,
                        const float* __restrict__ a2, const float* __restrict__ a3,
                        const float* __restrict__ a4, const float* __restrict__ a5,
                        ushort* __restrict__ Wb, float* __restrict__ Wt1,
                        float* __restrict__ Wsm) {
    int i = blockIdx.x * 256 + threadIdx.x;
    if (i < 3 * 49152) {
        int layer = i / 49152, r = i % 49152;
        const float* w = (layer == 0) ? w0 : ((layer == 1) ? w1 : w2);
        int g = r / 16384, r2 = r % 16384;
        int kb = r2 >> 11, r3 = r2 & 2047;
        int t = r3 >> 9, r4 = r3 & 511;
        int l = r4 >> 3, j = r4 & 7;
        int k = kb * 32 + (l >> 4) * 8 + j;
        int o = t * 16 + (l & 15);
        Wb[i] = f2bu(w[o * 768 + g * 256 + k]);
    } else if (i < 3 * 49152 + 3 * 16384) {
        int i2 = i - 3 * 49152;
        int layer = i2 / 16384, r = i2 % 16384;
        const float* w = (layer == 0) ? w0 : ((layer == 1) ? w1 : w2);
        int k = r >> 6, o = r & 63;
        Wt1[i2] = w[o * 768 + 256 + k];
    } else if (i < 3 * 49152 + 3 * 16384 + 6 * 4096) {
        int r2 = i - 3 * 49152 - 3 * 16384;
        int l = r2 >> 12, r = r2 & 4095;
        const float* w = (l == 0) ? a0 : (l == 1) ? a1 : (l == 2) ? a2
                       : (l == 3) ? a3 : (l == 4) ? a4 : a5;
        int o = r >> 6, j = r & 63;
        Wsm[l * 4096 + j * 64 + o] = w[r];
    }
}

// ---------------- x (f32) -> bf16 gather table ----------------
__global__ void k_x2h(const float* __restrict__ x, ushort* __restrict__ XH) {
    int i = blockIdx.x * 256 + threadIdx.x;
    if (i < NN * 16) {
        float4 v = *(const float4*)(x + (size_t)i * 4);
        ushort4 h;
        h.x = f2bu(v.x); h.y = f2bu(v.y); h.z = f2bu(v.z); h.w = f2bu(v.w);
        *(ushort4*)(XH + (size_t)i * 4) = h;
    }
}

// ======================================================================
// Fused layer, Ntile = 32 nodes/block.  Hybrid GEMM:
//   g=1 (cnt/DELTA-amplified chunk): f32 VALU from f32 stats (error-critical)
//   g=0,2 (scales 1, DELTA/cnt):     MFMA bf16-hi (error ≤ ~0.1 at output)
// Gather: 8-lane groups, 4-row double-buffered batches (low VGPR pressure).
// LDS (39808 B): Af32[k192][pad34] f32 | Ag[32][200] bf16 (overlaid by hsf
//   after frag loads) | biases/degs.
// __launch_bounds__(256,3): VGPR cap ~168 so the gather pipeline never spills.
// ======================================================================
__global__ __launch_bounds__(256, 3) void k_fused(
    const float* __restrict__ X, const ushort* __restrict__ XH,
    const int* __restrict__ row_ptr, const int* __restrict__ csr_src,
    const ushort* __restrict__ Wbh, const float* __restrict__ Wt1,
    const float* __restrict__ mlp_b,
    const float* __restrict__ W1t, const float* __restrict__ b1,
    const float* __restrict__ W2t, const float* __restrict__ b2,
    float* __restrict__ Y, float* __restrict__ bnstat) {
    __shared__ __align__(16) char smem[39808];
    float* const Af32 = (float*)smem;                 // 192 x 34 f32 = 26112 B
    ushort* const Ag = (ushort*)(smem + 26112);       // 32 x 200 bf16 = 12800 B
    float* const hsf = (float*)(smem + 26112);        // overlays Ag (8704 B)
    float* const mbias = (float*)(smem + 38912);
    float* const b1s = mbias + 64;
    float* const b2s = mbias + 128;
    float* const degs = mbias + 192;                  // 32

    const int tid = threadIdx.x;
    const int node0 = blockIdx.x * 32;

    if (tid < 64) {
        mbias[tid] = mlp_b[tid];
        b1s[tid] = b1[tid];
        b2s[tid] = b2[tid];
    }

    // ---- gather: 32 groups of 8 lanes; 4-row double-buffered batches ----
    {
        const int l8 = tid & 7;
        const int m = tid >> 3;                // 0..31
        const int node = node0 + m;
        const int f0 = l8 * 8;
        const ushort* Xp = XH + f0;

        float s[8], q[8], mx[8];
#pragma unroll
        for (int i = 0; i < 8; ++i) { s[i] = 0.f; q[i] = 0.f; mx[i] = -3.402823466e38f; }

        auto acc8 = [&](const uint4& rr) {
            float v0 = blo(rr.x), v1 = bhi(rr.x);
            float v2 = blo(rr.y), v3 = bhi(rr.y);
            float v4 = blo(rr.z), v5 = bhi(rr.z);
            float v6 = blo(rr.w), v7 = bhi(rr.w);
            s[0] += v0; q[0] = fmaf(v0, v0, q[0]); mx[0] = fmaxf(mx[0], v0);
            s[1] += v1; q[1] = fmaf(v1, v1, q[1]); mx[1] = fmaxf(mx[1], v1);
            s[2] += v2; q[2] = fmaf(v2, v2, q[2]); mx[2] = fmaxf(mx[2], v2);
            s[3] += v3; q[3] = fmaf(v3, v3, q[3]); mx[3] = fmaxf(mx[3], v3);
            s[4] += v4; q[4] = fmaf(v4, v4, q[4]); mx[4] = fmaxf(mx[4], v4);
            s[5] += v5; q[5] = fmaf(v5, v5, q[5]); mx[5] = fmaxf(mx[5], v5);
            s[6] += v6; q[6] = fmaf(v6, v6, q[6]); mx[6] = fmaxf(mx[6], v6);
            s[7] += v7; q[7] = fmaf(v7, v7, q[7]); mx[7] = fmaxf(mx[7], v7);
        };

        int beg = 0, end = 0;
        if (node < NN) { beg = row_ptr[node]; end = row_ptr[node + 1]; }
        const int deg = end - beg;
        const int nb = (deg + 3) >> 2;

        uint4 ra[4], rb[4];
        int ia[4];
        if (nb > 0) {
#pragma unroll
            for (int j = 0; j < 4; ++j) {
                int e = beg + j;
                ia[j] = csr_src[(e < end) ? e : end - 1];
            }
#pragma unroll
            for (int j = 0; j < 4; ++j)
                ra[j] = *(const uint4*)(Xp + (size_t)ia[j] * 64);
            if (nb > 1) {
#pragma unroll
                for (int j = 0; j < 4; ++j) {
                    int e = beg + 4 + j;
                    ia[j] = csr_src[(e < end) ? e : end - 1];
                }
            }
        }
        for (int t = 0; t < nb; ++t) {
            if (t + 1 < nb) {
#pragma unroll
                for (int j = 0; j < 4; ++j)
                    rb[j] = *(const uint4*)(Xp + (size_t)ia[j] * 64);
            }
            if (t + 2 < nb) {
                int b2e = beg + (t + 2) * 4;
#pragma unroll
                for (int j = 0; j < 4; ++j) {
                    int e = b2e + j;
                    ia[j] = csr_src[(e < end) ? e : end - 1];
                }
            }
            int cnt = end - (beg + t * 4);
            if (cnt >= 4) {
#pragma unroll
                for (int j = 0; j < 4; ++j) acc8(ra[j]);
            } else {
#pragma unroll
                for (int j = 0; j < 4; ++j) if (j < cnt) acc8(ra[j]);
            }
            if (t + 1 < nb) {
#pragma unroll
                for (int j = 0; j < 4; ++j) ra[j] = rb[j];
            }
        }

        float cdeg = (node < NN) ? (float)deg : 1.f;
        float rc = 1.0f / cdeg;
        float var[8];
#pragma unroll
        for (int i = 0; i < 8; ++i) {
            float mean = s[i] * rc;
            var[i] = fmaxf(q[i] * rc - mean * mean, 0.f);
            if (node >= NN) { mx[i] = 0.f; var[i] = 0.f; }
        }
        // f32 stats (for the VALU g=1 GEMM): [k][n] stride 34
#pragma unroll
        for (int i = 0; i < 8; ++i) {
            Af32[(f0 + i) * 34 + m] = s[i];
            Af32[(64 + f0 + i) * 34 + m] = mx[i];
            Af32[(128 + f0 + i) * 34 + m] = var[i];
        }
        // bf16-hi stats (for the MFMA g=0,2 GEMM): [m][k] pitch 200
        uint4 hv;
        hv.x = pk(s[0], s[1]); hv.y = pk(s[2], s[3]);
        hv.z = pk(s[4], s[5]); hv.w = pk(s[6], s[7]);
        *(uint4*)&Ag[m * 200 + f0] = hv;
        hv.x = pk(mx[0], mx[1]); hv.y = pk(mx[2], mx[3]);
        hv.z = pk(mx[4], mx[5]); hv.w = pk(mx[6], mx[7]);
        *(uint4*)&Ag[m * 200 + 64 + f0] = hv;
        hv.x = pk(var[0], var[1]); hv.y = pk(var[2], var[3]);
        hv.z = pk(var[4], var[5]); hv.w = pk(var[6], var[7]);
        *(uint4*)&Ag[m * 200 + 128 + f0] = hv;
        if (l8 == 0) degs[m] = cdeg;
    }
    __syncthreads();

    // ---- load MFMA A fragments (then Ag is dead; hsf overlays it) ----
    const int ln = tid & 63, wvi = tid >> 6;
    const int quad = ln >> 4, l16 = ln & 15;
    const int mtile = wvi >> 1;          // 0..1
    const int nt0 = (wvi & 1) * 2;       // ntiles nt0, nt0+1

    const ushort* Arow = Ag + (mtile * 16 + l16) * 200 + quad * 8;
    short8 afh[6];
    afh[0] = *(const short8*)(Arow + 0);    // s    k 0..31
    afh[1] = *(const short8*)(Arow + 32);   // s    k 32..63
    afh[2] = *(const short8*)(Arow + 64);   // max  k 0..31
    afh[3] = *(const short8*)(Arow + 96);   // max  k 32..63
    afh[4] = *(const short8*)(Arow + 128);  // var  k 0..31
    afh[5] = *(const short8*)(Arow + 160);  // var  k 32..63
    __syncthreads();   // all frag loads done -> hsf region free

    // ---- MFMA: g=0 and g=2 chunks, bf16-hi ----
    floatx4 accA[2][2], accB[2][2];
#pragma unroll
    for (int gi = 0; gi < 2; ++gi)
#pragma unroll
        for (int n = 0; n < 2; ++n) {
            accA[gi][n] = (floatx4){0.f, 0.f, 0.f, 0.f};
            accB[gi][n] = (floatx4){0.f, 0.f, 0.f, 0.f};
        }
#pragma unroll
    for (int gi = 0; gi < 2; ++gi) {
        const int g = gi * 2;
#pragma unroll
        for (int kb = 0; kb < 8; ++kb) {
            const int am = (kb < 4) ? kb : ((kb < 6) ? (kb - 4) : (kb - 2));
            const int boff = (((g * 8 + kb) * 4 + nt0) * 512) + ln * 8;
            short8 bh0 = *(const short8*)(Wbh + boff);
            short8 bh1 = *(const short8*)(Wbh + boff + 512);
            if (kb == 4 || kb == 5) {
                accB[gi][0] = __builtin_amdgcn_mfma_f32_16x16x32_bf16(afh[am], bh0, accB[gi][0], 0, 0, 0);
                accB[gi][1] = __builtin_amdgcn_mfma_f32_16x16x32_bf16(afh[am], bh1, accB[gi][1], 0, 0, 0);
            } else {
                accA[gi][0] = __builtin_amdgcn_mfma_f32_16x16x32_bf16(afh[am], bh0, accA[gi][0], 0, 0, 0);
                accA[gi][1] = __builtin_amdgcn_mfma_f32_16x16x32_bf16(afh[am], bh1, accA[gi][1], 0, 0, 0);
            }
        }
    }
    // MFMA partial (scales for g=0: 1 and 1/c; g=2: D/c and D/c^2) -> hsf[n][m]
#pragma unroll
    for (int r = 0; r < 4; ++r) {
        int m = mtile * 16 + quad * 4 + r;
        float dg = degs[m], rcd = 1.f / dg;
        float cA2 = DELTA_F * rcd;
        float cB2 = DELTA_F * rcd * rcd;
#pragma unroll
        for (int nt = 0; nt < 2; ++nt) {
            int n = (nt0 + nt) * 16 + l16;
            hsf[n * 34 + m] = accA[0][nt][r] + cA2 * accA[1][nt][r]
                            + rcd * accB[0][nt][r] + cB2 * accB[1][nt][r];
        }
    }

    // ---- f32 VALU GEMM for g=1 chunk (amplified by cnt/DELTA) ----
    const int tx = tid & 15, ty = tid >> 4;
    const int o0 = tx * 4, n0 = ty * 2;
    const float2* const Af2 = (const float2*)Af32;   // stride 17 float2

    float A1[8], B1[8];
#pragma unroll
    for (int i = 0; i < 8; ++i) { A1[i] = 0.f; B1[i] = 0.f; }
#pragma unroll 4
    for (int k = 0; k < 128; ++k) {          // s rows(0..63) + max rows(64..127)
        float2 a = Af2[k * 17 + ty];
        const float4 w = *(const float4*)(Wt1 + k * 64 + o0);
        A1[0] += a.x * w.x; A1[1] += a.x * w.y; A1[2] += a.x * w.z; A1[3] += a.x * w.w;
        A1[4] += a.y * w.x; A1[5] += a.y * w.y; A1[6] += a.y * w.z; A1[7] += a.y * w.w;
    }
#pragma unroll 4
    for (int k = 0; k < 64; ++k) {           // var rows x W rows 192..255
        float2 a = Af2[(128 + k) * 17 + ty];
        const float4 w = *(const float4*)(Wt1 + (192 + k) * 64 + o0);
        A1[0] += a.x * w.x; A1[1] += a.x * w.y; A1[2] += a.x * w.z; A1[3] += a.x * w.w;
        A1[4] += a.y * w.x; A1[5] += a.y * w.y; A1[6] += a.y * w.z; A1[7] += a.y * w.w;
    }
#pragma unroll 4
    for (int k = 0; k < 64; ++k) {           // mean fold: s rows x W rows 128..191
        float2 a = Af2[k * 17 + ty];
        const float4 w = *(const float4*)(Wt1 + (128 + k) * 64 + o0);
        B1[0] += a.x * w.x; B1[1] += a.x * w.y; B1[2] += a.x * w.z; B1[3] += a.x * w.w;
        B1[4] += a.y * w.x; B1[5] += a.y * w.y; B1[6] += a.y * w.z; B1[7] += a.y * w.w;
    }
    __syncthreads();   // all MFMA partials in hsf

    // ---- combine: h = partial + (c/D)*A1 + (1/D)*B1 + x + bias ----
#pragma unroll
    for (int ni = 0; ni < 2; ++ni) {
        int n = n0 + ni;
        int node = node0 + n;
        float dg = degs[n];
        float cA1 = dg * (1.0f / DELTA_F);
        const float cB1 = (1.0f / DELTA_F);
        float4 xv = make_float4(0.f, 0.f, 0.f, 0.f);
        if (node < NN) xv = *(const float4*)(X + (size_t)node * DD + o0);
#pragma unroll
        for (int oi = 0; oi < 4; ++oi) {
            int idx = (o0 + oi) * 34 + n;
            float xa = (oi == 0) ? xv.x : (oi == 1) ? xv.y : (oi == 2) ? xv.z : xv.w;
            hsf[idx] = hsf[idx] + cA1 * A1[ni * 4 + oi] + cB1 * B1[ni * 4 + oi]
                     + xa + mbias[o0 + oi];
        }
    }
    __syncthreads();

    // ---- Lin1 (f32): stream W1t from global, h-pairs from LDS ----
    const float2* const hs2 = (const float2*)hsf;
    float l1[8];
#pragma unroll
    for (int i = 0; i < 8; ++i) l1[i] = 0.f;
#pragma unroll 4
    for (int j = 0; j < 64; ++j) {
        float2 a = hs2[j * 17 + ty];
        const float4 wv4 = *(const float4*)(W1t + j * 64 + o0);
        l1[0] += a.x * wv4.x; l1[1] += a.x * wv4.y; l1[2] += a.x * wv4.z; l1[3] += a.x * wv4.w;
        l1[4] += a.y * wv4.x; l1[5] += a.y * wv4.y; l1[6] += a.y * wv4.z; l1[7] += a.y * wv4.w;
    }
    __syncthreads();
#pragma unroll
    for (int ni = 0; ni < 2; ++ni)
#pragma unroll
        for (int oi = 0; oi < 4; ++oi)
            hsf[(o0 + oi) * 34 + n0 + ni] = fmaxf(l1[ni * 4 + oi] + b1s[o0 + oi], 0.f);
    __syncthreads();

    // ---- Lin2 + outer relu ----
    float l2[8];
#pragma unroll
    for (int i = 0; i < 8; ++i) l2[i] = 0.f;
#pragma unroll 4
    for (int j = 0; j < 64; ++j) {
        float2 a = hs2[j * 17 + ty];
        const float4 wv4 = *(const float4*)(W2t + j * 64 + o0);
        l2[0] += a.x * wv4.x; l2[1] += a.x * wv4.y; l2[2] += a.x * wv4.z; l2[3] += a.x * wv4.w;
        l2[4] += a.y * wv4.x; l2[5] += a.y * wv4.y; l2[6] += a.y * wv4.z; l2[7] += a.y * wv4.w;
    }
    __syncthreads();
#pragma unroll
    for (int ni = 0; ni < 2; ++ni) {
        int node = node0 + n0 + ni;
        float4 yv;
        yv.x = fmaxf(l2[ni * 4 + 0] + b2s[o0 + 0], 0.f);
        yv.y = fmaxf(l2[ni * 4 + 1] + b2s[o0 + 1], 0.f);
        yv.z = fmaxf(l2[ni * 4 + 2] + b2s[o0 + 2], 0.f);
        yv.w = fmaxf(l2[ni * 4 + 3] + b2s[o0 + 3], 0.f);
        if (node < NN) *(float4*)(Y + (size_t)node * DD + o0) = yv;
        hsf[(o0 + 0) * 34 + n0 + ni] = yv.x;
        hsf[(o0 + 1) * 34 + n0 + ni] = yv.y;
        hsf[(o0 + 2) * 34 + n0 + ni] = yv.z;
        hsf[(o0 + 3) * 34 + n0 + ni] = yv.w;
    }
    __syncthreads();

    // ---- BN partial sums ----
    if (tid < 64) {
        float s = 0.f, sq = 0.f;
        int lim = NN - node0;
        if (lim > 32) lim = 32;
        for (int n = 0; n < lim; ++n) {
            float v = hsf[tid * 34 + n];
            s += v;
            sq += v * v;
        }
        atomicAdd(&bnstat[tid], s);
        atomicAdd(&bnstat[64 + tid], sq);
    }
}

// ---------------- BN finalize+apply (+bf16 table write, + fused pool) ----------------
__global__ __launch_bounds__(256) void k_bnapply(
    const float* __restrict__ Y, const float* __restrict__ bs,
    const float* __restrict__ g, const float* __restrict__ b,
    float* __restrict__ XO, ushort* __restrict__ XH,
    const int* __restrict__ batch, float* __restrict__ gpool, int do_pool) {
    __shared__ float sc[64], shf[64], pool[512];
    int tid = threadIdx.x;
    if (tid < 64) {
        float mean = bs[tid] * (1.f / NN);
        float var = fmaxf(bs[64 + tid] * (1.f / NN) - mean * mean, 0.f);
        float inv = rsqrtf(var + BN_EPS_F);
        float s = g[tid] * inv;
        sc[tid] = s;
        shf[tid] = b[tid] - mean * s;
    }
    __syncthreads();
    int i = blockIdx.x * 256 + tid;  // float4 index
    int n = i >> 4, fq = (i & 15) * 4;
    float4 r = make_float4(0.f, 0.f, 0.f, 0.f);
    bool valid = i < NN * 16;
    if (valid) {
        float4 y = *(const float4*)(Y + (size_t)i * 4);
        r.x = y.x * sc[fq + 0] + shf[fq + 0];
        r.y = y.y * sc[fq + 1] + shf[fq + 1];
        r.z = y.z * sc[fq + 2] + shf[fq + 2];
        r.w = y.w * sc[fq + 3] + shf[fq + 3];
        *(float4*)(XO + (size_t)i * 4) = r;
        ushort4 h;
        h.x = f2bu(r.x); h.y = f2bu(r.y); h.z = f2bu(r.z); h.w = f2bu(r.w);
        *(ushort4*)(XH + (size_t)i * 4) = h;
    }
    if (do_pool) {
        int nfirst = blockIdx.x * 16;
        int nlast = nfirst + 15;
        if (nlast >= NN) nlast = NN - 1;
        int gmin = batch[nfirst], gmax = batch[nlast];
        int span = gmax - gmin + 1;
        if (span <= 8) {
            for (int j = tid; j < span * 64; j += 256) pool[j] = 0.f;
            __syncthreads();
            if (valid) {
                int gb = batch[n] - gmin;
                atomicAdd(&pool[gb * 64 + fq + 0], r.x);
                atomicAdd(&pool[gb * 64 + fq + 1], r.y);
                atomicAdd(&pool[gb * 64 + fq + 2], r.z);
                atomicAdd(&pool[gb * 64 + fq + 3], r.w);
            }
            __syncthreads();
            for (int j = tid; j < span * 64; j += 256)
                atomicAdd(&gpool[(size_t)(gmin + (j >> 6)) * 64 + (j & 63)], pool[j]);
        } else {
            if (valid) {
                float* gp = gpool + (size_t)batch[n] * DD + fq;
                atomicAdd(gp + 0, r.x);
                atomicAdd(gp + 1, r.y);
                atomicAdd(gp + 2, r.z);
                atomicAdd(gp + 3, r.w);
            }
        }
    }
}

// ---------------- head: fc1+relu, fc2, log_softmax ----------------
__global__ __launch_bounds__(256) void k_head(const float* __restrict__ gpool,
                                              const float* __restrict__ fc1W, const float* __restrict__ fc1b,
                                              const float* __restrict__ fc2W, const float* __restrict__ fc2b,
                                              float* __restrict__ out) {
    __shared__ float sh[12576];
    float* const gs = sh;
    float* const w1t = sh + 4096;
    float* const z1s = sh + 8256;
    float* const b1s = sh + 12416;
    float* const b2s = sh + 12480;
    float* const w2t = sh;
    float* const z2s = sh + 4096;

    int tid = threadIdx.x;
    for (int i = tid; i < 4096; i += 256) {
        gs[i] = gpool[i];
        int o = i >> 6, j = i & 63;
        w1t[j * 65 + o] = fc1W[i];
    }
    if (tid < 64) b1s[tid] = fc1b[tid];
    if (tid < 32) b2s[tid] = fc2b[tid];
    __syncthreads();
    {
        int tx = tid & 15, ty = tid >> 4, o0 = tx * 4, g0 = ty * 4;
        float acc[16];
#pragma unroll
        for (int i = 0; i < 16; ++i) acc[i] = 0.f;
        for (int j = 0; j < 64; ++j) {
            float w0 = w1t[j * 65 + o0 + 0], w1 = w1t[j * 65 + o0 + 1];
            float w2 = w1t[j * 65 + o0 + 2], w3 = w1t[j * 65 + o0 + 3];
#pragma unroll
            for (int gi = 0; gi < 4; ++gi) {
                float a = gs[(g0 + gi) * 64 + j];
                acc[gi * 4 + 0] += a * w0; acc[gi * 4 + 1] += a * w1;
                acc[gi * 4 + 2] += a * w2; acc[gi * 4 + 3] += a * w3;
            }
        }
        __syncthreads();
#pragma unroll
        for (int gi = 0; gi < 4; ++gi)
#pragma unroll
            for (int oi = 0; oi < 4; ++oi)
                z1s[(g0 + gi) * 65 + o0 + oi] = fmaxf(acc[gi * 4 + oi] + b1s[o0 + oi], 0.f);
    }
    for (int i = tid; i < 2048; i += 256) {
        int o = i >> 6, j = i & 63;
        w2t[j * 33 + o] = fc2W[i];
    }
    __syncthreads();
    {
        int tx = tid & 7, ty = tid >> 3, o0 = tx * 4, g0 = ty * 2;
        float acc[8];
#pragma unroll
        for (int i = 0; i < 8; ++i) acc[i] = 0.f;
        for (int j = 0; j < 64; ++j) {
            float w0 = w2t[j * 33 + o0 + 0], w1 = w2t[j * 33 + o0 + 1];
            float w2 = w2t[j * 33 + o0 + 2], w3 = w2t[j * 33 + o0 + 3];
            float a0 = z1s[(g0 + 0) * 65 + j];
            float a1 = z1s[(g0 + 1) * 65 + j];
            acc[0] += a0 * w0; acc[1] += a0 * w1; acc[2] += a0 * w2; acc[3] += a0 * w3;
            acc[4] += a1 * w0; acc[5] += a1 * w1; acc[6] += a1 * w2; acc[7] += a1 * w3;
        }
#pragma unroll
        for (int gi = 0; gi < 2; ++gi)
#pragma unroll
            for (int oi = 0; oi < 4; ++oi)
                z2s[(g0 + gi) * 33 + o0 + oi] = acc[gi * 4 + oi] + b2s[o0 + oi];
    }
    __syncthreads();
    if (tid < 64) {
        float m = -3.402823466e38f;
        for (int c = 0; c < DOUT; ++c) m = fmaxf(m, z2s[tid * 33 + c]);
        float s = 0.f;
        for (int c = 0; c < DOUT; ++c) s += expf(z2s[tid * 33 + c] - m);
        float lse = m + logf(s);
        for (int c = 0; c < DOUT; ++c)
            out[tid * DOUT + c] = z2s[tid * 33 + c] - lse;
    }
}

extern "C" void kernel_launch(void* const* d_in, const int* in_sizes, int n_in,
                              void* d_out, int out_size, void* d_ws, size_t ws_size,
                              hipStream_t stream) {
    const float* x = (const float*)d_in[0];
    const int* ei = (const int*)d_in[1];
    const int* src = ei;
    const int* dst = ei + NE;
    const int* batch = (const int*)d_in[2];
    const float *mlpW[3], *mlpB[3], *w1[3], *bb1[3], *w2[3], *bb2[3], *bng[3], *bnb[3];
    for (int l = 0; l < 3; ++l) {
        mlpW[l] = (const float*)d_in[3 + 6 * l];
        mlpB[l] = (const float*)d_in[4 + 6 * l];
        w1[l]   = (const float*)d_in[5 + 6 * l];
        bb1[l]  = (const float*)d_in[6 + 6 * l];
        w2[l]   = (const float*)d_in[7 + 6 * l];
        bb2[l]  = (const float*)d_in[8 + 6 * l];
        bng[l]  = (const float*)d_in[21 + 2 * l];
        bnb[l]  = (const float*)d_in[22 + 2 * l];
    }
    const float* fc1W = (const float*)d_in[27];
    const float* fc1b = (const float*)d_in[28];
    const float* fc2W = (const float*)d_in[29];
    const float* fc2b = (const float*)d_in[30];
    float* out = (float*)d_out;

    char* ws = (char*)d_ws;
    size_t off = 0;
    auto alloc = [&](size_t bytes) -> void* {
        void* p = ws + off;
        off = (off + bytes + 511) & ~(size_t)511;
        return p;
    };
    int* counts    = (int*)alloc((size_t)NN * 4);
    int* row_ptr   = (int*)alloc((size_t)(NN + 1) * 4);
    int* rank      = (int*)alloc((size_t)NE * 4);
    int* blockSums = (int*)alloc(256 * 4);
    int* blockBase = (int*)alloc(256 * 4);
    int* csr_src   = (int*)alloc((size_t)NE * 4);
    float* XB      = (float*)alloc((size_t)NN * DD * 4);
    float* Yb      = (float*)alloc((size_t)NN * DD * 4);
    ushort* XH     = (ushort*)alloc((size_t)NN * DD * 2);
    ushort* Wb     = (ushort*)alloc((size_t)3 * 49152 * 2);
    float* Wt1     = (float*)alloc((size_t)3 * 16384 * 4);
    float* Wsm     = (float*)alloc((size_t)6 * 4096 * 4);
    float* bnstat  = (float*)alloc(384 * 4);
    float* gpool   = (float*)alloc((size_t)NGRAPH * DD * 4);
    (void)ws_size; (void)in_sizes; (void)n_in; (void)out_size;

    k_init<<<196, 256, 0, stream>>>(counts, bnstat, gpool);
    k_rank<<<6250, 256, 0, stream>>>(dst, counts, rank);
    k_scan_a<<<196, 256, 0, stream>>>(counts, blockSums);
    k_scan_b<<<1, 256, 0, stream>>>(blockSums, blockBase);
    k_scan_c<<<196, 256, 0, stream>>>(counts, blockBase, row_ptr);
    k_place<<<6250, 256, 0, stream>>>(src, dst, rank, row_ptr, csr_src);
    k_wprep<<<864, 256, 0, stream>>>(mlpW[0], mlpW[1], mlpW[2],
                                     w1[0], w2[0], w1[1], w2[1], w1[2], w2[2],
                                     Wb, Wt1, Wsm);
    k_x2h<<<3125, 256, 0, stream>>>(x, XH);

    const float* Xin = x;
    for (int l = 0; l < 3; ++l) {
        k_fused<<<1563, 256, 0, stream>>>(Xin, XH, row_ptr, csr_src,
                                          Wb + (size_t)l * 49152,
                                          Wt1 + (size_t)l * 16384,
                                          mlpB[l],
                                          Wsm + (size_t)(2 * l) * 4096, bb1[l],
                                          Wsm + (size_t)(2 * l + 1) * 4096, bb2[l],
                                          Yb, bnstat + l * 128);
        k_bnapply<<<3125, 256, 0, stream>>>(Yb, bnstat + l * 128, bng[l], bnb[l],
                                            XB, XH, batch, gpool, (l == 2) ? 1 : 0);
        Xin = XB;
    }
    k_head<<<1, 256, 0, stream>>>(gpool, fc1W, fc1b, fc2W, fc2b, out);
}

// Round 13
// 640.357 us; speedup vs baseline: 2.1980x; 1.0002x over previous
//
#include <hip/hip_runtime.h>

#define NN 50000
#define NE 1600000
#define DD 64
#define NGRAPH 64
#define DOUT 32
#define DELTA_F 2.5749f
#define BN_EPS_F 1e-5f

typedef unsigned short ushort;
typedef __attribute__((ext_vector_type(8))) short short8;
typedef __attribute__((ext_vector_type(4))) float floatx4;

static __device__ __forceinline__ float blo(unsigned u) {
    return __uint_as_float(u << 16);
}
static __device__ __forceinline__ float bhi(unsigned u) {
    return __uint_as_float(u & 0xFFFF0000u);
}
static __device__ __forceinline__ ushort f2bu(float f) {
    unsigned u = __float_as_uint(f);
    unsigned r = (u + 0x7FFF + ((u >> 16) & 1)) >> 16;   // round-to-nearest-even
    return (ushort)r;
}
static __device__ __forceinline__ unsigned pk(float a, float b) {
    return ((unsigned)f2bu(b) << 16) | (unsigned)f2bu(a);
}

// ---------------- init ----------------
__global__ void k_init(int* __restrict__ counts, float* __restrict__ bnstat,
                       float* __restrict__ gpool) {
    int i = blockIdx.x * 256 + threadIdx.x;
    if (i < NN) counts[i] = 0;
    if (i < 384) bnstat[i] = 0.f;
    if (i < NGRAPH * DD) gpool[i] = 0.f;
}

// ---------------- CSR build (rank/scan/place — single atomic pass) ----------------
__global__ void k_rank(const int* __restrict__ dst, int* __restrict__ counts,
                       int* __restrict__ rank) {
    int e = blockIdx.x * 256 + threadIdx.x;
    if (e < NE) rank[e] = atomicAdd(&counts[dst[e]], 1);
}

__global__ void k_scan_a(const int* __restrict__ counts, int* __restrict__ blockSums) {
    __shared__ int red[256];
    int tid = threadIdx.x;
    int gid = blockIdx.x * 256 + tid;
    int v = (gid < NN) ? counts[gid] : 0;
    red[tid] = v;
    __syncthreads();
    for (int s = 128; s > 0; s >>= 1) {
        if (tid < s) red[tid] += red[tid + s];
        __syncthreads();
    }
    if (tid == 0) blockSums[blockIdx.x] = red[0];
}

__global__ void k_scan_b(const int* __restrict__ blockSums, int* __restrict__ blockBase) {
    __shared__ int sh[256];
    int tid = threadIdx.x;
    int v = (tid < 196) ? blockSums[tid] : 0;
    sh[tid] = v;
    __syncthreads();
    for (int off = 1; off < 256; off <<= 1) {
        int t = (tid >= off) ? sh[tid - off] : 0;
        __syncthreads();
        sh[tid] += t;
        __syncthreads();
    }
    blockBase[tid] = sh[tid] - v;  // exclusive
}

__global__ void k_scan_c(const int* __restrict__ counts, const int* __restrict__ blockBase,
                         int* __restrict__ row_ptr) {
    __shared__ int sh[256];
    int tid = threadIdx.x;
    int gid = blockIdx.x * 256 + tid;
    int v = (gid < NN) ? counts[gid] : 0;
    sh[tid] = v;
    __syncthreads();
    for (int off = 1; off < 256; off <<= 1) {
        int t = (tid >= off) ? sh[tid - off] : 0;
        __syncthreads();
        sh[tid] += t;
        __syncthreads();
    }
    int excl = blockBase[blockIdx.x] + sh[tid] - v;
    if (gid <= NN) row_ptr[gid] = excl;
}

__global__ void k_place(const int* __restrict__ src, const int* __restrict__ dst,
                        const int* __restrict__ rank, const int* __restrict__ row_ptr,
                        int* __restrict__ csr_src) {
    int e = blockIdx.x * 256 + threadIdx.x;
    if (e < NE) csr_src[row_ptr[dst[e]] + rank[e]] = src[e];
}

// ---------------- weight prep ----------------
// Wb: bf16 MFMA B-fragment order (hi only). Per layer: [g 3][kb 8][t 4][lane 64][j 8]
//   value = W[o=t*16+(lane&15)][k_global = g*256 + kb*32 + (lane>>4)*8 + j]
// Wt1: f32 g=1 chunk transposed [layer][k 256][o 64]  (the cnt/DELTA-amplified chunk)
// Wsm: f32 transposed 64x64 (Lin1/Lin2).
__global__ void k_wprep(const float* __restrict__ w0, const float* __restrict__ w1,
                        const float* __restrict__ w2,
                        const float* __restrict__ a0, const float* __restrict__ a1,
                        const float* __restrict__ a2, const float* __restrict__ a3,
                        const float* __restrict__ a4, const float* __restrict__ a5,
                        ushort* __restrict__ Wb, float* __restrict__ Wt1,
                        float* __restrict__ Wsm) {
    int i = blockIdx.x * 256 + threadIdx.x;
    if (i < 3 * 49152) {
        int layer = i / 49152, r = i % 49152;
        const float* w = (layer == 0) ? w0 : ((layer == 1) ? w1 : w2);
        int g = r / 16384, r2 = r % 16384;
        int kb = r2 >> 11, r3 = r2 & 2047;
        int t = r3 >> 9, r4 = r3 & 511;
        int l = r4 >> 3, j = r4 & 7;
        int k = kb * 32 + (l >> 4) * 8 + j;
        int o = t * 16 + (l & 15);
        Wb[i] = f2bu(w[o * 768 + g * 256 + k]);
    } else if (i < 3 * 49152 + 3 * 16384) {
        int i2 = i - 3 * 49152;
        int layer = i2 / 16384, r = i2 % 16384;
        const float* w = (layer == 0) ? w0 : ((layer == 1) ? w1 : w2);
        int k = r >> 6, o = r & 63;
        Wt1[i2] = w[o * 768 + 256 + k];
    } else if (i < 3 * 49152 + 3 * 16384 + 6 * 4096) {
        int r2 = i - 3 * 49152 - 3 * 16384;
        int l = r2 >> 12, r = r2 & 4095;
        const float* w = (l == 0) ? a0 : (l == 1) ? a1 : (l == 2) ? a2
                       : (l == 3) ? a3 : (l == 4) ? a4 : a5;
        int o = r >> 6, j = r & 63;
        Wsm[l * 4096 + j * 64 + o] = w[r];
    }
}

// ---------------- x (f32) -> bf16 gather table ----------------
__global__ void k_x2h(const float* __restrict__ x, ushort* __restrict__ XH) {
    int i = blockIdx.x * 256 + threadIdx.x;
    if (i < NN * 16) {
        float4 v = *(const float4*)(x + (size_t)i * 4);
        ushort4 h;
        h.x = f2bu(v.x); h.y = f2bu(v.y); h.z = f2bu(v.z); h.w = f2bu(v.w);
        *(ushort4*)(XH + (size_t)i * 4) = h;
    }
}

// ======================================================================
// Fused layer, Ntile = 32 nodes/block.  Hybrid GEMM:
//   g=1 (cnt/DELTA-amplified chunk): f32 VALU from f32 stats (error-critical)
//   g=0,2 (scales 1, DELTA/cnt):     MFMA bf16-hi (error ≤ ~0.1 at output)
// Gather: 8-lane groups, 4-row double-buffered batches (low VGPR pressure).
// LDS (39808 B): Af32[k192][pad34] f32 | Ag[32][200] bf16 (overlaid by hsf
//   after frag loads) | biases/degs.
// __launch_bounds__(256,4): 4 blocks/CU (LDS 39936x4 = 159.7KB fits 160KB;
//   VGPR cap 128 >> 56 used — R12's (256,3) was itself the occupancy limiter).
// ======================================================================
__global__ __launch_bounds__(256, 4) void k_fused(
    const float* __restrict__ X, const ushort* __restrict__ XH,
    const int* __restrict__ row_ptr, const int* __restrict__ csr_src,
    const ushort* __restrict__ Wbh, const float* __restrict__ Wt1,
    const float* __restrict__ mlp_b,
    const float* __restrict__ W1t, const float* __restrict__ b1,
    const float* __restrict__ W2t, const float* __restrict__ b2,
    float* __restrict__ Y, float* __restrict__ bnstat) {
    __shared__ __align__(16) char smem[39808];
    float* const Af32 = (float*)smem;                 // 192 x 34 f32 = 26112 B
    ushort* const Ag = (ushort*)(smem + 26112);       // 32 x 200 bf16 = 12800 B
    float* const hsf = (float*)(smem + 26112);        // overlays Ag (8704 B)
    float* const mbias = (float*)(smem + 38912);
    float* const b1s = mbias + 64;
    float* const b2s = mbias + 128;
    float* const degs = mbias + 192;                  // 32

    const int tid = threadIdx.x;
    const int node0 = blockIdx.x * 32;

    if (tid < 64) {
        mbias[tid] = mlp_b[tid];
        b1s[tid] = b1[tid];
        b2s[tid] = b2[tid];
    }

    // ---- gather: 32 groups of 8 lanes; 4-row double-buffered batches ----
    {
        const int l8 = tid & 7;
        const int m = tid >> 3;                // 0..31
        const int node = node0 + m;
        const int f0 = l8 * 8;
        const ushort* Xp = XH + f0;

        float s[8], q[8], mx[8];
#pragma unroll
        for (int i = 0; i < 8; ++i) { s[i] = 0.f; q[i] = 0.f; mx[i] = -3.402823466e38f; }

        auto acc8 = [&](const uint4& rr) {
            float v0 = blo(rr.x), v1 = bhi(rr.x);
            float v2 = blo(rr.y), v3 = bhi(rr.y);
            float v4 = blo(rr.z), v5 = bhi(rr.z);
            float v6 = blo(rr.w), v7 = bhi(rr.w);
            s[0] += v0; q[0] = fmaf(v0, v0, q[0]); mx[0] = fmaxf(mx[0], v0);
            s[1] += v1; q[1] = fmaf(v1, v1, q[1]); mx[1] = fmaxf(mx[1], v1);
            s[2] += v2; q[2] = fmaf(v2, v2, q[2]); mx[2] = fmaxf(mx[2], v2);
            s[3] += v3; q[3] = fmaf(v3, v3, q[3]); mx[3] = fmaxf(mx[3], v3);
            s[4] += v4; q[4] = fmaf(v4, v4, q[4]); mx[4] = fmaxf(mx[4], v4);
            s[5] += v5; q[5] = fmaf(v5, v5, q[5]); mx[5] = fmaxf(mx[5], v5);
            s[6] += v6; q[6] = fmaf(v6, v6, q[6]); mx[6] = fmaxf(mx[6], v6);
            s[7] += v7; q[7] = fmaf(v7, v7, q[7]); mx[7] = fmaxf(mx[7], v7);
        };

        int beg = 0, end = 0;
        if (node < NN) { beg = row_ptr[node]; end = row_ptr[node + 1]; }
        const int deg = end - beg;
        const int nb = (deg + 3) >> 2;

        uint4 ra[4], rb[4];
        int ia[4];
        if (nb > 0) {
#pragma unroll
            for (int j = 0; j < 4; ++j) {
                int e = beg + j;
                ia[j] = csr_src[(e < end) ? e : end - 1];
            }
#pragma unroll
            for (int j = 0; j < 4; ++j)
                ra[j] = *(const uint4*)(Xp + (size_t)ia[j] * 64);
            if (nb > 1) {
#pragma unroll
                for (int j = 0; j < 4; ++j) {
                    int e = beg + 4 + j;
                    ia[j] = csr_src[(e < end) ? e : end - 1];
                }
            }
        }
        for (int t = 0; t < nb; ++t) {
            if (t + 1 < nb) {
#pragma unroll
                for (int j = 0; j < 4; ++j)
                    rb[j] = *(const uint4*)(Xp + (size_t)ia[j] * 64);
            }
            if (t + 2 < nb) {
                int b2e = beg + (t + 2) * 4;
#pragma unroll
                for (int j = 0; j < 4; ++j) {
                    int e = b2e + j;
                    ia[j] = csr_src[(e < end) ? e : end - 1];
                }
            }
            int cnt = end - (beg + t * 4);
            if (cnt >= 4) {
#pragma unroll
                for (int j = 0; j < 4; ++j) acc8(ra[j]);
            } else {
#pragma unroll
                for (int j = 0; j < 4; ++j) if (j < cnt) acc8(ra[j]);
            }
            if (t + 1 < nb) {
#pragma unroll
                for (int j = 0; j < 4; ++j) ra[j] = rb[j];
            }
        }

        float cdeg = (node < NN) ? (float)deg : 1.f;
        float rc = 1.0f / cdeg;
        float var[8];
#pragma unroll
        for (int i = 0; i < 8; ++i) {
            float mean = s[i] * rc;
            var[i] = fmaxf(q[i] * rc - mean * mean, 0.f);
            if (node >= NN) { mx[i] = 0.f; var[i] = 0.f; }
        }
        // f32 stats (for the VALU g=1 GEMM): [k][n] stride 34
#pragma unroll
        for (int i = 0; i < 8; ++i) {
            Af32[(f0 + i) * 34 + m] = s[i];
            Af32[(64 + f0 + i) * 34 + m] = mx[i];
            Af32[(128 + f0 + i) * 34 + m] = var[i];
        }
        // bf16-hi stats (for the MFMA g=0,2 GEMM): [m][k] pitch 200
        uint4 hv;
        hv.x = pk(s[0], s[1]); hv.y = pk(s[2], s[3]);
        hv.z = pk(s[4], s[5]); hv.w = pk(s[6], s[7]);
        *(uint4*)&Ag[m * 200 + f0] = hv;
        hv.x = pk(mx[0], mx[1]); hv.y = pk(mx[2], mx[3]);
        hv.z = pk(mx[4], mx[5]); hv.w = pk(mx[6], mx[7]);
        *(uint4*)&Ag[m * 200 + 64 + f0] = hv;
        hv.x = pk(var[0], var[1]); hv.y = pk(var[2], var[3]);
        hv.z = pk(var[4], var[5]); hv.w = pk(var[6], var[7]);
        *(uint4*)&Ag[m * 200 + 128 + f0] = hv;
        if (l8 == 0) degs[m] = cdeg;
    }
    __syncthreads();

    // ---- load MFMA A fragments (then Ag is dead; hsf overlays it) ----
    const int ln = tid & 63, wvi = tid >> 6;
    const int quad = ln >> 4, l16 = ln & 15;
    const int mtile = wvi >> 1;          // 0..1
    const int nt0 = (wvi & 1) * 2;       // ntiles nt0, nt0+1

    const ushort* Arow = Ag + (mtile * 16 + l16) * 200 + quad * 8;
    short8 afh[6];
    afh[0] = *(const short8*)(Arow + 0);    // s    k 0..31
    afh[1] = *(const short8*)(Arow + 32);   // s    k 32..63
    afh[2] = *(const short8*)(Arow + 64);   // max  k 0..31
    afh[3] = *(const short8*)(Arow + 96);   // max  k 32..63
    afh[4] = *(const short8*)(Arow + 128);  // var  k 0..31
    afh[5] = *(const short8*)(Arow + 160);  // var  k 32..63
    __syncthreads();   // all frag loads done -> hsf region free

    // ---- MFMA: g=0 and g=2 chunks, bf16-hi ----
    floatx4 accA[2][2], accB[2][2];
#pragma unroll
    for (int gi = 0; gi < 2; ++gi)
#pragma unroll
        for (int n = 0; n < 2; ++n) {
            accA[gi][n] = (floatx4){0.f, 0.f, 0.f, 0.f};
            accB[gi][n] = (floatx4){0.f, 0.f, 0.f, 0.f};
        }
#pragma unroll
    for (int gi = 0; gi < 2; ++gi) {
        const int g = gi * 2;
#pragma unroll
        for (int kb = 0; kb < 8; ++kb) {
            const int am = (kb < 4) ? kb : ((kb < 6) ? (kb - 4) : (kb - 2));
            const int boff = (((g * 8 + kb) * 4 + nt0) * 512) + ln * 8;
            short8 bh0 = *(const short8*)(Wbh + boff);
            short8 bh1 = *(const short8*)(Wbh + boff + 512);
            if (kb == 4 || kb == 5) {
                accB[gi][0] = __builtin_amdgcn_mfma_f32_16x16x32_bf16(afh[am], bh0, accB[gi][0], 0, 0, 0);
                accB[gi][1] = __builtin_amdgcn_mfma_f32_16x16x32_bf16(afh[am], bh1, accB[gi][1], 0, 0, 0);
            } else {
                accA[gi][0] = __builtin_amdgcn_mfma_f32_16x16x32_bf16(afh[am], bh0, accA[gi][0], 0, 0, 0);
                accA[gi][1] = __builtin_amdgcn_mfma_f32_16x16x32_bf16(afh[am], bh1, accA[gi][1], 0, 0, 0);
            }
        }
    }
    // MFMA partial (scales for g=0: 1 and 1/c; g=2: D/c and D/c^2) -> hsf[n][m]
#pragma unroll
    for (int r = 0; r < 4; ++r) {
        int m = mtile * 16 + quad * 4 + r;
        float dg = degs[m], rcd = 1.f / dg;
        float cA2 = DELTA_F * rcd;
        float cB2 = DELTA_F * rcd * rcd;
#pragma unroll
        for (int nt = 0; nt < 2; ++nt) {
            int n = (nt0 + nt) * 16 + l16;
            hsf[n * 34 + m] = accA[0][nt][r] + cA2 * accA[1][nt][r]
                            + rcd * accB[0][nt][r] + cB2 * accB[1][nt][r];
        }
    }

    // ---- f32 VALU GEMM for g=1 chunk (amplified by cnt/DELTA) ----
    const int tx = tid & 15, ty = tid >> 4;
    const int o0 = tx * 4, n0 = ty * 2;
    const float2* const Af2 = (const float2*)Af32;   // stride 17 float2

    float A1[8], B1[8];
#pragma unroll
    for (int i = 0; i < 8; ++i) { A1[i] = 0.f; B1[i] = 0.f; }
#pragma unroll 4
    for (int k = 0; k < 128; ++k) {          // s rows(0..63) + max rows(64..127)
        float2 a = Af2[k * 17 + ty];
        const float4 w = *(const float4*)(Wt1 + k * 64 + o0);
        A1[0] += a.x * w.x; A1[1] += a.x * w.y; A1[2] += a.x * w.z; A1[3] += a.x * w.w;
        A1[4] += a.y * w.x; A1[5] += a.y * w.y; A1[6] += a.y * w.z; A1[7] += a.y * w.w;
    }
#pragma unroll 4
    for (int k = 0; k < 64; ++k) {           // var rows x W rows 192..255
        float2 a = Af2[(128 + k) * 17 + ty];
        const float4 w = *(const float4*)(Wt1 + (192 + k) * 64 + o0);
        A1[0] += a.x * w.x; A1[1] += a.x * w.y; A1[2] += a.x * w.z; A1[3] += a.x * w.w;
        A1[4] += a.y * w.x; A1[5] += a.y * w.y; A1[6] += a.y * w.z; A1[7] += a.y * w.w;
    }
#pragma unroll 4
    for (int k = 0; k < 64; ++k) {           // mean fold: s rows x W rows 128..191
        float2 a = Af2[k * 17 + ty];
        const float4 w = *(const float4*)(Wt1 + (128 + k) * 64 + o0);
        B1[0] += a.x * w.x; B1[1] += a.x * w.y; B1[2] += a.x * w.z; B1[3] += a.x * w.w;
        B1[4] += a.y * w.x; B1[5] += a.y * w.y; B1[6] += a.y * w.z; B1[7] += a.y * w.w;
    }
    __syncthreads();   // all MFMA partials in hsf

    // ---- combine: h = partial + (c/D)*A1 + (1/D)*B1 + x + bias ----
#pragma unroll
    for (int ni = 0; ni < 2; ++ni) {
        int n = n0 + ni;
        int node = node0 + n;
        float dg = degs[n];
        float cA1 = dg * (1.0f / DELTA_F);
        const float cB1 = (1.0f / DELTA_F);
        float4 xv = make_float4(0.f, 0.f, 0.f, 0.f);
        if (node < NN) xv = *(const float4*)(X + (size_t)node * DD + o0);
#pragma unroll
        for (int oi = 0; oi < 4; ++oi) {
            int idx = (o0 + oi) * 34 + n;
            float xa = (oi == 0) ? xv.x : (oi == 1) ? xv.y : (oi == 2) ? xv.z : xv.w;
            hsf[idx] = hsf[idx] + cA1 * A1[ni * 4 + oi] + cB1 * B1[ni * 4 + oi]
                     + xa + mbias[o0 + oi];
        }
    }
    __syncthreads();

    // ---- Lin1 (f32): stream W1t from global, h-pairs from LDS ----
    const float2* const hs2 = (const float2*)hsf;
    float l1[8];
#pragma unroll
    for (int i = 0; i < 8; ++i) l1[i] = 0.f;
#pragma unroll 4
    for (int j = 0; j < 64; ++j) {
        float2 a = hs2[j * 17 + ty];
        const float4 wv4 = *(const float4*)(W1t + j * 64 + o0);
        l1[0] += a.x * wv4.x; l1[1] += a.x * wv4.y; l1[2] += a.x * wv4.z; l1[3] += a.x * wv4.w;
        l1[4] += a.y * wv4.x; l1[5] += a.y * wv4.y; l1[6] += a.y * wv4.z; l1[7] += a.y * wv4.w;
    }
    __syncthreads();
#pragma unroll
    for (int ni = 0; ni < 2; ++ni)
#pragma unroll
        for (int oi = 0; oi < 4; ++oi)
            hsf[(o0 + oi) * 34 + n0 + ni] = fmaxf(l1[ni * 4 + oi] + b1s[o0 + oi], 0.f);
    __syncthreads();

    // ---- Lin2 + outer relu ----
    float l2[8];
#pragma unroll
    for (int i = 0; i < 8; ++i) l2[i] = 0.f;
#pragma unroll 4
    for (int j = 0; j < 64; ++j) {
        float2 a = hs2[j * 17 + ty];
        const float4 wv4 = *(const float4*)(W2t + j * 64 + o0);
        l2[0] += a.x * wv4.x; l2[1] += a.x * wv4.y; l2[2] += a.x * wv4.z; l2[3] += a.x * wv4.w;
        l2[4] += a.y * wv4.x; l2[5] += a.y * wv4.y; l2[6] += a.y * wv4.z; l2[7] += a.y * wv4.w;
    }
    __syncthreads();
#pragma unroll
    for (int ni = 0; ni < 2; ++ni) {
        int node = node0 + n0 + ni;
        float4 yv;
        yv.x = fmaxf(l2[ni * 4 + 0] + b2s[o0 + 0], 0.f);
        yv.y = fmaxf(l2[ni * 4 + 1] + b2s[o0 + 1], 0.f);
        yv.z = fmaxf(l2[ni * 4 + 2] + b2s[o0 + 2], 0.f);
        yv.w = fmaxf(l2[ni * 4 + 3] + b2s[o0 + 3], 0.f);
        if (node < NN) *(float4*)(Y + (size_t)node * DD + o0) = yv;
        hsf[(o0 + 0) * 34 + n0 + ni] = yv.x;
        hsf[(o0 + 1) * 34 + n0 + ni] = yv.y;
        hsf[(o0 + 2) * 34 + n0 + ni] = yv.z;
        hsf[(o0 + 3) * 34 + n0 + ni] = yv.w;
    }
    __syncthreads();

    // ---- BN partial sums ----
    if (tid < 64) {
        float s = 0.f, sq = 0.f;
        int lim = NN - node0;
        if (lim > 32) lim = 32;
        for (int n = 0; n < lim; ++n) {
            float v = hsf[tid * 34 + n];
            s += v;
            sq += v * v;
        }
        atomicAdd(&bnstat[tid], s);
        atomicAdd(&bnstat[64 + tid], sq);
    }
}

// ---------------- BN finalize+apply (+bf16 table write, + fused pool) ----------------
__global__ __launch_bounds__(256) void k_bnapply(
    const float* __restrict__ Y, const float* __restrict__ bs,
    const float* __restrict__ g, const float* __restrict__ b,
    float* __restrict__ XO, ushort* __restrict__ XH,
    const int* __restrict__ batch, float* __restrict__ gpool, int do_pool) {
    __shared__ float sc[64], shf[64], pool[512];
    int tid = threadIdx.x;
    if (tid < 64) {
        float mean = bs[tid] * (1.f / NN);
        float var = fmaxf(bs[64 + tid] * (1.f / NN) - mean * mean, 0.f);
        float inv = rsqrtf(var + BN_EPS_F);
        float s = g[tid] * inv;
        sc[tid] = s;
        shf[tid] = b[tid] - mean * s;
    }
    __syncthreads();
    int i = blockIdx.x * 256 + tid;  // float4 index
    int n = i >> 4, fq = (i & 15) * 4;
    float4 r = make_float4(0.f, 0.f, 0.f, 0.f);
    bool valid = i < NN * 16;
    if (valid) {
        float4 y = *(const float4*)(Y + (size_t)i * 4);
        r.x = y.x * sc[fq + 0] + shf[fq + 0];
        r.y = y.y * sc[fq + 1] + shf[fq + 1];
        r.z = y.z * sc[fq + 2] + shf[fq + 2];
        r.w = y.w * sc[fq + 3] + shf[fq + 3];
        *(float4*)(XO + (size_t)i * 4) = r;
        ushort4 h;
        h.x = f2bu(r.x); h.y = f2bu(r.y); h.z = f2bu(r.z); h.w = f2bu(r.w);
        *(ushort4*)(XH + (size_t)i * 4) = h;
    }
    if (do_pool) {
        int nfirst = blockIdx.x * 16;
        int nlast = nfirst + 15;
        if (nlast >= NN) nlast = NN - 1;
        int gmin = batch[nfirst], gmax = batch[nlast];
        int span = gmax - gmin + 1;
        if (span <= 8) {
            for (int j = tid; j < span * 64; j += 256) pool[j] = 0.f;
            __syncthreads();
            if (valid) {
                int gb = batch[n] - gmin;
                atomicAdd(&pool[gb * 64 + fq + 0], r.x);
                atomicAdd(&pool[gb * 64 + fq + 1], r.y);
                atomicAdd(&pool[gb * 64 + fq + 2], r.z);
                atomicAdd(&pool[gb * 64 + fq + 3], r.w);
            }
            __syncthreads();
            for (int j = tid; j < span * 64; j += 256)
                atomicAdd(&gpool[(size_t)(gmin + (j >> 6)) * 64 + (j & 63)], pool[j]);
        } else {
            if (valid) {
                float* gp = gpool + (size_t)batch[n] * DD + fq;
                atomicAdd(gp + 0, r.x);
                atomicAdd(gp + 1, r.y);
                atomicAdd(gp + 2, r.z);
                atomicAdd(gp + 3, r.w);
            }
        }
    }
}

// ---------------- head: fc1+relu, fc2, log_softmax ----------------
__global__ __launch_bounds__(256) void k_head(const float* __restrict__ gpool,
                                              const float* __restrict__ fc1W, const float* __restrict__ fc1b,
                                              const float* __restrict__ fc2W, const float* __restrict__ fc2b,
                                              float* __restrict__ out) {
    __shared__ float sh[12576];
    float* const gs = sh;
    float* const w1t = sh + 4096;
    float* const z1s = sh + 8256;
    float* const b1s = sh + 12416;
    float* const b2s = sh + 12480;
    float* const w2t = sh;
    float* const z2s = sh + 4096;

    int tid = threadIdx.x;
    for (int i = tid; i < 4096; i += 256) {
        gs[i] = gpool[i];
        int o = i >> 6, j = i & 63;
        w1t[j * 65 + o] = fc1W[i];
    }
    if (tid < 64) b1s[tid] = fc1b[tid];
    if (tid < 32) b2s[tid] = fc2b[tid];
    __syncthreads();
    {
        int tx = tid & 15, ty = tid >> 4, o0 = tx * 4, g0 = ty * 4;
        float acc[16];
#pragma unroll
        for (int i = 0; i < 16; ++i) acc[i] = 0.f;
        for (int j = 0; j < 64; ++j) {
            float w0 = w1t[j * 65 + o0 + 0], w1 = w1t[j * 65 + o0 + 1];
            float w2 = w1t[j * 65 + o0 + 2], w3 = w1t[j * 65 + o0 + 3];
#pragma unroll
            for (int gi = 0; gi < 4; ++gi) {
                float a = gs[(g0 + gi) * 64 + j];
                acc[gi * 4 + 0] += a * w0; acc[gi * 4 + 1] += a * w1;
                acc[gi * 4 + 2] += a * w2; acc[gi * 4 + 3] += a * w3;
            }
        }
        __syncthreads();
#pragma unroll
        for (int gi = 0; gi < 4; ++gi)
#pragma unroll
            for (int oi = 0; oi < 4; ++oi)
                z1s[(g0 + gi) * 65 + o0 + oi] = fmaxf(acc[gi * 4 + oi] + b1s[o0 + oi], 0.f);
    }
    for (int i = tid; i < 2048; i += 256) {
        int o = i >> 6, j = i & 63;
        w2t[j * 33 + o] = fc2W[i];
    }
    __syncthreads();
    {
        int tx = tid & 7, ty = tid >> 3, o0 = tx * 4, g0 = ty * 2;
        float acc[8];
#pragma unroll
        for (int i = 0; i < 8; ++i) acc[i] = 0.f;
        for (int j = 0; j < 64; ++j) {
            float w0 = w2t[j * 33 + o0 + 0], w1 = w2t[j * 33 + o0 + 1];
            float w2 = w2t[j * 33 + o0 + 2], w3 = w2t[j * 33 + o0 + 3];
            float a0 = z1s[(g0 + 0) * 65 + j];
            float a1 = z1s[(g0 + 1) * 65 + j];
            acc[0] += a0 * w0; acc[1] += a0 * w1; acc[2] += a0 * w2; acc[3] += a0 * w3;
            acc[4] += a1 * w0; acc[5] += a1 * w1; acc[6] += a1 * w2; acc[7] += a1 * w3;
        }
#pragma unroll
        for (int gi = 0; gi < 2; ++gi)
#pragma unroll
            for (int oi = 0; oi < 4; ++oi)
                z2s[(g0 + gi) * 33 + o0 + oi] = acc[gi * 4 + oi] + b2s[o0 + oi];
    }
    __syncthreads();
    if (tid < 64) {
        float m = -3.402823466e38f;
        for (int c = 0; c < DOUT; ++c) m = fmaxf(m, z2s[tid * 33 + c]);
        float s = 0.f;
        for (int c = 0; c < DOUT; ++c) s += expf(z2s[tid * 33 + c] - m);
        float lse = m + logf(s);
        for (int c = 0; c < DOUT; ++c)
            out[tid * DOUT + c] = z2s[tid * 33 + c] - lse;
    }
}

extern "C" void kernel_launch(void* const* d_in, const int* in_sizes, int n_in,
                              void* d_out, int out_size, void* d_ws, size_t ws_size,
                              hipStream_t stream) {
    const float* x = (const float*)d_in[0];
    const int* ei = (const int*)d_in[1];
    const int* src = ei;
    const int* dst = ei + NE;
    const int* batch = (const int*)d_in[2];
    const float *mlpW[3], *mlpB[3], *w1[3], *bb1[3], *w2[3], *bb2[3], *bng[3], *bnb[3];
    for (int l = 0; l < 3; ++l) {
        mlpW[l] = (const float*)d_in[3 + 6 * l];
        mlpB[l] = (const float*)d_in[4 + 6 * l];
        w1[l]   = (const float*)d_in[5 + 6 * l];
        bb1[l]  = (const float*)d_in[6 + 6 * l];
        w2[l]   = (const float*)d_in[7 + 6 * l];
        bb2[l]  = (const float*)d_in[8 + 6 * l];
        bng[l]  = (const float*)d_in[21 + 2 * l];
        bnb[l]  = (const float*)d_in[22 + 2 * l];
    }
    const float* fc1W = (const float*)d_in[27];
    const float* fc1b = (const float*)d_in[28];
    const float* fc2W = (const float*)d_in[29];
    const float* fc2b = (const float*)d_in[30];
    float* out = (float*)d_out;

    char* ws = (char*)d_ws;
    size_t off = 0;
    auto alloc = [&](size_t bytes) -> void* {
        void* p = ws + off;
        off = (off + bytes + 511) & ~(size_t)511;
        return p;
    };
    int* counts    = (int*)alloc((size_t)NN * 4);
    int* row_ptr   = (int*)alloc((size_t)(NN + 1) * 4);
    int* rank      = (int*)alloc((size_t)NE * 4);
    int* blockSums = (int*)alloc(256 * 4);
    int* blockBase = (int*)alloc(256 * 4);
    int* csr_src   = (int*)alloc((size_t)NE * 4);
    float* XB      = (float*)alloc((size_t)NN * DD * 4);
    float* Yb      = (float*)alloc((size_t)NN * DD * 4);
    ushort* XH     = (ushort*)alloc((size_t)NN * DD * 2);
    ushort* Wb     = (ushort*)alloc((size_t)3 * 49152 * 2);
    float* Wt1     = (float*)alloc((size_t)3 * 16384 * 4);
    float* Wsm     = (float*)alloc((size_t)6 * 4096 * 4);
    float* bnstat  = (float*)alloc(384 * 4);
    float* gpool   = (float*)alloc((size_t)NGRAPH * DD * 4);
    (void)ws_size; (void)in_sizes; (void)n_in; (void)out_size;

    k_init<<<196, 256, 0, stream>>>(counts, bnstat, gpool);
    k_rank<<<6250, 256, 0, stream>>>(dst, counts, rank);
    k_scan_a<<<196, 256, 0, stream>>>(counts, blockSums);
    k_scan_b<<<1, 256, 0, stream>>>(blockSums, blockBase);
    k_scan_c<<<196, 256, 0, stream>>>(counts, blockBase, row_ptr);
    k_place<<<6250, 256, 0, stream>>>(src, dst, rank, row_ptr, csr_src);
    k_wprep<<<864, 256, 0, stream>>>(mlpW[0], mlpW[1], mlpW[2],
                                     w1[0], w2[0], w1[1], w2[1], w1[2], w2[2],
                                     Wb, Wt1, Wsm);
    k_x2h<<<3125, 256, 0, stream>>>(x, XH);

    const float* Xin = x;
    for (int l = 0; l < 3; ++l) {
        k_fused<<<1563, 256, 0, stream>>>(Xin, XH, row_ptr, csr_src,
                                          Wb + (size_t)l * 49152,
                                          Wt1 + (size_t)l * 16384,
                                          mlpB[l],
                                          Wsm + (size_t)(2 * l) * 4096, bb1[l],
                                          Wsm + (size_t)(2 * l + 1) * 4096, bb2[l],
                                          Yb, bnstat + l * 128);
        k_bnapply<<<3125, 256, 0, stream>>>(Yb, bnstat + l * 128, bng[l], bnb[l],
                                            XB, XH, batch, gpool, (l == 2) ? 1 : 0);
        Xin = XB;
    }
    k_head<<<1, 256, 0, stream>>>(gpool, fc1W, fc1b, fc2W, fc2b, out);
}